// Round 2
// baseline (467.128 us; speedup 1.0000x reference)
//
#include <hip/hip_runtime.h>
#include <math.h>

// ---------------------------------------------------------------------------
// BiAttention round 8:
//  - k_prep: ib path re-tiled 128x128 -> 64tok x 128h so static smem drops
//    34816/32768 -> 16640 B. R7 showed conflicts fixed (1.66e7 -> 1.6e6) but
//    dur ~flat: kernel is latency-bound (Occ 37%, VALU 10%, HBM 34%).
//    16.6 KB LDS lifts residency 5 -> 8 blocks/CU (wave cap) for ~1.6x more
//    loads in flight. Same XOR 16B-group swizzle (group ^= tok>>3, 3 bits):
//    transpose read stays ~2-way (8*128/2 = 512 = 0 mod 32 neutralized by
//    group XOR); dbf/store patterns conflict-free.
//  - k_pooled: #pragma unroll 4 on the L loop (1 block/CU, serial loads were
//    the latency chain).
//  - everything else identical to verified R7.
// Fragment scheme (verified R2..R7): A/B frag row = lane&15, k-group
// (lane>>4)*8 contiguous, XOR swizzle (colgroup ^ (row&7));
// C/D: col = lane&15, row = (lane>>4)*4 + r.
// ---------------------------------------------------------------------------

#define SCALE 0.04419417382415922f  // 1/sqrt(512)

typedef __attribute__((ext_vector_type(8))) short short8;
typedef __attribute__((ext_vector_type(4))) float floatx4;

__device__ __forceinline__ unsigned short f2bf(float x) {
  unsigned u = __float_as_uint(x);
  unsigned r = u + 0x7FFFu + ((u >> 16) & 1u);
  return (unsigned short)(r >> 16);
}
__device__ __forceinline__ float bf2f(unsigned short h) {
  return __uint_as_float(((unsigned)h) << 16);
}
__device__ __forceinline__ unsigned pk2(float a, float b) {
  return (unsigned)f2bf(a) | ((unsigned)f2bf(b) << 16);
}

__device__ __forceinline__ float wave_max(float v) {
#pragma unroll
  for (int o = 32; o > 0; o >>= 1) v = fmaxf(v, __shfl_xor(v, o, 64));
  return v;
}
__device__ __forceinline__ float wave_sum(float v) {
#pragma unroll
  for (int o = 32; o > 0; o >>= 1) v += __shfl_xor(v, o, 64);
  return v;
}

#define GLD_LDS16(gptr, lptr)                                             \
  __builtin_amdgcn_global_load_lds(                                       \
      (const __attribute__((address_space(1))) void*)(gptr),              \
      (__attribute__((address_space(3))) void*)(lptr), 16, 0, 0)

// ---------------------------------------------------------------------------
// Merged prep: idx<512 weights; [512,4608) ib 64x128 tiles; [4608,6656) qb.
__global__ __launch_bounds__(256) void k_prep(
    const float* __restrict__ ib, const float* __restrict__ qb,
    const float* __restrict__ lf_w1, const float* __restrict__ if_w1,
    const float* __restrict__ lf_wm, const float* __restrict__ if_wm,
    const float* __restrict__ fh_w, unsigned short* __restrict__ ib_bf,
    unsigned short* __restrict__ ibT, unsigned short* __restrict__ qb_bf,
    unsigned short* __restrict__ qbT, unsigned short* __restrict__ w1t_lf,
    unsigned short* __restrict__ w1t_if, unsigned short* __restrict__ wcat_t,
    unsigned short* __restrict__ fh_wt) {
  __shared__ __align__(16) char smem[64 * 65 * 4];  // 16640 B
  const int idx = blockIdx.x, t = threadIdx.x;

  if (idx < 512) {
    // ---- weights: f32 [K,N] -> bf16 [N, koff+K] (stride 65: conflict-free)
    float(*T)[65] = (float(*)[65])smem;
    const float* src;
    unsigned short* dst;
    int N, ds, koff, k0, n0;
    if (idx < 64) {
      src = lf_w1; dst = w1t_lf; N = 512; ds = 512; koff = 0;
      k0 = (idx & 7) * 64; n0 = (idx >> 3) * 64;
    } else if (idx < 128) {
      int l = idx - 64;
      src = if_w1; dst = w1t_if; N = 512; ds = 512; koff = 0;
      k0 = (l & 7) * 64; n0 = (l >> 3) * 64;
    } else if (idx < 256) {
      int l = idx - 128;
      src = lf_wm; dst = wcat_t; N = 1024; ds = 1024; koff = 0;
      k0 = (l & 7) * 64; n0 = (l >> 3) * 64;
    } else if (idx < 384) {
      int l = idx - 256;
      src = if_wm; dst = wcat_t; N = 1024; ds = 1024; koff = 512;
      k0 = (l & 7) * 64; n0 = (l >> 3) * 64;
    } else {
      int l = idx - 384;
      src = fh_w; dst = fh_wt; N = 512; ds = 1024; koff = 0;
      k0 = (l & 15) * 64; n0 = (l >> 4) * 64;
    }
#pragma unroll
    for (int i = 0; i < 16; i++) {
      int e = t + i * 256, r = e >> 6, c = e & 63;
      T[r][c] = src[(size_t)(k0 + r) * N + n0 + c];
    }
    __syncthreads();
#pragma unroll
    for (int i = 0; i < 8; i++) {
      int e = t + i * 256, r = e >> 5, c2 = (e & 31) * 2;
      *(unsigned*)&dst[(size_t)(n0 + r) * ds + koff + k0 + c2] =
          pk2(T[c2][r], T[c2 + 1][r]);
    }
  } else if (idx < 4608) {
    // ---- ib 64tok x 128h tiles, swizzled [64][128] bf16 (16 KB) ----
    // Logical (tok, h) stored at Tb[tok*128 + sw] where the 16B column group
    // (h>>3) is XORed with (tok>>3) (3 bits). Transpose-read lanes differ in
    // tok>>3 -> spread over 8 bank groups (~2-way, free).
    int j = idx - 512;
    int b = j >> 4, tok0 = ((j >> 2) & 3) * 64, h0 = (j & 3) * 128;
    unsigned short* Tb = (unsigned short*)smem;  // [64][128] swizzled
    const float* src = ib + ((size_t)b * 256 + tok0) * 512 + h0;
#pragma unroll
    for (int i = 0; i < 8; i++) {
      int e = t + i * 256, tok = e >> 5, h4 = (e & 31) * 4;
      float4 v = *(const float4*)&src[(size_t)tok * 512 + h4];
      uint2 p;
      p.x = pk2(v.x, v.y);
      p.y = pk2(v.z, v.w);
      int col = ((((h4 >> 3) ^ (tok >> 3)) & 15) << 3) | (h4 & 7);
      *(uint2*)&Tb[tok * 128 + col] = p;
    }
    __syncthreads();
    unsigned short* dbf = ib_bf + ((size_t)b * 256 + tok0) * 512 + h0;
#pragma unroll
    for (int i = 0; i < 4; i++) {
      int e = t + i * 256, tok = e >> 4, g = e & 15;
      int sg = (g ^ (tok >> 3)) & 15;
      *(uint4*)&dbf[(size_t)tok * 512 + g * 8] = *(const uint4*)&Tb[tok * 128 + sg * 8];
    }
    unsigned short* dT = ibT + ((size_t)b * 512 + h0) * 256 + tok0;
#pragma unroll
    for (int i = 0; i < 4; i++) {
      int e = t + i * 256, h = e >> 3, tc = (e & 7) * 8;
      int hg = h >> 3, ho = h & 7;
      unsigned y[8];
#pragma unroll
      for (int k = 0; k < 8; k++) {
        int r = tc + k;
        y[k] = Tb[r * 128 + (((hg ^ (r >> 3)) & 15) << 3) + ho];
      }
      uint4 v;
      v.x = y[0] | (y[1] << 16);
      v.y = y[2] | (y[3] << 16);
      v.z = y[4] | (y[5] << 16);
      v.w = y[6] | (y[7] << 16);
      *(uint4*)&dT[(size_t)h * 256 + tc] = v;
    }
  } else {
    // ---- qb 64x64 tiles (stride 65: conflict-free) ----
    int j = idx - 4608;
    int b = j >> 3, h0 = (j & 7) * 64;
    float(*T)[65] = (float(*)[65])smem;
    const float* src = qb + (size_t)b * 64 * 512;
    unsigned short* dbf = qb_bf + (size_t)b * 64 * 512;
    unsigned short* dT = qbT + (size_t)b * 512 * 64;
#pragma unroll
    for (int i = 0; i < 16; i++) {
      int e = t + i * 256, r = e >> 6, c = e & 63;
      T[r][c] = src[(size_t)r * 512 + h0 + c];
    }
    __syncthreads();
#pragma unroll
    for (int i = 0; i < 8; i++) {
      int e = t + i * 256, r = e >> 5, c2 = (e & 31) * 2;
      *(unsigned*)&dbf[(size_t)r * 512 + h0 + c2] = pk2(T[r][c2], T[r][c2 + 1]);
    }
#pragma unroll
    for (int i = 0; i < 8; i++) {
      int e = t + i * 256, h = e >> 5, r2 = (e & 31) * 2;
      *(unsigned*)&dT[(size_t)(h0 + h) * 64 + r2] = pk2(T[r2][h], T[r2 + 1][h]);
    }
  }
}

// ---------------------------------------------------------------------------
// Fused scores: per (i-chunk, batch). S[64q x 128i] = qb @ ib^T * SCALE.
// Emits P1[b,i,q] normalized bf16 (softmax over q, qmask) and P2[b,q,i] raw
// exp bf16 (imask; unnormalized) + psum[b*64+q][8] per-wave partial row sums.
__global__ __launch_bounds__(256) void k_scores_f(
    const unsigned short* __restrict__ ibf, const unsigned short* __restrict__ qbf,
    const int* __restrict__ imask, const int* __restrict__ qmask,
    unsigned short* __restrict__ P1, unsigned short* __restrict__ P2,
    float* __restrict__ psum) {
  __shared__ unsigned short As[64 * 64];
  __shared__ unsigned short Bs[128 * 64];
  __shared__ __align__(16) unsigned short X[128 * 72];  // E:[64][136] / Pl:[128][72]
  const int b = blockIdx.y, ic = blockIdx.x, i0 = ic * 128;
  const int t = threadIdx.x, w = t >> 6, lane = t & 63, c = lane & 15, qq = lane >> 4;

  floatx4 acc[4][2];
#pragma unroll
  for (int ti = 0; ti < 4; ti++)
#pragma unroll
    for (int tj = 0; tj < 2; tj++) acc[ti][tj] = (floatx4){0.f, 0.f, 0.f, 0.f};

  for (int k0 = 0; k0 < 512; k0 += 64) {
#pragma unroll
    for (int i = 0; i < 2; i++) {
      int s = i * 256 + t, row = s >> 3, src = (s & 7) ^ (row & 7);
      GLD_LDS16(qbf + ((size_t)b * 64 + row) * 512 + k0 + src * 8,
                &As[(i * 256 + w * 64) * 8]);
    }
#pragma unroll
    for (int i = 0; i < 4; i++) {
      int s = i * 256 + t, row = s >> 3, src = (s & 7) ^ (row & 7);
      GLD_LDS16(ibf + ((size_t)b * 256 + i0 + row) * 512 + k0 + src * 8,
                &Bs[(i * 256 + w * 64) * 8]);
    }
    __syncthreads();
#pragma unroll
    for (int kk = 0; kk < 2; kk++) {
      short8 a[4], bb[2];
#pragma unroll
      for (int ti = 0; ti < 4; ti++)
        a[ti] = *(const short8*)&As[(ti * 16 + c) * 64 + ((kk * 4 + qq) ^ (c & 7)) * 8];
#pragma unroll
      for (int tj = 0; tj < 2; tj++)
        bb[tj] = *(const short8*)&Bs[(w * 32 + tj * 16 + c) * 64 + ((kk * 4 + qq) ^ (c & 7)) * 8];
#pragma unroll
      for (int ti = 0; ti < 4; ti++)
#pragma unroll
        for (int tj = 0; tj < 2; tj++)
          acc[ti][tj] = __builtin_amdgcn_mfma_f32_16x16x32_bf16(a[ti], bb[tj], acc[ti][tj], 0, 0, 0);
    }
    __syncthreads();
  }

  const int il0 = w * 32 + c;  // tj=0 local i; tj=1 is il0+16
  int imsk0 = imask[b * 256 + i0 + il0];
  int imsk1 = imask[b * 256 + i0 + il0 + 16];
  int qm[4][4];
#pragma unroll
  for (int ti = 0; ti < 4; ti++)
#pragma unroll
    for (int rr = 0; rr < 4; rr++) qm[ti][rr] = qmask[b * 64 + ti * 16 + qq * 4 + rr];

  // ---- E phase: raw exp (imask) into X[64][136], per-wave row sums ----
#pragma unroll
  for (int ti = 0; ti < 4; ti++)
#pragma unroll
    for (int rr = 0; rr < 4; rr++) {
      int qv = ti * 16 + qq * 4 + rr;
      float e0 = imsk0 ? 0.f : __expf(acc[ti][0][rr] * SCALE);
      float e1 = imsk1 ? 0.f : __expf(acc[ti][1][rr] * SCALE);
      X[qv * 136 + il0] = f2bf(e0);
      X[qv * 136 + il0 + 16] = f2bf(e1);
      float s = e0 + e1;
#pragma unroll
      for (int o = 1; o <= 8; o <<= 1) s += __shfl_xor(s, o, 64);
      if (c == 0) psum[((size_t)(b * 64 + qv)) * 8 + ic * 4 + w] = s;
    }
  __syncthreads();
#pragma unroll
  for (int i = 0; i < 4; i++) {
    int e2 = t + i * 256, qv = e2 >> 4, g = e2 & 15;
    *(uint4*)&P2[((size_t)b * 64 + qv) * 256 + i0 + g * 8] = *(const uint4*)&X[qv * 136 + g * 8];
  }
  __syncthreads();

  // ---- P1 phase: column softmax over q (qmask), normalized, into X[128][72]
#pragma unroll
  for (int tj = 0; tj < 2; tj++) {
    float ev[4][4];
    float s1 = 0.f;
#pragma unroll
    for (int ti = 0; ti < 4; ti++)
#pragma unroll
      for (int rr = 0; rr < 4; rr++) {
        ev[ti][rr] = qm[ti][rr] ? 0.f : __expf(acc[ti][tj][rr] * SCALE);
        s1 += ev[ti][rr];
      }
    s1 += __shfl_xor(s1, 16, 64);
    s1 += __shfl_xor(s1, 32, 64);
    float inv = 1.f / s1;
    int il = il0 + tj * 16;
#pragma unroll
    for (int ti = 0; ti < 4; ti++)
#pragma unroll
      for (int rr = 0; rr < 4; rr++)
        X[il * 72 + ti * 16 + qq * 4 + rr] = f2bf(ev[ti][rr] * inv);
  }
  __syncthreads();
#pragma unroll
  for (int i = 0; i < 4; i++) {
    int e2 = t + i * 256, il = e2 >> 3, g = e2 & 7;
    *(uint4*)&P1[((size_t)b * 256 + i0 + il) * 64 + g * 8] = *(const uint4*)&X[il * 72 + g * 8];
  }
}

// ---------------------------------------------------------------------------
// ifeat[b,256,512] = P1 @ qb ; B from qbT (bf16 [512][64]). K=64 single step.
__global__ __launch_bounds__(256) void k_av1(const unsigned short* __restrict__ P1,
                                             const unsigned short* __restrict__ qbT,
                                             unsigned short* __restrict__ ifeat) {
  __shared__ unsigned short As[128 * 64];
  __shared__ unsigned short Bs[128 * 64];
  const int b = blockIdx.y, m0 = (blockIdx.x >> 2) * 128, n0 = (blockIdx.x & 3) * 128;
  const int t = threadIdx.x, w = t >> 6, lane = t & 63, c = lane & 15, q = lane >> 4;
  const int wm = w >> 1, wn = w & 1;
#pragma unroll
  for (int i = 0; i < 4; i++) {
    int s = i * 256 + t, row = s >> 3, src = (s & 7) ^ (row & 7);
    GLD_LDS16(P1 + ((size_t)b * 256 + m0 + row) * 64 + src * 8, &As[(i * 256 + w * 64) * 8]);
  }
#pragma unroll
  for (int i = 0; i < 4; i++) {
    int s = i * 256 + t, row = s >> 3, src = (s & 7) ^ (row & 7);
    GLD_LDS16(qbT + ((size_t)b * 512 + n0 + row) * 64 + src * 8, &Bs[(i * 256 + w * 64) * 8]);
  }
  __syncthreads();
  floatx4 acc[4][4];
#pragma unroll
  for (int ti = 0; ti < 4; ti++)
#pragma unroll
    for (int tj = 0; tj < 4; tj++) acc[ti][tj] = (floatx4){0.f, 0.f, 0.f, 0.f};
#pragma unroll
  for (int kk = 0; kk < 2; kk++) {
    short8 a[4], bb[4];
#pragma unroll
    for (int ti = 0; ti < 4; ti++)
      a[ti] = *(const short8*)&As[(wm * 64 + ti * 16 + c) * 64 + ((kk * 4 + q) ^ (c & 7)) * 8];
#pragma unroll
    for (int tj = 0; tj < 4; tj++)
      bb[tj] = *(const short8*)&Bs[(wn * 64 + tj * 16 + c) * 64 + ((kk * 4 + q) ^ (c & 7)) * 8];
#pragma unroll
    for (int ti = 0; ti < 4; ti++)
#pragma unroll
      for (int tj = 0; tj < 4; tj++)
        acc[ti][tj] = __builtin_amdgcn_mfma_f32_16x16x32_bf16(a[ti], bb[tj], acc[ti][tj], 0, 0, 0);
  }
#pragma unroll
  for (int ti = 0; ti < 4; ti++)
#pragma unroll
    for (int rr = 0; rr < 4; rr++) {
      int m = m0 + wm * 64 + ti * 16 + q * 4 + rr;
      unsigned short* op = ifeat + ((size_t)b * 256 + m) * 512 + n0 + wn * 64;
#pragma unroll
      for (int tj = 0; tj < 4; tj++) op[tj * 16 + c] = f2bf(acc[ti][tj][rr]);
    }
}

// ---------------------------------------------------------------------------
// lfeat[b,64,512] = (P2 @ ib) * rowscale ; B from ibT (bf16 [512][256]).
// K=256, 4 chunks. Row scale 1/sum(psum[row][0..7]) folded into epilogue.
__global__ __launch_bounds__(256) void k_av2(const unsigned short* __restrict__ P2,
                                             const unsigned short* __restrict__ ibT,
                                             const float* __restrict__ psum,
                                             unsigned short* __restrict__ lfeat) {
  __shared__ unsigned short As[64 * 64];
  __shared__ unsigned short Bs[128 * 64];
  const int b = blockIdx.y, n0 = blockIdx.x * 128;
  const int t = threadIdx.x, w = t >> 6, lane = t & 63, c = lane & 15, q = lane >> 4;
  const int wm = w >> 1, wn = w & 1;
  floatx4 acc[2][4];
#pragma unroll
  for (int ti = 0; ti < 2; ti++)
#pragma unroll
    for (int tj = 0; tj < 4; tj++) acc[ti][tj] = (floatx4){0.f, 0.f, 0.f, 0.f};

  for (int kc = 0; kc < 256; kc += 64) {
#pragma unroll
    for (int i = 0; i < 2; i++) {
      int s = i * 256 + t, row = s >> 3, src = (s & 7) ^ (row & 7);
      GLD_LDS16(P2 + ((size_t)b * 64 + row) * 256 + kc + src * 8, &As[(i * 256 + w * 64) * 8]);
    }
#pragma unroll
    for (int i = 0; i < 4; i++) {
      int s = i * 256 + t, row = s >> 3, src = (s & 7) ^ (row & 7);
      GLD_LDS16(ibT + ((size_t)b * 512 + n0 + row) * 256 + kc + src * 8,
                &Bs[(i * 256 + w * 64) * 8]);
    }
    __syncthreads();
#pragma unroll
    for (int kk = 0; kk < 2; kk++) {
      short8 a[2], bb[4];
#pragma unroll
      for (int ti = 0; ti < 2; ti++)
        a[ti] = *(const short8*)&As[(wm * 32 + ti * 16 + c) * 64 + ((kk * 4 + q) ^ (c & 7)) * 8];
#pragma unroll
      for (int tj = 0; tj < 4; tj++)
        bb[tj] = *(const short8*)&Bs[(wn * 64 + tj * 16 + c) * 64 + ((kk * 4 + q) ^ (c & 7)) * 8];
#pragma unroll
      for (int ti = 0; ti < 2; ti++)
#pragma unroll
        for (int tj = 0; tj < 4; tj++)
          acc[ti][tj] = __builtin_amdgcn_mfma_f32_16x16x32_bf16(a[ti], bb[tj], acc[ti][tj], 0, 0, 0);
    }
    __syncthreads();
  }
#pragma unroll
  for (int ti = 0; ti < 2; ti++)
#pragma unroll
    for (int rr = 0; rr < 4; rr++) {
      int m = wm * 32 + ti * 16 + q * 4 + rr;
      const float* ps = psum + ((size_t)(b * 64 + m)) * 8;
      float s = ps[0] + ps[1] + ps[2] + ps[3] + ps[4] + ps[5] + ps[6] + ps[7];
      float inv = 1.f / s;
      unsigned short* op = lfeat + ((size_t)b * 64 + m) * 512 + n0 + wn * 64;
#pragma unroll
      for (int tj = 0; tj < 4; tj++) op[tj * 16 + c] = f2bf(acc[ti][tj][rr] * inv);
    }
}

// ---------------------------------------------------------------------------
// Partial logits: outp[nc*M + m] = sum over n-chunk nc of relu(X@W1+b1)*w2.
__global__ __launch_bounds__(256) void k_logits_part(
    const unsigned short* __restrict__ X, const unsigned short* __restrict__ W1t,
    const float* __restrict__ b1, const float* __restrict__ w2,
    float* __restrict__ outp, int M) {
  __shared__ unsigned short As[128 * 64];
  __shared__ unsigned short Bs[128 * 64];
  __shared__ float red[2][128];
  const int t = threadIdx.x, w = t >> 6, lane = t & 63;
  const int wm = w >> 1, wn = w & 1, c = lane & 15, q = lane >> 4;
  const int idx = blockIdx.x;
  const int m_tile = (idx & 7) + ((idx >> 5) << 3), nc = (idx >> 3) & 3;
  const int m0 = m_tile * 128, n0 = nc * 128;

  floatx4 acc[4][4];
#pragma unroll
  for (int ti = 0; ti < 4; ti++)
#pragma unroll
    for (int tj = 0; tj < 4; tj++) acc[ti][tj] = (floatx4){0.f, 0.f, 0.f, 0.f};

  for (int k0 = 0; k0 < 512; k0 += 64) {
#pragma unroll
    for (int it = 0; it < 4; it++) {
      int s = it * 256 + t, row = s >> 3, src = (s & 7) ^ (row & 7);
      GLD_LDS16(X + (size_t)(m0 + row) * 512 + k0 + src * 8, &As[(it * 256 + w * 64) * 8]);
      GLD_LDS16(W1t + (size_t)(n0 + row) * 512 + k0 + src * 8, &Bs[(it * 256 + w * 64) * 8]);
    }
    __syncthreads();
#pragma unroll
    for (int kk = 0; kk < 2; kk++) {
      short8 a[4], bb[4];
#pragma unroll
      for (int ti = 0; ti < 4; ti++)
        a[ti] = *(const short8*)&As[(wm * 64 + ti * 16 + c) * 64 + ((kk * 4 + q) ^ (c & 7)) * 8];
#pragma unroll
      for (int tj = 0; tj < 4; tj++)
        bb[tj] = *(const short8*)&Bs[(wn * 64 + tj * 16 + c) * 64 + ((kk * 4 + q) ^ (c & 7)) * 8];
#pragma unroll
      for (int ti = 0; ti < 4; ti++)
#pragma unroll
        for (int tj = 0; tj < 4; tj++)
          acc[ti][tj] = __builtin_amdgcn_mfma_f32_16x16x32_bf16(a[ti], bb[tj], acc[ti][tj], 0, 0, 0);
    }
    __syncthreads();
  }
  float partial[4][4] = {};
#pragma unroll
  for (int tj = 0; tj < 4; tj++) {
    int n = n0 + wn * 64 + tj * 16 + c;
    float bia = b1[n], wwv = w2[n];
#pragma unroll
    for (int ti = 0; ti < 4; ti++)
#pragma unroll
      for (int r = 0; r < 4; r++)
        partial[ti][r] += fmaxf(acc[ti][tj][r] + bia, 0.f) * wwv;
  }
#pragma unroll
  for (int msk = 1; msk <= 8; msk <<= 1)
#pragma unroll
    for (int ti = 0; ti < 4; ti++)
#pragma unroll
      for (int r = 0; r < 4; r++)
        partial[ti][r] += __shfl_xor(partial[ti][r], msk, 64);
  if (c == 0) {
#pragma unroll
    for (int ti = 0; ti < 4; ti++)
#pragma unroll
      for (int r = 0; r < 4; r++)
        red[wn][wm * 64 + ti * 16 + q * 4 + r] = partial[ti][r];
  }
  __syncthreads();
  if (t < 128) outp[(size_t)nc * M + m0 + t] = red[0][t] + red[1][t];
}

// ---------------------------------------------------------------------------
__global__ __launch_bounds__(256) void k_attsoft_i(const float* __restrict__ lp,
                                                   const int* __restrict__ imask,
                                                   float* __restrict__ att,
                                                   float* __restrict__ iw_out) {
  __shared__ float red[4];
  const int b = blockIdx.x, t = threadIdx.x;
  const int i = b * 256 + t;
  float x = lp[i] + lp[65536 + i] + lp[131072 + i] + lp[196608 + i];
  float v = imask[i] ? -1e9f : x;
  float wm = wave_max(v);
  if ((t & 63) == 0) red[t >> 6] = wm;
  __syncthreads();
  float mx = fmaxf(fmaxf(red[0], red[1]), fmaxf(red[2], red[3]));
  __syncthreads();
  float e = __expf(v - mx);
  float wsum = wave_sum(e);
  if ((t & 63) == 0) red[t >> 6] = wsum;
  __syncthreads();
  float s = red[0] + red[1] + red[2] + red[3];
  float p = e / s;
  att[i] = p;
  iw_out[i] = p;
}

__global__ __launch_bounds__(64) void k_attsoft_l(const float* __restrict__ lp,
                                                  const int* __restrict__ qmask,
                                                  float* __restrict__ att) {
  const int b = blockIdx.x, t = threadIdx.x;
  const int i = b * 64 + t;
  float x = lp[i] + lp[16384 + i] + lp[32768 + i] + lp[49152 + i];
  float v = qmask[i] ? -1e9f : x;
  float mx = wave_max(v);
  float e = __expf(v - mx);
  float s = wave_sum(e);
  att[i] = e / s;
}

// pooled_bf[b*1024 + ooff + h] = sum_l att[b,l] * X[b,l,h]
__global__ __launch_bounds__(256) void k_pooled(const unsigned short* __restrict__ X,
                                                const float* __restrict__ att, int L,
                                                unsigned short* __restrict__ out,
                                                int ooff) {
  __shared__ float ar[256];
  const int b = blockIdx.x, t = threadIdx.x;
  if (t < L) ar[t] = att[b * L + t];
  __syncthreads();
  float a0 = 0.f, a1 = 0.f;
  const unsigned short* Xb = X + (size_t)b * L * 512 + 2 * t;
#pragma unroll 4
  for (int l = 0; l < L; l++) {
    unsigned u = *(const unsigned*)&Xb[(size_t)l * 512];
    float a = ar[l];
    a0 += a * bf2f((unsigned short)(u & 0xffff));
    a1 += a * bf2f((unsigned short)(u >> 16));
  }
  *(unsigned*)&out[(size_t)b * 1024 + ooff + 2 * t] = pk2(a0, a1);
}

// ---------------------------------------------------------------------------
// Epilogue GEMM: out[M,N] = X[M,K]bf16 @ Wt[N,K]bf16 + biasA (+biasB).
__global__ __launch_bounds__(256) void k_egemm(const unsigned short* __restrict__ X,
                                               const unsigned short* __restrict__ Wt,
                                               const float* __restrict__ biasA,
                                               const float* __restrict__ biasB,
                                               float* __restrict__ outf,
                                               unsigned short* __restrict__ outbf,
                                               int N, int K) {
  __shared__ unsigned short As[64 * 64];
  __shared__ unsigned short Bs[64 * 64];
  const int n0 = blockIdx.x * 64, m0 = blockIdx.y * 64;
  const int t = threadIdx.x, w = t >> 6, lane = t & 63, c = lane & 15, q = lane >> 4;
  const int wm = w >> 1, wn = w & 1;
  floatx4 acc[2][2];
#pragma unroll
  for (int ti = 0; ti < 2; ti++)
#pragma unroll
    for (int tj = 0; tj < 2; tj++) acc[ti][tj] = (floatx4){0.f, 0.f, 0.f, 0.f};

  for (int k0 = 0; k0 < K; k0 += 64) {
#pragma unroll
    for (int i = 0; i < 2; i++) {
      int s = i * 256 + t, row = s >> 3, src = (s & 7) ^ (row & 7);
      GLD_LDS16(X + (size_t)(m0 + row) * K + k0 + src * 8, &As[(i * 256 + w * 64) * 8]);
      GLD_LDS16(Wt + (size_t)(n0 + row) * K + k0 + src * 8, &Bs[(i * 256 + w * 64) * 8]);
    }
    __syncthreads();
#pragma unroll
    for (int kk = 0; kk < 2; kk++) {
      short8 a[2], bb[2];
#pragma unroll
      for (int ti = 0; ti < 2; ti++)
        a[ti] = *(const short8*)&As[(wm * 32 + ti * 16 + c) * 64 + ((kk * 4 + q) ^ (c & 7)) * 8];
#pragma unroll
      for (int tj = 0; tj < 2; tj++)
        bb[tj] = *(const short8*)&Bs[(wn * 32 + tj * 16 + c) * 64 + ((kk * 4 + q) ^ (c & 7)) * 8];
#pragma unroll
      for (int ti = 0; ti < 2; ti++)
#pragma unroll
        for (int tj = 0; tj < 2; tj++)
          acc[ti][tj] = __builtin_amdgcn_mfma_f32_16x16x32_bf16(a[ti], bb[tj], acc[ti][tj], 0, 0, 0);
    }
    __syncthreads();
  }
#pragma unroll
  for (int tj = 0; tj < 2; tj++) {
    int n = n0 + wn * 32 + tj * 16 + c;
    float bias = biasA[n] + (biasB ? biasB[n] : 0.f);
#pragma unroll
    for (int ti = 0; ti < 2; ti++)
#pragma unroll
      for (int rr = 0; rr < 4; rr++) {
        int m = m0 + wm * 32 + ti * 16 + q * 4 + rr;
        float v = acc[ti][tj][rr] + bias;
        if (outbf) outbf[(size_t)m * N + n] = f2bf(v);
        else outf[(size_t)m * N + n] = v;
      }
  }
}

// ---------------------------------------------------------------------------
extern "C" void kernel_launch(void* const* d_in, const int* in_sizes, int n_in,
                              void* d_out, int out_size, void* d_ws, size_t ws_size,
                              hipStream_t stream) {
  const float* ib = (const float*)d_in[0];
  const float* qb = (const float*)d_in[1];
  const int* imask = (const int*)d_in[2];
  const int* qmask = (const int*)d_in[3];
  const float* lf_w1 = (const float*)d_in[4];
  const float* lf_b1 = (const float*)d_in[5];
  const float* lf_w2 = (const float*)d_in[6];
  const float* lf_wm = (const float*)d_in[8];
  const float* lf_bm = (const float*)d_in[9];
  const float* if_w1 = (const float*)d_in[10];
  const float* if_b1 = (const float*)d_in[11];
  const float* if_w2 = (const float*)d_in[12];
  const float* if_wm = (const float*)d_in[14];
  const float* if_bm = (const float*)d_in[15];
  const float* fh_w = (const float*)d_in[16];
  const float* fh_b = (const float*)d_in[17];
  float* out = (float*)d_out;  // [256*512] out, then [256*256] i_weight

  float* lp_i = (float*)d_ws;              // 262,144 (4 x 65536)
  float* lp_l = lp_i + 262144;             // 65,536 (4 x 16384)
  float* att_i = lp_l + 65536;             // 65,536
  float* att_l = att_i + 65536;            // 16,384
  float* psum = att_l + 16384;             // 131,072 (16384 x 8)
  unsigned short* P1 = (unsigned short*)(psum + 131072);  // 4,194,304
  unsigned short* P2 = P1 + 4194304;                      // 4,194,304
  unsigned short* ib_bf = P2 + 4194304;                   // 33,554,432 (ifeat alias)
  unsigned short* qb_bf = ib_bf + 33554432;               // 8,388,608 (lfeat alias)
  unsigned short* qbT = qb_bf + 8388608;                  // 8,388,608
  unsigned short* ibT = qbT + 8388608;                    // 33,554,432
  unsigned short* w1t_lf = ibT + 33554432;                // 262,144
  unsigned short* w1t_if = w1t_lf + 262144;               // 262,144
  unsigned short* wcat_t = w1t_if + 262144;               // 1,048,576
  unsigned short* fh_wt = wcat_t + 1048576;               // 524,288
  unsigned short* pooled_bf = fh_wt + 524288;             // 262,144
  unsigned short* F_bf = pooled_bf + 262144;              // 262,144
  unsigned short* ifeat = ib_bf;  // ib_bf dead after k_scores_f
  unsigned short* lfeat = qb_bf;  // qb_bf dead after k_scores_f

  k_prep<<<6656, 256, 0, stream>>>(ib, qb, lf_w1, if_w1, lf_wm, if_wm, fh_w,
                                   ib_bf, ibT, qb_bf, qbT, w1t_lf, w1t_if,
                                   wcat_t, fh_wt);

  k_scores_f<<<dim3(2, 256), 256, 0, stream>>>(ib_bf, qb_bf, imask, qmask, P1, P2, psum);
  k_av1<<<dim3(8, 256), 256, 0, stream>>>(P1, qbT, ifeat);
  k_av2<<<dim3(4, 256), 256, 0, stream>>>(P2, ibT, psum, lfeat);

  k_logits_part<<<2048, 256, 0, stream>>>(ifeat, w1t_lf, lf_b1, lf_w2, lp_i, 65536);
  k_logits_part<<<512, 256, 0, stream>>>(lfeat, w1t_if, if_b1, if_w2, lp_l, 16384);
  k_attsoft_i<<<256, 256, 0, stream>>>(lp_i, imask, att_i, out + 131072);
  k_attsoft_l<<<256, 64, 0, stream>>>(lp_l, qmask, att_l);
  k_pooled<<<256, 256, 0, stream>>>(ifeat, att_i, 256, pooled_bf, 0);
  k_pooled<<<256, 256, 0, stream>>>(lfeat, att_l, 64, pooled_bf, 512);

  k_egemm<<<dim3(16, 4), 256, 0, stream>>>(pooled_bf, wcat_t, lf_bm, if_bm,
                                           nullptr, F_bf, 1024, 1024);
  k_egemm<<<dim3(8, 4), 256, 0, stream>>>(F_bf, fh_wt, fh_b, nullptr,
                                          out, nullptr, 512, 1024);
}

// Round 3
// 416.922 us; speedup vs baseline: 1.1204x; 1.1204x over previous
//
#include <hip/hip_runtime.h>
#include <math.h>

// ---------------------------------------------------------------------------
// BiAttention round 9: i-side algebraic restructure.
//   ifeat = P1 @ qb was only consumed linearly:
//     logits_i pre-act = ifeat @ W1 = P1 @ (qb @ W1)
//     pooled_i = att_i^T @ ifeat = (att_i^T @ P1) @ qb
//   => never materialize ifeat. Removed: k_av1, big k_logits_part(i) (K=512,
//   268 MB logical ifeat re-reads), serial k_pooled(ifeat,256).
//   Added: k_qbw1 (qbW1T[b,512,64] = (qb@lf_w1)^T, k_av2-shaped),
//          k_logits_i64 (P1 @ qbW1T, K=64, fused relu*w2 epilogue),
//          k_attp (v = att_i^T @ P1, tiny), k_pooled(qb_bf, v, L=64).
//   qbT now dead -> k_prep qb path is a pure stream convert (-16.7 MB write).
//   lfeat re-aliased to ib_bf (qb_bf must stay live for qbw1/pooled).
//   k_prep R8 result: conflicts+occupancy fixed, dur flat -> traffic-bound;
//   this round cuts its bytes instead of its stalls.
// Fragment scheme (verified R2..R8): A/B frag row = lane&15, k-group
// (lane>>4)*8 contiguous, XOR swizzle (colgroup ^ (row&7));
// C/D: col = lane&15, row = (lane>>4)*4 + r.
// ---------------------------------------------------------------------------

#define SCALE 0.04419417382415922f  // 1/sqrt(512)

typedef __attribute__((ext_vector_type(8))) short short8;
typedef __attribute__((ext_vector_type(4))) float floatx4;

__device__ __forceinline__ unsigned short f2bf(float x) {
  unsigned u = __float_as_uint(x);
  unsigned r = u + 0x7FFFu + ((u >> 16) & 1u);
  return (unsigned short)(r >> 16);
}
__device__ __forceinline__ float bf2f(unsigned short h) {
  return __uint_as_float(((unsigned)h) << 16);
}
__device__ __forceinline__ unsigned pk2(float a, float b) {
  return (unsigned)f2bf(a) | ((unsigned)f2bf(b) << 16);
}

__device__ __forceinline__ float wave_max(float v) {
#pragma unroll
  for (int o = 32; o > 0; o >>= 1) v = fmaxf(v, __shfl_xor(v, o, 64));
  return v;
}
__device__ __forceinline__ float wave_sum(float v) {
#pragma unroll
  for (int o = 32; o > 0; o >>= 1) v += __shfl_xor(v, o, 64);
  return v;
}

#define GLD_LDS16(gptr, lptr)                                             \
  __builtin_amdgcn_global_load_lds(                                       \
      (const __attribute__((address_space(1))) void*)(gptr),              \
      (__attribute__((address_space(3))) void*)(lptr), 16, 0, 0)

// ---------------------------------------------------------------------------
// Merged prep: idx<512 weights; [512,4608) ib 64x128 tiles; [4608,6656) qb
// pure stream convert (qbT dead after k_av1 removal).
__global__ __launch_bounds__(256) void k_prep(
    const float* __restrict__ ib, const float* __restrict__ qb,
    const float* __restrict__ lf_w1, const float* __restrict__ if_w1,
    const float* __restrict__ lf_wm, const float* __restrict__ if_wm,
    const float* __restrict__ fh_w, unsigned short* __restrict__ ib_bf,
    unsigned short* __restrict__ ibT, unsigned short* __restrict__ qb_bf,
    unsigned short* __restrict__ w1t_lf, unsigned short* __restrict__ w1t_if,
    unsigned short* __restrict__ wcat_t, unsigned short* __restrict__ fh_wt) {
  __shared__ __align__(16) char smem[64 * 65 * 4];  // 16640 B
  const int idx = blockIdx.x, t = threadIdx.x;

  if (idx < 512) {
    // ---- weights: f32 [K,N] -> bf16 [N, koff+K] (stride 65: conflict-free)
    float(*T)[65] = (float(*)[65])smem;
    const float* src;
    unsigned short* dst;
    int N, ds, koff, k0, n0;
    if (idx < 64) {
      src = lf_w1; dst = w1t_lf; N = 512; ds = 512; koff = 0;
      k0 = (idx & 7) * 64; n0 = (idx >> 3) * 64;
    } else if (idx < 128) {
      int l = idx - 64;
      src = if_w1; dst = w1t_if; N = 512; ds = 512; koff = 0;
      k0 = (l & 7) * 64; n0 = (l >> 3) * 64;
    } else if (idx < 256) {
      int l = idx - 128;
      src = lf_wm; dst = wcat_t; N = 1024; ds = 1024; koff = 0;
      k0 = (l & 7) * 64; n0 = (l >> 3) * 64;
    } else if (idx < 384) {
      int l = idx - 256;
      src = if_wm; dst = wcat_t; N = 1024; ds = 1024; koff = 512;
      k0 = (l & 7) * 64; n0 = (l >> 3) * 64;
    } else {
      int l = idx - 384;
      src = fh_w; dst = fh_wt; N = 512; ds = 1024; koff = 0;
      k0 = (l & 15) * 64; n0 = (l >> 4) * 64;
    }
#pragma unroll
    for (int i = 0; i < 16; i++) {
      int e = t + i * 256, r = e >> 6, c = e & 63;
      T[r][c] = src[(size_t)(k0 + r) * N + n0 + c];
    }
    __syncthreads();
#pragma unroll
    for (int i = 0; i < 8; i++) {
      int e = t + i * 256, r = e >> 5, c2 = (e & 31) * 2;
      *(unsigned*)&dst[(size_t)(n0 + r) * ds + koff + k0 + c2] =
          pk2(T[c2][r], T[c2 + 1][r]);
    }
  } else if (idx < 4608) {
    // ---- ib 64tok x 128h tiles, swizzled [64][128] bf16 (16 KB) ----
    int j = idx - 512;
    int b = j >> 4, tok0 = ((j >> 2) & 3) * 64, h0 = (j & 3) * 128;
    unsigned short* Tb = (unsigned short*)smem;  // [64][128] swizzled
    const float* src = ib + ((size_t)b * 256 + tok0) * 512 + h0;
#pragma unroll
    for (int i = 0; i < 8; i++) {
      int e = t + i * 256, tok = e >> 5, h4 = (e & 31) * 4;
      float4 v = *(const float4*)&src[(size_t)tok * 512 + h4];
      uint2 p;
      p.x = pk2(v.x, v.y);
      p.y = pk2(v.z, v.w);
      int col = ((((h4 >> 3) ^ (tok >> 3)) & 15) << 3) | (h4 & 7);
      *(uint2*)&Tb[tok * 128 + col] = p;
    }
    __syncthreads();
    unsigned short* dbf = ib_bf + ((size_t)b * 256 + tok0) * 512 + h0;
#pragma unroll
    for (int i = 0; i < 4; i++) {
      int e = t + i * 256, tok = e >> 4, g = e & 15;
      int sg = (g ^ (tok >> 3)) & 15;
      *(uint4*)&dbf[(size_t)tok * 512 + g * 8] = *(const uint4*)&Tb[tok * 128 + sg * 8];
    }
    unsigned short* dT = ibT + ((size_t)b * 512 + h0) * 256 + tok0;
#pragma unroll
    for (int i = 0; i < 4; i++) {
      int e = t + i * 256, h = e >> 3, tc = (e & 7) * 8;
      int hg = h >> 3, ho = h & 7;
      unsigned y[8];
#pragma unroll
      for (int k = 0; k < 8; k++) {
        int r = tc + k;
        y[k] = Tb[r * 128 + (((hg ^ (r >> 3)) & 15) << 3) + ho];
      }
      uint4 v;
      v.x = y[0] | (y[1] << 16);
      v.y = y[2] | (y[3] << 16);
      v.z = y[4] | (y[5] << 16);
      v.w = y[6] | (y[7] << 16);
      *(uint4*)&dT[(size_t)h * 256 + tc] = v;
    }
  } else {
    // ---- qb f32 -> bf16 pure stream (no transpose needed anymore) ----
    int j = idx - 4608;  // 2048 blocks x 4096 floats
    const float4* src = (const float4*)(qb + (size_t)j * 4096);
    uint2* dst = (uint2*)(qb_bf + (size_t)j * 4096);
#pragma unroll
    for (int i = 0; i < 4; i++) {
      int e = t + i * 256;
      float4 v = src[e];
      uint2 p;
      p.x = pk2(v.x, v.y);
      p.y = pk2(v.z, v.w);
      dst[e] = p;
    }
  }
}

// ---------------------------------------------------------------------------
// Fused scores: per (i-chunk, batch). S[64q x 128i] = qb @ ib^T * SCALE.
// Emits P1[b,i,q] normalized bf16 (softmax over q, qmask) and P2[b,q,i] raw
// exp bf16 (imask; unnormalized) + psum[b*64+q][8] per-wave partial row sums.
__global__ __launch_bounds__(256) void k_scores_f(
    const unsigned short* __restrict__ ibf, const unsigned short* __restrict__ qbf,
    const int* __restrict__ imask, const int* __restrict__ qmask,
    unsigned short* __restrict__ P1, unsigned short* __restrict__ P2,
    float* __restrict__ psum) {
  __shared__ unsigned short As[64 * 64];
  __shared__ unsigned short Bs[128 * 64];
  __shared__ __align__(16) unsigned short X[128 * 72];  // E:[64][136] / Pl:[128][72]
  const int b = blockIdx.y, ic = blockIdx.x, i0 = ic * 128;
  const int t = threadIdx.x, w = t >> 6, lane = t & 63, c = lane & 15, qq = lane >> 4;

  floatx4 acc[4][2];
#pragma unroll
  for (int ti = 0; ti < 4; ti++)
#pragma unroll
    for (int tj = 0; tj < 2; tj++) acc[ti][tj] = (floatx4){0.f, 0.f, 0.f, 0.f};

  for (int k0 = 0; k0 < 512; k0 += 64) {
#pragma unroll
    for (int i = 0; i < 2; i++) {
      int s = i * 256 + t, row = s >> 3, src = (s & 7) ^ (row & 7);
      GLD_LDS16(qbf + ((size_t)b * 64 + row) * 512 + k0 + src * 8,
                &As[(i * 256 + w * 64) * 8]);
    }
#pragma unroll
    for (int i = 0; i < 4; i++) {
      int s = i * 256 + t, row = s >> 3, src = (s & 7) ^ (row & 7);
      GLD_LDS16(ibf + ((size_t)b * 256 + i0 + row) * 512 + k0 + src * 8,
                &Bs[(i * 256 + w * 64) * 8]);
    }
    __syncthreads();
#pragma unroll
    for (int kk = 0; kk < 2; kk++) {
      short8 a[4], bb[2];
#pragma unroll
      for (int ti = 0; ti < 4; ti++)
        a[ti] = *(const short8*)&As[(ti * 16 + c) * 64 + ((kk * 4 + qq) ^ (c & 7)) * 8];
#pragma unroll
      for (int tj = 0; tj < 2; tj++)
        bb[tj] = *(const short8*)&Bs[(w * 32 + tj * 16 + c) * 64 + ((kk * 4 + qq) ^ (c & 7)) * 8];
#pragma unroll
      for (int ti = 0; ti < 4; ti++)
#pragma unroll
        for (int tj = 0; tj < 2; tj++)
          acc[ti][tj] = __builtin_amdgcn_mfma_f32_16x16x32_bf16(a[ti], bb[tj], acc[ti][tj], 0, 0, 0);
    }
    __syncthreads();
  }

  const int il0 = w * 32 + c;  // tj=0 local i; tj=1 is il0+16
  int imsk0 = imask[b * 256 + i0 + il0];
  int imsk1 = imask[b * 256 + i0 + il0 + 16];
  int qm[4][4];
#pragma unroll
  for (int ti = 0; ti < 4; ti++)
#pragma unroll
    for (int rr = 0; rr < 4; rr++) qm[ti][rr] = qmask[b * 64 + ti * 16 + qq * 4 + rr];

  // ---- E phase: raw exp (imask) into X[64][136], per-wave row sums ----
#pragma unroll
  for (int ti = 0; ti < 4; ti++)
#pragma unroll
    for (int rr = 0; rr < 4; rr++) {
      int qv = ti * 16 + qq * 4 + rr;
      float e0 = imsk0 ? 0.f : __expf(acc[ti][0][rr] * SCALE);
      float e1 = imsk1 ? 0.f : __expf(acc[ti][1][rr] * SCALE);
      X[qv * 136 + il0] = f2bf(e0);
      X[qv * 136 + il0 + 16] = f2bf(e1);
      float s = e0 + e1;
#pragma unroll
      for (int o = 1; o <= 8; o <<= 1) s += __shfl_xor(s, o, 64);
      if (c == 0) psum[((size_t)(b * 64 + qv)) * 8 + ic * 4 + w] = s;
    }
  __syncthreads();
#pragma unroll
  for (int i = 0; i < 4; i++) {
    int e2 = t + i * 256, qv = e2 >> 4, g = e2 & 15;
    *(uint4*)&P2[((size_t)b * 64 + qv) * 256 + i0 + g * 8] = *(const uint4*)&X[qv * 136 + g * 8];
  }
  __syncthreads();

  // ---- P1 phase: column softmax over q (qmask), normalized, into X[128][72]
#pragma unroll
  for (int tj = 0; tj < 2; tj++) {
    float ev[4][4];
    float s1 = 0.f;
#pragma unroll
    for (int ti = 0; ti < 4; ti++)
#pragma unroll
      for (int rr = 0; rr < 4; rr++) {
        ev[ti][rr] = qm[ti][rr] ? 0.f : __expf(acc[ti][tj][rr] * SCALE);
        s1 += ev[ti][rr];
      }
    s1 += __shfl_xor(s1, 16, 64);
    s1 += __shfl_xor(s1, 32, 64);
    float inv = 1.f / s1;
    int il = il0 + tj * 16;
#pragma unroll
    for (int ti = 0; ti < 4; ti++)
#pragma unroll
      for (int rr = 0; rr < 4; rr++)
        X[il * 72 + ti * 16 + qq * 4 + rr] = f2bf(ev[ti][rr] * inv);
  }
  __syncthreads();
#pragma unroll
  for (int i = 0; i < 4; i++) {
    int e2 = t + i * 256, il = e2 >> 3, g = e2 & 7;
    *(uint4*)&P1[((size_t)b * 256 + i0 + il) * 64 + g * 8] = *(const uint4*)&X[il * 72 + g * 8];
  }
}

// ---------------------------------------------------------------------------
// lfeat[b,64,512] = (P2 @ ib) * rowscale ; B from ibT (bf16 [512][256]).
// K=256, 4 chunks. Row scale 1/sum(psum[row][0..7]) folded into epilogue.
__global__ __launch_bounds__(256) void k_av2(const unsigned short* __restrict__ P2,
                                             const unsigned short* __restrict__ ibT,
                                             const float* __restrict__ psum,
                                             unsigned short* __restrict__ lfeat) {
  __shared__ unsigned short As[64 * 64];
  __shared__ unsigned short Bs[128 * 64];
  const int b = blockIdx.y, n0 = blockIdx.x * 128;
  const int t = threadIdx.x, w = t >> 6, lane = t & 63, c = lane & 15, q = lane >> 4;
  const int wm = w >> 1, wn = w & 1;
  floatx4 acc[2][4];
#pragma unroll
  for (int ti = 0; ti < 2; ti++)
#pragma unroll
    for (int tj = 0; tj < 4; tj++) acc[ti][tj] = (floatx4){0.f, 0.f, 0.f, 0.f};

  for (int kc = 0; kc < 256; kc += 64) {
#pragma unroll
    for (int i = 0; i < 2; i++) {
      int s = i * 256 + t, row = s >> 3, src = (s & 7) ^ (row & 7);
      GLD_LDS16(P2 + ((size_t)b * 64 + row) * 256 + kc + src * 8, &As[(i * 256 + w * 64) * 8]);
    }
#pragma unroll
    for (int i = 0; i < 4; i++) {
      int s = i * 256 + t, row = s >> 3, src = (s & 7) ^ (row & 7);
      GLD_LDS16(ibT + ((size_t)b * 512 + n0 + row) * 256 + kc + src * 8,
                &Bs[(i * 256 + w * 64) * 8]);
    }
    __syncthreads();
#pragma unroll
    for (int kk = 0; kk < 2; kk++) {
      short8 a[2], bb[4];
#pragma unroll
      for (int ti = 0; ti < 2; ti++)
        a[ti] = *(const short8*)&As[(wm * 32 + ti * 16 + c) * 64 + ((kk * 4 + q) ^ (c & 7)) * 8];
#pragma unroll
      for (int tj = 0; tj < 4; tj++)
        bb[tj] = *(const short8*)&Bs[(wn * 64 + tj * 16 + c) * 64 + ((kk * 4 + q) ^ (c & 7)) * 8];
#pragma unroll
      for (int ti = 0; ti < 2; ti++)
#pragma unroll
        for (int tj = 0; tj < 4; tj++)
          acc[ti][tj] = __builtin_amdgcn_mfma_f32_16x16x32_bf16(a[ti], bb[tj], acc[ti][tj], 0, 0, 0);
    }
    __syncthreads();
  }
#pragma unroll
  for (int ti = 0; ti < 2; ti++)
#pragma unroll
    for (int rr = 0; rr < 4; rr++) {
      int m = wm * 32 + ti * 16 + q * 4 + rr;
      const float* ps = psum + ((size_t)(b * 64 + m)) * 8;
      float s = ps[0] + ps[1] + ps[2] + ps[3] + ps[4] + ps[5] + ps[6] + ps[7];
      float inv = 1.f / s;
      unsigned short* op = lfeat + ((size_t)b * 64 + m) * 512 + n0 + wn * 64;
#pragma unroll
      for (int tj = 0; tj < 4; tj++) op[tj * 16 + c] = f2bf(acc[ti][tj][rr] * inv);
    }
}

// ---------------------------------------------------------------------------
// qbW1T[b,512n,64q] = (qb_bf[b] @ lf_w1)^T, bf16. A=qb_bf [64][512],
// B=w1t_lf [512n][512k]. K=512, M=64, N=128/block. k_av2-shaped.
__global__ __launch_bounds__(256) void k_qbw1(const unsigned short* __restrict__ qbf,
                                              const unsigned short* __restrict__ W1t,
                                              unsigned short* __restrict__ qbW1T) {
  __shared__ unsigned short As[64 * 64];
  __shared__ unsigned short Bs[128 * 64];
  const int b = blockIdx.y, n0 = blockIdx.x * 128;
  const int t = threadIdx.x, w = t >> 6, lane = t & 63, c = lane & 15, q = lane >> 4;
  const int wm = w >> 1, wn = w & 1;
  floatx4 acc[2][4];
#pragma unroll
  for (int ti = 0; ti < 2; ti++)
#pragma unroll
    for (int tj = 0; tj < 4; tj++) acc[ti][tj] = (floatx4){0.f, 0.f, 0.f, 0.f};

  for (int k0 = 0; k0 < 512; k0 += 64) {
#pragma unroll
    for (int i = 0; i < 2; i++) {
      int s = i * 256 + t, row = s >> 3, src = (s & 7) ^ (row & 7);
      GLD_LDS16(qbf + ((size_t)b * 64 + row) * 512 + k0 + src * 8,
                &As[(i * 256 + w * 64) * 8]);
    }
#pragma unroll
    for (int i = 0; i < 4; i++) {
      int s = i * 256 + t, row = s >> 3, src = (s & 7) ^ (row & 7);
      GLD_LDS16(W1t + (size_t)(n0 + row) * 512 + k0 + src * 8,
                &Bs[(i * 256 + w * 64) * 8]);
    }
    __syncthreads();
#pragma unroll
    for (int kk = 0; kk < 2; kk++) {
      short8 a[2], bb[4];
#pragma unroll
      for (int ti = 0; ti < 2; ti++)
        a[ti] = *(const short8*)&As[(wm * 32 + ti * 16 + c) * 64 + ((kk * 4 + q) ^ (c & 7)) * 8];
#pragma unroll
      for (int tj = 0; tj < 4; tj++)
        bb[tj] = *(const short8*)&Bs[(wn * 64 + tj * 16 + c) * 64 + ((kk * 4 + q) ^ (c & 7)) * 8];
#pragma unroll
      for (int ti = 0; ti < 2; ti++)
#pragma unroll
        for (int tj = 0; tj < 4; tj++)
          acc[ti][tj] = __builtin_amdgcn_mfma_f32_16x16x32_bf16(a[ti], bb[tj], acc[ti][tj], 0, 0, 0);
    }
    __syncthreads();
  }
  // Transposed store: qbW1T[(b*512 + n)*64 + m], m = q-row. 8B per (ti,tj).
#pragma unroll
  for (int ti = 0; ti < 2; ti++)
#pragma unroll
    for (int tj = 0; tj < 4; tj++) {
      int n = n0 + wn * 64 + tj * 16 + c;
      int m = wm * 32 + ti * 16 + q * 4;
      uint2 p;
      p.x = pk2(acc[ti][tj][0], acc[ti][tj][1]);
      p.y = pk2(acc[ti][tj][2], acc[ti][tj][3]);
      *(uint2*)&qbW1T[((size_t)b * 512 + n) * 64 + m] = p;
    }
}

// ---------------------------------------------------------------------------
// lp_i partials: A = P1[b,256,64] (normalized), B = qbW1T[b,512,64]. K=64.
// acc = P1 @ qbW1T^T = ifeat @ W1 exactly (associativity). Epilogue fuses
// relu(acc + b1)*w2 row-sum over the block's 128 n -> outp[nc*65536 + row].
__global__ __launch_bounds__(256) void k_logits_i64(
    const unsigned short* __restrict__ P1, const unsigned short* __restrict__ qbW1T,
    const float* __restrict__ b1, const float* __restrict__ w2,
    float* __restrict__ outp) {
  __shared__ unsigned short As[128 * 64];
  __shared__ unsigned short Bs[128 * 64];
  __shared__ float red[2][128];
  const int b = blockIdx.y;
  const int mt = blockIdx.x & 1, nc = blockIdx.x >> 1;
  const int m0 = mt * 128, n0 = nc * 128;
  const int t = threadIdx.x, w = t >> 6, lane = t & 63, c = lane & 15, q = lane >> 4;
  const int wm = w >> 1, wn = w & 1;

#pragma unroll
  for (int i = 0; i < 4; i++) {
    int s = i * 256 + t, row = s >> 3, src = (s & 7) ^ (row & 7);
    GLD_LDS16(P1 + ((size_t)b * 256 + m0 + row) * 64 + src * 8, &As[(i * 256 + w * 64) * 8]);
  }
#pragma unroll
  for (int i = 0; i < 4; i++) {
    int s = i * 256 + t, row = s >> 3, src = (s & 7) ^ (row & 7);
    GLD_LDS16(qbW1T + ((size_t)b * 512 + n0 + row) * 64 + src * 8, &Bs[(i * 256 + w * 64) * 8]);
  }
  __syncthreads();
  floatx4 acc[4][4];
#pragma unroll
  for (int ti = 0; ti < 4; ti++)
#pragma unroll
    for (int tj = 0; tj < 4; tj++) acc[ti][tj] = (floatx4){0.f, 0.f, 0.f, 0.f};
#pragma unroll
  for (int kk = 0; kk < 2; kk++) {
    short8 a[4], bb[4];
#pragma unroll
    for (int ti = 0; ti < 4; ti++)
      a[ti] = *(const short8*)&As[(wm * 64 + ti * 16 + c) * 64 + ((kk * 4 + q) ^ (c & 7)) * 8];
#pragma unroll
    for (int tj = 0; tj < 4; tj++)
      bb[tj] = *(const short8*)&Bs[(wn * 64 + tj * 16 + c) * 64 + ((kk * 4 + q) ^ (c & 7)) * 8];
#pragma unroll
    for (int ti = 0; ti < 4; ti++)
#pragma unroll
      for (int tj = 0; tj < 4; tj++)
        acc[ti][tj] = __builtin_amdgcn_mfma_f32_16x16x32_bf16(a[ti], bb[tj], acc[ti][tj], 0, 0, 0);
  }

  float partial[4][4] = {};
#pragma unroll
  for (int tj = 0; tj < 4; tj++) {
    int n = n0 + wn * 64 + tj * 16 + c;
    float bia = b1[n], wwv = w2[n];
#pragma unroll
    for (int ti = 0; ti < 4; ti++)
#pragma unroll
      for (int r = 0; r < 4; r++)
        partial[ti][r] += fmaxf(acc[ti][tj][r] + bia, 0.f) * wwv;
  }
#pragma unroll
  for (int msk = 1; msk <= 8; msk <<= 1)
#pragma unroll
    for (int ti = 0; ti < 4; ti++)
#pragma unroll
      for (int r = 0; r < 4; r++)
        partial[ti][r] += __shfl_xor(partial[ti][r], msk, 64);
  if (c == 0) {
#pragma unroll
    for (int ti = 0; ti < 4; ti++)
#pragma unroll
      for (int r = 0; r < 4; r++)
        red[wn][wm * 64 + ti * 16 + q * 4 + r] = partial[ti][r];
  }
  __syncthreads();
  if (t < 128) outp[(size_t)nc * 65536 + b * 256 + m0 + t] = red[0][t] + red[1][t];
}

// ---------------------------------------------------------------------------
// Partial logits (l-side): outp[nc*M + m] = sum over n-chunk nc of
// relu(X@W1+b1)*w2.
__global__ __launch_bounds__(256) void k_logits_part(
    const unsigned short* __restrict__ X, const unsigned short* __restrict__ W1t,
    const float* __restrict__ b1, const float* __restrict__ w2,
    float* __restrict__ outp, int M) {
  __shared__ unsigned short As[128 * 64];
  __shared__ unsigned short Bs[128 * 64];
  __shared__ float red[2][128];
  const int t = threadIdx.x, w = t >> 6, lane = t & 63;
  const int wm = w >> 1, wn = w & 1, c = lane & 15, q = lane >> 4;
  const int idx = blockIdx.x;
  const int m_tile = (idx & 7) + ((idx >> 5) << 3), nc = (idx >> 3) & 3;
  const int m0 = m_tile * 128, n0 = nc * 128;

  floatx4 acc[4][4];
#pragma unroll
  for (int ti = 0; ti < 4; ti++)
#pragma unroll
    for (int tj = 0; tj < 4; tj++) acc[ti][tj] = (floatx4){0.f, 0.f, 0.f, 0.f};

  for (int k0 = 0; k0 < 512; k0 += 64) {
#pragma unroll
    for (int it = 0; it < 4; it++) {
      int s = it * 256 + t, row = s >> 3, src = (s & 7) ^ (row & 7);
      GLD_LDS16(X + (size_t)(m0 + row) * 512 + k0 + src * 8, &As[(it * 256 + w * 64) * 8]);
      GLD_LDS16(W1t + (size_t)(n0 + row) * 512 + k0 + src * 8, &Bs[(it * 256 + w * 64) * 8]);
    }
    __syncthreads();
#pragma unroll
    for (int kk = 0; kk < 2; kk++) {
      short8 a[4], bb[4];
#pragma unroll
      for (int ti = 0; ti < 4; ti++)
        a[ti] = *(const short8*)&As[(wm * 64 + ti * 16 + c) * 64 + ((kk * 4 + q) ^ (c & 7)) * 8];
#pragma unroll
      for (int tj = 0; tj < 4; tj++)
        bb[tj] = *(const short8*)&Bs[(wn * 64 + tj * 16 + c) * 64 + ((kk * 4 + q) ^ (c & 7)) * 8];
#pragma unroll
      for (int ti = 0; ti < 4; ti++)
#pragma unroll
        for (int tj = 0; tj < 4; tj++)
          acc[ti][tj] = __builtin_amdgcn_mfma_f32_16x16x32_bf16(a[ti], bb[tj], acc[ti][tj], 0, 0, 0);
    }
    __syncthreads();
  }
  float partial[4][4] = {};
#pragma unroll
  for (int tj = 0; tj < 4; tj++) {
    int n = n0 + wn * 64 + tj * 16 + c;
    float bia = b1[n], wwv = w2[n];
#pragma unroll
    for (int ti = 0; ti < 4; ti++)
#pragma unroll
      for (int r = 0; r < 4; r++)
        partial[ti][r] += fmaxf(acc[ti][tj][r] + bia, 0.f) * wwv;
  }
#pragma unroll
  for (int msk = 1; msk <= 8; msk <<= 1)
#pragma unroll
    for (int ti = 0; ti < 4; ti++)
#pragma unroll
      for (int r = 0; r < 4; r++)
        partial[ti][r] += __shfl_xor(partial[ti][r], msk, 64);
  if (c == 0) {
#pragma unroll
    for (int ti = 0; ti < 4; ti++)
#pragma unroll
      for (int r = 0; r < 4; r++)
        red[wn][wm * 64 + ti * 16 + q * 4 + r] = partial[ti][r];
  }
  __syncthreads();
  if (t < 128) outp[(size_t)nc * M + m0 + t] = red[0][t] + red[1][t];
}

// ---------------------------------------------------------------------------
__global__ __launch_bounds__(256) void k_attsoft_i(const float* __restrict__ lp,
                                                   const int* __restrict__ imask,
                                                   float* __restrict__ att,
                                                   float* __restrict__ iw_out) {
  __shared__ float red[4];
  const int b = blockIdx.x, t = threadIdx.x;
  const int i = b * 256 + t;
  float x = lp[i] + lp[65536 + i] + lp[131072 + i] + lp[196608 + i];
  float v = imask[i] ? -1e9f : x;
  float wm = wave_max(v);
  if ((t & 63) == 0) red[t >> 6] = wm;
  __syncthreads();
  float mx = fmaxf(fmaxf(red[0], red[1]), fmaxf(red[2], red[3]));
  __syncthreads();
  float e = __expf(v - mx);
  float wsum = wave_sum(e);
  if ((t & 63) == 0) red[t >> 6] = wsum;
  __syncthreads();
  float s = red[0] + red[1] + red[2] + red[3];
  float p = e / s;
  att[i] = p;
  iw_out[i] = p;
}

__global__ __launch_bounds__(64) void k_attsoft_l(const float* __restrict__ lp,
                                                  const int* __restrict__ qmask,
                                                  float* __restrict__ att) {
  const int b = blockIdx.x, t = threadIdx.x;
  const int i = b * 64 + t;
  float x = lp[i] + lp[16384 + i] + lp[32768 + i] + lp[49152 + i];
  float v = qmask[i] ? -1e9f : x;
  float mx = wave_max(v);
  float e = __expf(v - mx);
  float s = wave_sum(e);
  att[i] = e / s;
}

// ---------------------------------------------------------------------------
// v[b,64] = att_i[b,256]^T @ P1[b,256,64]  (f32 out).
__global__ __launch_bounds__(256) void k_attp(const float* __restrict__ att,
                                              const unsigned short* __restrict__ P1,
                                              float* __restrict__ v) {
  __shared__ float av[256];
  __shared__ float red[4][64];
  const int b = blockIdx.x, t = threadIdx.x;
  const int part = t >> 6, lane = t & 63;
  av[t] = att[b * 256 + t];
  __syncthreads();
  const unsigned short* Pb = P1 + ((size_t)b * 256 + part * 64) * 64 + lane;
  float s0 = 0.f, s1 = 0.f;
#pragma unroll 8
  for (int ii = 0; ii < 64; ii += 2) {
    s0 += av[part * 64 + ii] * bf2f(Pb[(size_t)ii * 64]);
    s1 += av[part * 64 + ii + 1] * bf2f(Pb[(size_t)(ii + 1) * 64]);
  }
  red[part][lane] = s0 + s1;
  __syncthreads();
  if (t < 64) v[b * 64 + t] = red[0][t] + red[1][t] + red[2][t] + red[3][t];
}

// pooled_bf[b*1024 + ooff + h] = sum_l att[b,l] * X[b,l,h]
__global__ __launch_bounds__(256) void k_pooled(const unsigned short* __restrict__ X,
                                                const float* __restrict__ att, int L,
                                                unsigned short* __restrict__ out,
                                                int ooff) {
  __shared__ float ar[256];
  const int b = blockIdx.x, t = threadIdx.x;
  if (t < L) ar[t] = att[b * L + t];
  __syncthreads();
  float a0 = 0.f, a1 = 0.f;
  const unsigned short* Xb = X + (size_t)b * L * 512 + 2 * t;
#pragma unroll 4
  for (int l = 0; l < L; l++) {
    unsigned u = *(const unsigned*)&Xb[(size_t)l * 512];
    float a = ar[l];
    a0 += a * bf2f((unsigned short)(u & 0xffff));
    a1 += a * bf2f((unsigned short)(u >> 16));
  }
  *(unsigned*)&out[(size_t)b * 1024 + ooff + 2 * t] = pk2(a0, a1);
}

// ---------------------------------------------------------------------------
// Epilogue GEMM: out[M,N] = X[M,K]bf16 @ Wt[N,K]bf16 + biasA (+biasB).
__global__ __launch_bounds__(256) void k_egemm(const unsigned short* __restrict__ X,
                                               const unsigned short* __restrict__ Wt,
                                               const float* __restrict__ biasA,
                                               const float* __restrict__ biasB,
                                               float* __restrict__ outf,
                                               unsigned short* __restrict__ outbf,
                                               int N, int K) {
  __shared__ unsigned short As[64 * 64];
  __shared__ unsigned short Bs[64 * 64];
  const int n0 = blockIdx.x * 64, m0 = blockIdx.y * 64;
  const int t = threadIdx.x, w = t >> 6, lane = t & 63, c = lane & 15, q = lane >> 4;
  const int wm = w >> 1, wn = w & 1;
  floatx4 acc[2][2];
#pragma unroll
  for (int ti = 0; ti < 2; ti++)
#pragma unroll
    for (int tj = 0; tj < 2; tj++) acc[ti][tj] = (floatx4){0.f, 0.f, 0.f, 0.f};

  for (int k0 = 0; k0 < K; k0 += 64) {
#pragma unroll
    for (int i = 0; i < 2; i++) {
      int s = i * 256 + t, row = s >> 3, src = (s & 7) ^ (row & 7);
      GLD_LDS16(X + (size_t)(m0 + row) * K + k0 + src * 8, &As[(i * 256 + w * 64) * 8]);
      GLD_LDS16(Wt + (size_t)(n0 + row) * K + k0 + src * 8, &Bs[(i * 256 + w * 64) * 8]);
    }
    __syncthreads();
#pragma unroll
    for (int kk = 0; kk < 2; kk++) {
      short8 a[2], bb[2];
#pragma unroll
      for (int ti = 0; ti < 2; ti++)
        a[ti] = *(const short8*)&As[(wm * 32 + ti * 16 + c) * 64 + ((kk * 4 + q) ^ (c & 7)) * 8];
#pragma unroll
      for (int tj = 0; tj < 2; tj++)
        bb[tj] = *(const short8*)&Bs[(wn * 32 + tj * 16 + c) * 64 + ((kk * 4 + q) ^ (c & 7)) * 8];
#pragma unroll
      for (int ti = 0; ti < 2; ti++)
#pragma unroll
        for (int tj = 0; tj < 2; tj++)
          acc[ti][tj] = __builtin_amdgcn_mfma_f32_16x16x32_bf16(a[ti], bb[tj], acc[ti][tj], 0, 0, 0);
    }
    __syncthreads();
  }
#pragma unroll
  for (int tj = 0; tj < 2; tj++) {
    int n = n0 + wn * 32 + tj * 16 + c;
    float bias = biasA[n] + (biasB ? biasB[n] : 0.f);
#pragma unroll
    for (int ti = 0; ti < 2; ti++)
#pragma unroll
      for (int rr = 0; rr < 4; rr++) {
        int m = m0 + wm * 32 + ti * 16 + q * 4 + rr;
        float v = acc[ti][tj][rr] + bias;
        if (outbf) outbf[(size_t)m * N + n] = f2bf(v);
        else outf[(size_t)m * N + n] = v;
      }
  }
}

// ---------------------------------------------------------------------------
extern "C" void kernel_launch(void* const* d_in, const int* in_sizes, int n_in,
                              void* d_out, int out_size, void* d_ws, size_t ws_size,
                              hipStream_t stream) {
  const float* ib = (const float*)d_in[0];
  const float* qb = (const float*)d_in[1];
  const int* imask = (const int*)d_in[2];
  const int* qmask = (const int*)d_in[3];
  const float* lf_w1 = (const float*)d_in[4];
  const float* lf_b1 = (const float*)d_in[5];
  const float* lf_w2 = (const float*)d_in[6];
  const float* lf_wm = (const float*)d_in[8];
  const float* lf_bm = (const float*)d_in[9];
  const float* if_w1 = (const float*)d_in[10];
  const float* if_b1 = (const float*)d_in[11];
  const float* if_w2 = (const float*)d_in[12];
  const float* if_wm = (const float*)d_in[14];
  const float* if_bm = (const float*)d_in[15];
  const float* fh_w = (const float*)d_in[16];
  const float* fh_b = (const float*)d_in[17];
  float* out = (float*)d_out;  // [256*512] out, then [256*256] i_weight

  float* lp_i = (float*)d_ws;              // 262,144 (4 x 65536)
  float* lp_l = lp_i + 262144;             // 65,536 (4 x 16384)
  float* att_i = lp_l + 65536;             // 65,536
  float* att_l = att_i + 65536;            // 16,384
  float* psum = att_l + 16384;             // 131,072 (16384 x 8; v_i reuses)
  unsigned short* P1 = (unsigned short*)(psum + 131072);  // 4,194,304
  unsigned short* P2 = P1 + 4194304;                      // 4,194,304
  unsigned short* ib_bf = P2 + 4194304;                   // 33,554,432 (lfeat alias)
  unsigned short* qb_bf = ib_bf + 33554432;               // 8,388,608 (stays live!)
  unsigned short* qbW1T = qb_bf + 8388608;                // 8,388,608 (was qbT slot)
  unsigned short* ibT = qbW1T + 8388608;                  // 33,554,432
  unsigned short* w1t_lf = ibT + 33554432;                // 262,144
  unsigned short* w1t_if = w1t_lf + 262144;               // 262,144
  unsigned short* wcat_t = w1t_if + 262144;               // 1,048,576
  unsigned short* fh_wt = wcat_t + 1048576;               // 524,288
  unsigned short* pooled_bf = fh_wt + 524288;             // 262,144
  unsigned short* F_bf = pooled_bf + 262144;              // 262,144
  unsigned short* lfeat = ib_bf;  // ib_bf dead after k_scores_f
  float* v_i = psum;              // psum dead after k_av2

  k_prep<<<6656, 256, 0, stream>>>(ib, qb, lf_w1, if_w1, lf_wm, if_wm, fh_w,
                                   ib_bf, ibT, qb_bf, w1t_lf, w1t_if,
                                   wcat_t, fh_wt);

  k_scores_f<<<dim3(2, 256), 256, 0, stream>>>(ib_bf, qb_bf, imask, qmask, P1, P2, psum);
  k_av2<<<dim3(4, 256), 256, 0, stream>>>(P2, ibT, psum, lfeat);
  k_qbw1<<<dim3(4, 256), 256, 0, stream>>>(qb_bf, w1t_lf, qbW1T);
  k_logits_i64<<<dim3(8, 256), 256, 0, stream>>>(P1, qbW1T, lf_b1, lf_w2, lp_i);
  k_logits_part<<<512, 256, 0, stream>>>(lfeat, w1t_if, if_b1, if_w2, lp_l, 16384);
  k_attsoft_i<<<256, 256, 0, stream>>>(lp_i, imask, att_i, out + 131072);
  k_attsoft_l<<<256, 64, 0, stream>>>(lp_l, qmask, att_l);
  k_attp<<<256, 256, 0, stream>>>(att_i, P1, v_i);
  k_pooled<<<256, 256, 0, stream>>>(qb_bf, v_i, 64, pooled_bf, 0);
  k_pooled<<<256, 256, 0, stream>>>(lfeat, att_l, 64, pooled_bf, 512);

  k_egemm<<<dim3(16, 4), 256, 0, stream>>>(pooled_bf, wcat_t, lf_bm, if_bm,
                                           nullptr, F_bf, 1024, 1024);
  k_egemm<<<dim3(8, 4), 256, 0, stream>>>(F_bf, fh_wt, fh_b, nullptr,
                                          out, nullptr, 512, 1024);
}

// Round 4
// 416.163 us; speedup vs baseline: 1.1225x; 1.0018x over previous
//
#include <hip/hip_runtime.h>
#include <math.h>

// ---------------------------------------------------------------------------
// BiAttention round 10:
//  - ib_bf eliminated: k_scores_f stages its B operand directly from f32 ib
//    (native [i][h] layout = exactly what scores needs), converting inline
//    (float4 -> pk2 -> ds_write_b64, same fragment XOR swizzle). k_prep's ib
//    path now produces ONLY ibT (-67 MB HBM writes; R9 showed k_prep is
//    pure-traffic-bound at 2.7 TB/s, so bytes ~= time).
//  - epilogue fusion: attsoft_i+attp+pooled(i) -> k_final_i;
//    attsoft_l+pooled(l) -> k_final_l. 13 -> 10 launches; att_i/att_l/v_i
//    stay in LDS (i_weight global output kept).
//  - everything else identical to verified R9.
// Fragment scheme (verified R2..R9): A/B frag row = lane&15, k-group
// (lane>>4)*8 contiguous, XOR swizzle (colgroup ^ (row&7));
// C/D: col = lane&15, row = (lane>>4)*4 + r.
// ---------------------------------------------------------------------------

#define SCALE 0.04419417382415922f  // 1/sqrt(512)

typedef __attribute__((ext_vector_type(8))) short short8;
typedef __attribute__((ext_vector_type(4))) float floatx4;

__device__ __forceinline__ unsigned short f2bf(float x) {
  unsigned u = __float_as_uint(x);
  unsigned r = u + 0x7FFFu + ((u >> 16) & 1u);
  return (unsigned short)(r >> 16);
}
__device__ __forceinline__ float bf2f(unsigned short h) {
  return __uint_as_float(((unsigned)h) << 16);
}
__device__ __forceinline__ unsigned pk2(float a, float b) {
  return (unsigned)f2bf(a) | ((unsigned)f2bf(b) << 16);
}

__device__ __forceinline__ float wave_max(float v) {
#pragma unroll
  for (int o = 32; o > 0; o >>= 1) v = fmaxf(v, __shfl_xor(v, o, 64));
  return v;
}
__device__ __forceinline__ float wave_sum(float v) {
#pragma unroll
  for (int o = 32; o > 0; o >>= 1) v += __shfl_xor(v, o, 64);
  return v;
}

#define GLD_LDS16(gptr, lptr)                                             \
  __builtin_amdgcn_global_load_lds(                                       \
      (const __attribute__((address_space(1))) void*)(gptr),              \
      (__attribute__((address_space(3))) void*)(lptr), 16, 0, 0)

// ---------------------------------------------------------------------------
// Merged prep: idx<512 weights; [512,4608) ib 64x128 tiles -> ibT only;
// [4608,6656) qb pure stream convert.
__global__ __launch_bounds__(256) void k_prep(
    const float* __restrict__ ib, const float* __restrict__ qb,
    const float* __restrict__ lf_w1, const float* __restrict__ if_w1,
    const float* __restrict__ lf_wm, const float* __restrict__ if_wm,
    const float* __restrict__ fh_w, unsigned short* __restrict__ ibT,
    unsigned short* __restrict__ qb_bf, unsigned short* __restrict__ w1t_lf,
    unsigned short* __restrict__ w1t_if, unsigned short* __restrict__ wcat_t,
    unsigned short* __restrict__ fh_wt) {
  __shared__ __align__(16) char smem[64 * 65 * 4];  // 16640 B
  const int idx = blockIdx.x, t = threadIdx.x;

  if (idx < 512) {
    // ---- weights: f32 [K,N] -> bf16 [N, koff+K] (stride 65: conflict-free)
    float(*T)[65] = (float(*)[65])smem;
    const float* src;
    unsigned short* dst;
    int N, ds, koff, k0, n0;
    if (idx < 64) {
      src = lf_w1; dst = w1t_lf; N = 512; ds = 512; koff = 0;
      k0 = (idx & 7) * 64; n0 = (idx >> 3) * 64;
    } else if (idx < 128) {
      int l = idx - 64;
      src = if_w1; dst = w1t_if; N = 512; ds = 512; koff = 0;
      k0 = (l & 7) * 64; n0 = (l >> 3) * 64;
    } else if (idx < 256) {
      int l = idx - 128;
      src = lf_wm; dst = wcat_t; N = 1024; ds = 1024; koff = 0;
      k0 = (l & 7) * 64; n0 = (l >> 3) * 64;
    } else if (idx < 384) {
      int l = idx - 256;
      src = if_wm; dst = wcat_t; N = 1024; ds = 1024; koff = 512;
      k0 = (l & 7) * 64; n0 = (l >> 3) * 64;
    } else {
      int l = idx - 384;
      src = fh_w; dst = fh_wt; N = 512; ds = 1024; koff = 0;
      k0 = (l & 15) * 64; n0 = (l >> 4) * 64;
    }
#pragma unroll
    for (int i = 0; i < 16; i++) {
      int e = t + i * 256, r = e >> 6, c = e & 63;
      T[r][c] = src[(size_t)(k0 + r) * N + n0 + c];
    }
    __syncthreads();
#pragma unroll
    for (int i = 0; i < 8; i++) {
      int e = t + i * 256, r = e >> 5, c2 = (e & 31) * 2;
      *(unsigned*)&dst[(size_t)(n0 + r) * ds + koff + k0 + c2] =
          pk2(T[c2][r], T[c2 + 1][r]);
    }
  } else if (idx < 4608) {
    // ---- ib 64tok x 128h tiles, swizzled [64][128] bf16 -> ibT only ----
    int j = idx - 512;
    int b = j >> 4, tok0 = ((j >> 2) & 3) * 64, h0 = (j & 3) * 128;
    unsigned short* Tb = (unsigned short*)smem;  // [64][128] swizzled
    const float* src = ib + ((size_t)b * 256 + tok0) * 512 + h0;
#pragma unroll
    for (int i = 0; i < 8; i++) {
      int e = t + i * 256, tok = e >> 5, h4 = (e & 31) * 4;
      float4 v = *(const float4*)&src[(size_t)tok * 512 + h4];
      uint2 p;
      p.x = pk2(v.x, v.y);
      p.y = pk2(v.z, v.w);
      int col = ((((h4 >> 3) ^ (tok >> 3)) & 15) << 3) | (h4 & 7);
      *(uint2*)&Tb[tok * 128 + col] = p;
    }
    __syncthreads();
    unsigned short* dT = ibT + ((size_t)b * 512 + h0) * 256 + tok0;
#pragma unroll
    for (int i = 0; i < 4; i++) {
      int e = t + i * 256, h = e >> 3, tc = (e & 7) * 8;
      int hg = h >> 3, ho = h & 7;
      unsigned y[8];
#pragma unroll
      for (int k = 0; k < 8; k++) {
        int r = tc + k;
        y[k] = Tb[r * 128 + (((hg ^ (r >> 3)) & 15) << 3) + ho];
      }
      uint4 v;
      v.x = y[0] | (y[1] << 16);
      v.y = y[2] | (y[3] << 16);
      v.z = y[4] | (y[5] << 16);
      v.w = y[6] | (y[7] << 16);
      *(uint4*)&dT[(size_t)h * 256 + tc] = v;
    }
  } else {
    // ---- qb f32 -> bf16 pure stream ----
    int j = idx - 4608;  // 2048 blocks x 4096 floats
    const float4* src = (const float4*)(qb + (size_t)j * 4096);
    uint2* dst = (uint2*)(qb_bf + (size_t)j * 4096);
#pragma unroll
    for (int i = 0; i < 4; i++) {
      int e = t + i * 256;
      float4 v = src[e];
      uint2 p;
      p.x = pk2(v.x, v.y);
      p.y = pk2(v.z, v.w);
      dst[e] = p;
    }
  }
}

// ---------------------------------------------------------------------------
// Fused scores: per (i-chunk, batch). S[64q x 128i] = qb @ ib^T * SCALE.
// B operand staged directly from f32 ib with inline bf16 convert (native
// [i][h] layout). Emits P1[b,i,q] normalized bf16 (softmax over q, qmask)
// and P2[b,q,i] raw exp bf16 (imask) + psum[b*64+q][8] per-wave partials.
__global__ __launch_bounds__(256) void k_scores_f(
    const float* __restrict__ ib, const unsigned short* __restrict__ qbf,
    const int* __restrict__ imask, const int* __restrict__ qmask,
    unsigned short* __restrict__ P1, unsigned short* __restrict__ P2,
    float* __restrict__ psum) {
  __shared__ unsigned short As[64 * 64];
  __shared__ unsigned short Bs[128 * 64];
  __shared__ __align__(16) unsigned short X[128 * 72];  // E:[64][136] / Pl:[128][72]
  const int b = blockIdx.y, ic = blockIdx.x, i0 = ic * 128;
  const int t = threadIdx.x, w = t >> 6, lane = t & 63, c = lane & 15, qq = lane >> 4;

  floatx4 acc[4][2];
#pragma unroll
  for (int ti = 0; ti < 4; ti++)
#pragma unroll
    for (int tj = 0; tj < 2; tj++) acc[ti][tj] = (floatx4){0.f, 0.f, 0.f, 0.f};

  for (int k0 = 0; k0 < 512; k0 += 64) {
#pragma unroll
    for (int i = 0; i < 2; i++) {
      int s = i * 256 + t, row = s >> 3, src = (s & 7) ^ (row & 7);
      GLD_LDS16(qbf + ((size_t)b * 64 + row) * 512 + k0 + src * 8,
                &As[(i * 256 + w * 64) * 8]);
    }
    // B: [128 i][64 h] from f32 ib, inline convert. 2048 float4 slots.
#pragma unroll
    for (int i = 0; i < 8; i++) {
      int s = i * 256 + t, row = s >> 4, c4 = s & 15;
      float4 v = *(const float4*)&ib[((size_t)b * 256 + i0 + row) * 512 + k0 + c4 * 4];
      int gs = (c4 >> 1) ^ (row & 7), sub = c4 & 1;
      uint2 p;
      p.x = pk2(v.x, v.y);
      p.y = pk2(v.z, v.w);
      *(uint2*)&Bs[row * 64 + gs * 8 + sub * 4] = p;
    }
    __syncthreads();
#pragma unroll
    for (int kk = 0; kk < 2; kk++) {
      short8 a[4], bb[2];
#pragma unroll
      for (int ti = 0; ti < 4; ti++)
        a[ti] = *(const short8*)&As[(ti * 16 + c) * 64 + ((kk * 4 + qq) ^ (c & 7)) * 8];
#pragma unroll
      for (int tj = 0; tj < 2; tj++)
        bb[tj] = *(const short8*)&Bs[(w * 32 + tj * 16 + c) * 64 + ((kk * 4 + qq) ^ (c & 7)) * 8];
#pragma unroll
      for (int ti = 0; ti < 4; ti++)
#pragma unroll
        for (int tj = 0; tj < 2; tj++)
          acc[ti][tj] = __builtin_amdgcn_mfma_f32_16x16x32_bf16(a[ti], bb[tj], acc[ti][tj], 0, 0, 0);
    }
    __syncthreads();
  }

  const int il0 = w * 32 + c;  // tj=0 local i; tj=1 is il0+16
  int imsk0 = imask[b * 256 + i0 + il0];
  int imsk1 = imask[b * 256 + i0 + il0 + 16];
  int qm[4][4];
#pragma unroll
  for (int ti = 0; ti < 4; ti++)
#pragma unroll
    for (int rr = 0; rr < 4; rr++) qm[ti][rr] = qmask[b * 64 + ti * 16 + qq * 4 + rr];

  // ---- E phase: raw exp (imask) into X[64][136], per-wave row sums ----
#pragma unroll
  for (int ti = 0; ti < 4; ti++)
#pragma unroll
    for (int rr = 0; rr < 4; rr++) {
      int qv = ti * 16 + qq * 4 + rr;
      float e0 = imsk0 ? 0.f : __expf(acc[ti][0][rr] * SCALE);
      float e1 = imsk1 ? 0.f : __expf(acc[ti][1][rr] * SCALE);
      X[qv * 136 + il0] = f2bf(e0);
      X[qv * 136 + il0 + 16] = f2bf(e1);
      float s = e0 + e1;
#pragma unroll
      for (int o = 1; o <= 8; o <<= 1) s += __shfl_xor(s, o, 64);
      if (c == 0) psum[((size_t)(b * 64 + qv)) * 8 + ic * 4 + w] = s;
    }
  __syncthreads();
#pragma unroll
  for (int i = 0; i < 4; i++) {
    int e2 = t + i * 256, qv = e2 >> 4, g = e2 & 15;
    *(uint4*)&P2[((size_t)b * 64 + qv) * 256 + i0 + g * 8] = *(const uint4*)&X[qv * 136 + g * 8];
  }
  __syncthreads();

  // ---- P1 phase: column softmax over q (qmask), normalized, into X[128][72]
#pragma unroll
  for (int tj = 0; tj < 2; tj++) {
    float ev[4][4];
    float s1 = 0.f;
#pragma unroll
    for (int ti = 0; ti < 4; ti++)
#pragma unroll
      for (int rr = 0; rr < 4; rr++) {
        ev[ti][rr] = qm[ti][rr] ? 0.f : __expf(acc[ti][tj][rr] * SCALE);
        s1 += ev[ti][rr];
      }
    s1 += __shfl_xor(s1, 16, 64);
    s1 += __shfl_xor(s1, 32, 64);
    float inv = 1.f / s1;
    int il = il0 + tj * 16;
#pragma unroll
    for (int ti = 0; ti < 4; ti++)
#pragma unroll
      for (int rr = 0; rr < 4; rr++)
        X[il * 72 + ti * 16 + qq * 4 + rr] = f2bf(ev[ti][rr] * inv);
  }
  __syncthreads();
#pragma unroll
  for (int i = 0; i < 4; i++) {
    int e2 = t + i * 256, il = e2 >> 3, g = e2 & 7;
    *(uint4*)&P1[((size_t)b * 256 + i0 + il) * 64 + g * 8] = *(const uint4*)&X[il * 72 + g * 8];
  }
}

// ---------------------------------------------------------------------------
// lfeat[b,64,512] = (P2 @ ib) * rowscale ; B from ibT (bf16 [512][256]).
// K=256, 4 chunks. Row scale 1/sum(psum[row][0..7]) folded into epilogue.
__global__ __launch_bounds__(256) void k_av2(const unsigned short* __restrict__ P2,
                                             const unsigned short* __restrict__ ibT,
                                             const float* __restrict__ psum,
                                             unsigned short* __restrict__ lfeat) {
  __shared__ unsigned short As[64 * 64];
  __shared__ unsigned short Bs[128 * 64];
  const int b = blockIdx.y, n0 = blockIdx.x * 128;
  const int t = threadIdx.x, w = t >> 6, lane = t & 63, c = lane & 15, q = lane >> 4;
  const int wm = w >> 1, wn = w & 1;
  floatx4 acc[2][4];
#pragma unroll
  for (int ti = 0; ti < 2; ti++)
#pragma unroll
    for (int tj = 0; tj < 4; tj++) acc[ti][tj] = (floatx4){0.f, 0.f, 0.f, 0.f};

  for (int kc = 0; kc < 256; kc += 64) {
#pragma unroll
    for (int i = 0; i < 2; i++) {
      int s = i * 256 + t, row = s >> 3, src = (s & 7) ^ (row & 7);
      GLD_LDS16(P2 + ((size_t)b * 64 + row) * 256 + kc + src * 8, &As[(i * 256 + w * 64) * 8]);
    }
#pragma unroll
    for (int i = 0; i < 4; i++) {
      int s = i * 256 + t, row = s >> 3, src = (s & 7) ^ (row & 7);
      GLD_LDS16(ibT + ((size_t)b * 512 + n0 + row) * 256 + kc + src * 8,
                &Bs[(i * 256 + w * 64) * 8]);
    }
    __syncthreads();
#pragma unroll
    for (int kk = 0; kk < 2; kk++) {
      short8 a[2], bb[4];
#pragma unroll
      for (int ti = 0; ti < 2; ti++)
        a[ti] = *(const short8*)&As[(wm * 32 + ti * 16 + c) * 64 + ((kk * 4 + q) ^ (c & 7)) * 8];
#pragma unroll
      for (int tj = 0; tj < 4; tj++)
        bb[tj] = *(const short8*)&Bs[(wn * 64 + tj * 16 + c) * 64 + ((kk * 4 + q) ^ (c & 7)) * 8];
#pragma unroll
      for (int ti = 0; ti < 2; ti++)
#pragma unroll
        for (int tj = 0; tj < 4; tj++)
          acc[ti][tj] = __builtin_amdgcn_mfma_f32_16x16x32_bf16(a[ti], bb[tj], acc[ti][tj], 0, 0, 0);
    }
    __syncthreads();
  }
#pragma unroll
  for (int ti = 0; ti < 2; ti++)
#pragma unroll
    for (int rr = 0; rr < 4; rr++) {
      int m = wm * 32 + ti * 16 + q * 4 + rr;
      const float* ps = psum + ((size_t)(b * 64 + m)) * 8;
      float s = ps[0] + ps[1] + ps[2] + ps[3] + ps[4] + ps[5] + ps[6] + ps[7];
      float inv = 1.f / s;
      unsigned short* op = lfeat + ((size_t)b * 64 + m) * 512 + n0 + wn * 64;
#pragma unroll
      for (int tj = 0; tj < 4; tj++) op[tj * 16 + c] = f2bf(acc[ti][tj][rr] * inv);
    }
}

// ---------------------------------------------------------------------------
// qbW1T[b,512n,64q] = (qb_bf[b] @ lf_w1)^T, bf16.
__global__ __launch_bounds__(256) void k_qbw1(const unsigned short* __restrict__ qbf,
                                              const unsigned short* __restrict__ W1t,
                                              unsigned short* __restrict__ qbW1T) {
  __shared__ unsigned short As[64 * 64];
  __shared__ unsigned short Bs[128 * 64];
  const int b = blockIdx.y, n0 = blockIdx.x * 128;
  const int t = threadIdx.x, w = t >> 6, lane = t & 63, c = lane & 15, q = lane >> 4;
  const int wm = w >> 1, wn = w & 1;
  floatx4 acc[2][4];
#pragma unroll
  for (int ti = 0; ti < 2; ti++)
#pragma unroll
    for (int tj = 0; tj < 4; tj++) acc[ti][tj] = (floatx4){0.f, 0.f, 0.f, 0.f};

  for (int k0 = 0; k0 < 512; k0 += 64) {
#pragma unroll
    for (int i = 0; i < 2; i++) {
      int s = i * 256 + t, row = s >> 3, src = (s & 7) ^ (row & 7);
      GLD_LDS16(qbf + ((size_t)b * 64 + row) * 512 + k0 + src * 8,
                &As[(i * 256 + w * 64) * 8]);
    }
#pragma unroll
    for (int i = 0; i < 4; i++) {
      int s = i * 256 + t, row = s >> 3, src = (s & 7) ^ (row & 7);
      GLD_LDS16(W1t + (size_t)(n0 + row) * 512 + k0 + src * 8,
                &Bs[(i * 256 + w * 64) * 8]);
    }
    __syncthreads();
#pragma unroll
    for (int kk = 0; kk < 2; kk++) {
      short8 a[2], bb[4];
#pragma unroll
      for (int ti = 0; ti < 2; ti++)
        a[ti] = *(const short8*)&As[(wm * 32 + ti * 16 + c) * 64 + ((kk * 4 + q) ^ (c & 7)) * 8];
#pragma unroll
      for (int tj = 0; tj < 4; tj++)
        bb[tj] = *(const short8*)&Bs[(wn * 64 + tj * 16 + c) * 64 + ((kk * 4 + q) ^ (c & 7)) * 8];
#pragma unroll
      for (int ti = 0; ti < 2; ti++)
#pragma unroll
        for (int tj = 0; tj < 4; tj++)
          acc[ti][tj] = __builtin_amdgcn_mfma_f32_16x16x32_bf16(a[ti], bb[tj], acc[ti][tj], 0, 0, 0);
    }
    __syncthreads();
  }
#pragma unroll
  for (int ti = 0; ti < 2; ti++)
#pragma unroll
    for (int tj = 0; tj < 4; tj++) {
      int n = n0 + wn * 64 + tj * 16 + c;
      int m = wm * 32 + ti * 16 + q * 4;
      uint2 p;
      p.x = pk2(acc[ti][tj][0], acc[ti][tj][1]);
      p.y = pk2(acc[ti][tj][2], acc[ti][tj][3]);
      *(uint2*)&qbW1T[((size_t)b * 512 + n) * 64 + m] = p;
    }
}

// ---------------------------------------------------------------------------
// lp_i partials: A = P1[b,256,64], B = qbW1T[b,512,64]. K=64. Fused relu*w2.
__global__ __launch_bounds__(256) void k_logits_i64(
    const unsigned short* __restrict__ P1, const unsigned short* __restrict__ qbW1T,
    const float* __restrict__ b1, const float* __restrict__ w2,
    float* __restrict__ outp) {
  __shared__ unsigned short As[128 * 64];
  __shared__ unsigned short Bs[128 * 64];
  __shared__ float red[2][128];
  const int b = blockIdx.y;
  const int mt = blockIdx.x & 1, nc = blockIdx.x >> 1;
  const int m0 = mt * 128, n0 = nc * 128;
  const int t = threadIdx.x, w = t >> 6, lane = t & 63, c = lane & 15, q = lane >> 4;
  const int wm = w >> 1, wn = w & 1;

#pragma unroll
  for (int i = 0; i < 4; i++) {
    int s = i * 256 + t, row = s >> 3, src = (s & 7) ^ (row & 7);
    GLD_LDS16(P1 + ((size_t)b * 256 + m0 + row) * 64 + src * 8, &As[(i * 256 + w * 64) * 8]);
  }
#pragma unroll
  for (int i = 0; i < 4; i++) {
    int s = i * 256 + t, row = s >> 3, src = (s & 7) ^ (row & 7);
    GLD_LDS16(qbW1T + ((size_t)b * 512 + n0 + row) * 64 + src * 8, &Bs[(i * 256 + w * 64) * 8]);
  }
  __syncthreads();
  floatx4 acc[4][4];
#pragma unroll
  for (int ti = 0; ti < 4; ti++)
#pragma unroll
    for (int tj = 0; tj < 4; tj++) acc[ti][tj] = (floatx4){0.f, 0.f, 0.f, 0.f};
#pragma unroll
  for (int kk = 0; kk < 2; kk++) {
    short8 a[4], bb[4];
#pragma unroll
    for (int ti = 0; ti < 4; ti++)
      a[ti] = *(const short8*)&As[(wm * 64 + ti * 16 + c) * 64 + ((kk * 4 + q) ^ (c & 7)) * 8];
#pragma unroll
    for (int tj = 0; tj < 4; tj++)
      bb[tj] = *(const short8*)&Bs[(wn * 64 + tj * 16 + c) * 64 + ((kk * 4 + q) ^ (c & 7)) * 8];
#pragma unroll
    for (int ti = 0; ti < 4; ti++)
#pragma unroll
      for (int tj = 0; tj < 4; tj++)
        acc[ti][tj] = __builtin_amdgcn_mfma_f32_16x16x32_bf16(a[ti], bb[tj], acc[ti][tj], 0, 0, 0);
  }

  float partial[4][4] = {};
#pragma unroll
  for (int tj = 0; tj < 4; tj++) {
    int n = n0 + wn * 64 + tj * 16 + c;
    float bia = b1[n], wwv = w2[n];
#pragma unroll
    for (int ti = 0; ti < 4; ti++)
#pragma unroll
      for (int r = 0; r < 4; r++)
        partial[ti][r] += fmaxf(acc[ti][tj][r] + bia, 0.f) * wwv;
  }
#pragma unroll
  for (int msk = 1; msk <= 8; msk <<= 1)
#pragma unroll
    for (int ti = 0; ti < 4; ti++)
#pragma unroll
      for (int r = 0; r < 4; r++)
        partial[ti][r] += __shfl_xor(partial[ti][r], msk, 64);
  if (c == 0) {
#pragma unroll
    for (int ti = 0; ti < 4; ti++)
#pragma unroll
      for (int r = 0; r < 4; r++)
        red[wn][wm * 64 + ti * 16 + q * 4 + r] = partial[ti][r];
  }
  __syncthreads();
  if (t < 128) outp[(size_t)nc * 65536 + b * 256 + m0 + t] = red[0][t] + red[1][t];
}

// ---------------------------------------------------------------------------
// Partial logits (l-side).
__global__ __launch_bounds__(256) void k_logits_part(
    const unsigned short* __restrict__ X, const unsigned short* __restrict__ W1t,
    const float* __restrict__ b1, const float* __restrict__ w2,
    float* __restrict__ outp, int M) {
  __shared__ unsigned short As[128 * 64];
  __shared__ unsigned short Bs[128 * 64];
  __shared__ float red[2][128];
  const int t = threadIdx.x, w = t >> 6, lane = t & 63;
  const int wm = w >> 1, wn = w & 1, c = lane & 15, q = lane >> 4;
  const int idx = blockIdx.x;
  const int m_tile = (idx & 7) + ((idx >> 5) << 3), nc = (idx >> 3) & 3;
  const int m0 = m_tile * 128, n0 = nc * 128;

  floatx4 acc[4][4];
#pragma unroll
  for (int ti = 0; ti < 4; ti++)
#pragma unroll
    for (int tj = 0; tj < 4; tj++) acc[ti][tj] = (floatx4){0.f, 0.f, 0.f, 0.f};

  for (int k0 = 0; k0 < 512; k0 += 64) {
#pragma unroll
    for (int it = 0; it < 4; it++) {
      int s = it * 256 + t, row = s >> 3, src = (s & 7) ^ (row & 7);
      GLD_LDS16(X + (size_t)(m0 + row) * 512 + k0 + src * 8, &As[(it * 256 + w * 64) * 8]);
      GLD_LDS16(W1t + (size_t)(n0 + row) * 512 + k0 + src * 8, &Bs[(it * 256 + w * 64) * 8]);
    }
    __syncthreads();
#pragma unroll
    for (int kk = 0; kk < 2; kk++) {
      short8 a[4], bb[4];
#pragma unroll
      for (int ti = 0; ti < 4; ti++)
        a[ti] = *(const short8*)&As[(wm * 64 + ti * 16 + c) * 64 + ((kk * 4 + q) ^ (c & 7)) * 8];
#pragma unroll
      for (int tj = 0; tj < 4; tj++)
        bb[tj] = *(const short8*)&Bs[(wn * 64 + tj * 16 + c) * 64 + ((kk * 4 + q) ^ (c & 7)) * 8];
#pragma unroll
      for (int ti = 0; ti < 4; ti++)
#pragma unroll
        for (int tj = 0; tj < 4; tj++)
          acc[ti][tj] = __builtin_amdgcn_mfma_f32_16x16x32_bf16(a[ti], bb[tj], acc[ti][tj], 0, 0, 0);
    }
    __syncthreads();
  }
  float partial[4][4] = {};
#pragma unroll
  for (int tj = 0; tj < 4; tj++) {
    int n = n0 + wn * 64 + tj * 16 + c;
    float bia = b1[n], wwv = w2[n];
#pragma unroll
    for (int ti = 0; ti < 4; ti++)
#pragma unroll
      for (int r = 0; r < 4; r++)
        partial[ti][r] += fmaxf(acc[ti][tj][r] + bia, 0.f) * wwv;
  }
#pragma unroll
  for (int msk = 1; msk <= 8; msk <<= 1)
#pragma unroll
    for (int ti = 0; ti < 4; ti++)
#pragma unroll
      for (int r = 0; r < 4; r++)
        partial[ti][r] += __shfl_xor(partial[ti][r], msk, 64);
  if (c == 0) {
#pragma unroll
    for (int ti = 0; ti < 4; ti++)
#pragma unroll
      for (int r = 0; r < 4; r++)
        red[wn][wm * 64 + ti * 16 + q * 4 + r] = partial[ti][r];
  }
  __syncthreads();
  if (t < 128) outp[(size_t)nc * M + m0 + t] = red[0][t] + red[1][t];
}

// ---------------------------------------------------------------------------
// Fused i-side epilogue: softmax(lp_i w/ imask) -> i_weight out + att in LDS;
// v = att^T @ P1 ; pooled_i = sum_l v[l] * qb[b,l,:].
__global__ __launch_bounds__(256) void k_final_i(const float* __restrict__ lp,
                                                 const int* __restrict__ imask,
                                                 const unsigned short* __restrict__ P1,
                                                 const unsigned short* __restrict__ qbf,
                                                 float* __restrict__ iw_out,
                                                 unsigned short* __restrict__ pooled) {
  __shared__ float red4[4];
  __shared__ float ar[256];
  __shared__ float red[4][64];
  __shared__ float vsm[64];
  const int b = blockIdx.x, t = threadIdx.x;
  const int i = b * 256 + t;
  float x = lp[i] + lp[65536 + i] + lp[131072 + i] + lp[196608 + i];
  float v = imask[i] ? -1e9f : x;
  float wmx = wave_max(v);
  if ((t & 63) == 0) red4[t >> 6] = wmx;
  __syncthreads();
  float mx = fmaxf(fmaxf(red4[0], red4[1]), fmaxf(red4[2], red4[3]));
  __syncthreads();
  float e = __expf(v - mx);
  float ws = wave_sum(e);
  if ((t & 63) == 0) red4[t >> 6] = ws;
  __syncthreads();
  float s = red4[0] + red4[1] + red4[2] + red4[3];
  float p = e / s;
  iw_out[i] = p;
  ar[t] = p;
  __syncthreads();
  // v[64] = att^T @ P1
  const int part = t >> 6, lane = t & 63;
  const unsigned short* Pb = P1 + ((size_t)b * 256 + part * 64) * 64 + lane;
  float s0 = 0.f, s1 = 0.f;
#pragma unroll 8
  for (int ii = 0; ii < 64; ii += 2) {
    s0 += ar[part * 64 + ii] * bf2f(Pb[(size_t)ii * 64]);
    s1 += ar[part * 64 + ii + 1] * bf2f(Pb[(size_t)(ii + 1) * 64]);
  }
  red[part][lane] = s0 + s1;
  __syncthreads();
  if (t < 64) vsm[t] = red[0][t] + red[1][t] + red[2][t] + red[3][t];
  __syncthreads();
  // pooled_i over qb_bf, L=64
  float a0 = 0.f, a1 = 0.f;
  const unsigned short* Xb = qbf + (size_t)b * 64 * 512 + 2 * t;
#pragma unroll 4
  for (int l = 0; l < 64; l++) {
    unsigned u = *(const unsigned*)&Xb[(size_t)l * 512];
    float a = vsm[l];
    a0 += a * bf2f((unsigned short)(u & 0xffff));
    a1 += a * bf2f((unsigned short)(u >> 16));
  }
  *(unsigned*)&pooled[(size_t)b * 1024 + 2 * t] = pk2(a0, a1);
}

// ---------------------------------------------------------------------------
// Fused l-side epilogue: softmax(lp_l w/ qmask) in LDS; pooled_l from lfeat.
__global__ __launch_bounds__(256) void k_final_l(const float* __restrict__ lp,
                                                 const int* __restrict__ qmask,
                                                 const unsigned short* __restrict__ lfeat,
                                                 unsigned short* __restrict__ pooled) {
  __shared__ float ar[64];
  const int b = blockIdx.x, t = threadIdx.x;
  if (t < 64) {
    const int i = b * 64 + t;
    float x = lp[i] + lp[16384 + i] + lp[32768 + i] + lp[49152 + i];
    float v = qmask[i] ? -1e9f : x;
    float mx = wave_max(v);
    float e = __expf(v - mx);
    float s = wave_sum(e);
    ar[t] = e / s;
  }
  __syncthreads();
  float a0 = 0.f, a1 = 0.f;
  const unsigned short* Xb = lfeat + (size_t)b * 64 * 512 + 2 * t;
#pragma unroll 4
  for (int l = 0; l < 64; l++) {
    unsigned u = *(const unsigned*)&Xb[(size_t)l * 512];
    float a = ar[l];
    a0 += a * bf2f((unsigned short)(u & 0xffff));
    a1 += a * bf2f((unsigned short)(u >> 16));
  }
  *(unsigned*)&pooled[(size_t)b * 1024 + 512 + 2 * t] = pk2(a0, a1);
}

// ---------------------------------------------------------------------------
// Epilogue GEMM: out[M,N] = X[M,K]bf16 @ Wt[N,K]bf16 + biasA (+biasB).
__global__ __launch_bounds__(256) void k_egemm(const unsigned short* __restrict__ X,
                                               const unsigned short* __restrict__ Wt,
                                               const float* __restrict__ biasA,
                                               const float* __restrict__ biasB,
                                               float* __restrict__ outf,
                                               unsigned short* __restrict__ outbf,
                                               int N, int K) {
  __shared__ unsigned short As[64 * 64];
  __shared__ unsigned short Bs[64 * 64];
  const int n0 = blockIdx.x * 64, m0 = blockIdx.y * 64;
  const int t = threadIdx.x, w = t >> 6, lane = t & 63, c = lane & 15, q = lane >> 4;
  const int wm = w >> 1, wn = w & 1;
  floatx4 acc[2][2];
#pragma unroll
  for (int ti = 0; ti < 2; ti++)
#pragma unroll
    for (int tj = 0; tj < 2; tj++) acc[ti][tj] = (floatx4){0.f, 0.f, 0.f, 0.f};

  for (int k0 = 0; k0 < K; k0 += 64) {
#pragma unroll
    for (int i = 0; i < 2; i++) {
      int s = i * 256 + t, row = s >> 3, src = (s & 7) ^ (row & 7);
      GLD_LDS16(X + (size_t)(m0 + row) * K + k0 + src * 8, &As[(i * 256 + w * 64) * 8]);
      GLD_LDS16(Wt + (size_t)(n0 + row) * K + k0 + src * 8, &Bs[(i * 256 + w * 64) * 8]);
    }
    __syncthreads();
#pragma unroll
    for (int kk = 0; kk < 2; kk++) {
      short8 a[2], bb[2];
#pragma unroll
      for (int ti = 0; ti < 2; ti++)
        a[ti] = *(const short8*)&As[(wm * 32 + ti * 16 + c) * 64 + ((kk * 4 + q) ^ (c & 7)) * 8];
#pragma unroll
      for (int tj = 0; tj < 2; tj++)
        bb[tj] = *(const short8*)&Bs[(wn * 32 + tj * 16 + c) * 64 + ((kk * 4 + q) ^ (c & 7)) * 8];
#pragma unroll
      for (int ti = 0; ti < 2; ti++)
#pragma unroll
        for (int tj = 0; tj < 2; tj++)
          acc[ti][tj] = __builtin_amdgcn_mfma_f32_16x16x32_bf16(a[ti], bb[tj], acc[ti][tj], 0, 0, 0);
    }
    __syncthreads();
  }
#pragma unroll
  for (int tj = 0; tj < 2; tj++) {
    int n = n0 + wn * 32 + tj * 16 + c;
    float bias = biasA[n] + (biasB ? biasB[n] : 0.f);
#pragma unroll
    for (int ti = 0; ti < 2; ti++)
#pragma unroll
      for (int rr = 0; rr < 4; rr++) {
        int m = m0 + wm * 32 + ti * 16 + q * 4 + rr;
        float v = acc[ti][tj][rr] + bias;
        if (outbf) outbf[(size_t)m * N + n] = f2bf(v);
        else outf[(size_t)m * N + n] = v;
      }
  }
}

// ---------------------------------------------------------------------------
extern "C" void kernel_launch(void* const* d_in, const int* in_sizes, int n_in,
                              void* d_out, int out_size, void* d_ws, size_t ws_size,
                              hipStream_t stream) {
  const float* ib = (const float*)d_in[0];
  const float* qb = (const float*)d_in[1];
  const int* imask = (const int*)d_in[2];
  const int* qmask = (const int*)d_in[3];
  const float* lf_w1 = (const float*)d_in[4];
  const float* lf_b1 = (const float*)d_in[5];
  const float* lf_w2 = (const float*)d_in[6];
  const float* lf_wm = (const float*)d_in[8];
  const float* lf_bm = (const float*)d_in[9];
  const float* if_w1 = (const float*)d_in[10];
  const float* if_b1 = (const float*)d_in[11];
  const float* if_w2 = (const float*)d_in[12];
  const float* if_wm = (const float*)d_in[14];
  const float* if_bm = (const float*)d_in[15];
  const float* fh_w = (const float*)d_in[16];
  const float* fh_b = (const float*)d_in[17];
  float* out = (float*)d_out;  // [256*512] out, then [256*256] i_weight

  float* lp_i = (float*)d_ws;              // 262,144 (4 x 65536)
  float* lp_l = lp_i + 262144;             // 65,536 (4 x 16384)
  float* att_i = lp_l + 65536;             // 65,536 (unused, kept for layout)
  float* att_l = att_i + 65536;            // 16,384 (unused)
  float* psum = att_l + 16384;             // 131,072 (16384 x 8)
  unsigned short* P1 = (unsigned short*)(psum + 131072);  // 4,194,304
  unsigned short* P2 = P1 + 4194304;                      // 4,194,304
  unsigned short* lfeat = P2 + 4194304;                   // 33,554,432 slot
  unsigned short* qb_bf = lfeat + 33554432;               // 8,388,608
  unsigned short* qbW1T = qb_bf + 8388608;                // 8,388,608
  unsigned short* ibT = qbW1T + 8388608;                  // 33,554,432
  unsigned short* w1t_lf = ibT + 33554432;                // 262,144
  unsigned short* w1t_if = w1t_lf + 262144;               // 262,144
  unsigned short* wcat_t = w1t_if + 262144;               // 1,048,576
  unsigned short* fh_wt = wcat_t + 1048576;               // 524,288
  unsigned short* pooled_bf = fh_wt + 524288;             // 262,144
  unsigned short* F_bf = pooled_bf + 262144;              // 262,144

  k_prep<<<6656, 256, 0, stream>>>(ib, qb, lf_w1, if_w1, lf_wm, if_wm, fh_w,
                                   ibT, qb_bf, w1t_lf, w1t_if, wcat_t, fh_wt);

  k_scores_f<<<dim3(2, 256), 256, 0, stream>>>(ib, qb_bf, imask, qmask, P1, P2, psum);
  k_av2<<<dim3(4, 256), 256, 0, stream>>>(P2, ibT, psum, lfeat);
  k_qbw1<<<dim3(4, 256), 256, 0, stream>>>(qb_bf, w1t_lf, qbW1T);
  k_logits_i64<<<dim3(8, 256), 256, 0, stream>>>(P1, qbW1T, lf_b1, lf_w2, lp_i);
  k_logits_part<<<512, 256, 0, stream>>>(lfeat, w1t_if, if_b1, if_w2, lp_l, 16384);
  k_final_i<<<256, 256, 0, stream>>>(lp_i, imask, P1, qb_bf, out + 131072, pooled_bf);
  k_final_l<<<256, 256, 0, stream>>>(lp_l, qmask, lfeat, pooled_bf);

  k_egemm<<<dim3(16, 4), 256, 0, stream>>>(pooled_bf, wcat_t, lf_bm, if_bm,
                                           nullptr, F_bf, 1024, 1024);
  k_egemm<<<dim3(8, 4), 256, 0, stream>>>(F_bf, fh_wt, fh_b, nullptr,
                                          out, nullptr, 512, 1024);
}

// Round 5
// 381.319 us; speedup vs baseline: 1.2250x; 1.0914x over previous
//
#include <hip/hip_runtime.h>
#include <math.h>

// ---------------------------------------------------------------------------
// BiAttention round 11: ibT eliminated (-134 MB glue traffic).
//  - k_av2 stages its B operand ([h][tok] bf16 fragments) in-LDS per K-chunk
//    directly from f32 ib: Tb[64tok][128h] convert+swizzle (k_prep's verified
//    tile), then LDS->LDS transpose into fragment-layout Bs (k_prep's y[8]
//    gather, ~2-way conflicts). ib is L3-warm (k_scores_f reads it first).
//  - k_prep ib path deleted: weights + qb stream convert only (grid 2560).
//  - bit-identical values (same f2bf on same f32) -> absmax unchanged.
//  - everything else identical to verified R10.
// Fragment scheme (verified R2..R10): A/B frag row = lane&15, k-group
// (lane>>4)*8 contiguous, XOR swizzle (colgroup ^ (row&7));
// C/D: col = lane&15, row = (lane>>4)*4 + r.
// ---------------------------------------------------------------------------

#define SCALE 0.04419417382415922f  // 1/sqrt(512)

typedef __attribute__((ext_vector_type(8))) short short8;
typedef __attribute__((ext_vector_type(4))) float floatx4;

__device__ __forceinline__ unsigned short f2bf(float x) {
  unsigned u = __float_as_uint(x);
  unsigned r = u + 0x7FFFu + ((u >> 16) & 1u);
  return (unsigned short)(r >> 16);
}
__device__ __forceinline__ float bf2f(unsigned short h) {
  return __uint_as_float(((unsigned)h) << 16);
}
__device__ __forceinline__ unsigned pk2(float a, float b) {
  return (unsigned)f2bf(a) | ((unsigned)f2bf(b) << 16);
}

__device__ __forceinline__ float wave_max(float v) {
#pragma unroll
  for (int o = 32; o > 0; o >>= 1) v = fmaxf(v, __shfl_xor(v, o, 64));
  return v;
}
__device__ __forceinline__ float wave_sum(float v) {
#pragma unroll
  for (int o = 32; o > 0; o >>= 1) v += __shfl_xor(v, o, 64);
  return v;
}

#define GLD_LDS16(gptr, lptr)                                             \
  __builtin_amdgcn_global_load_lds(                                       \
      (const __attribute__((address_space(1))) void*)(gptr),              \
      (__attribute__((address_space(3))) void*)(lptr), 16, 0, 0)

// ---------------------------------------------------------------------------
// Merged prep: idx<512 weights; [512,2560) qb pure stream convert.
__global__ __launch_bounds__(256) void k_prep(
    const float* __restrict__ qb, const float* __restrict__ lf_w1,
    const float* __restrict__ if_w1, const float* __restrict__ lf_wm,
    const float* __restrict__ if_wm, const float* __restrict__ fh_w,
    unsigned short* __restrict__ qb_bf, unsigned short* __restrict__ w1t_lf,
    unsigned short* __restrict__ w1t_if, unsigned short* __restrict__ wcat_t,
    unsigned short* __restrict__ fh_wt) {
  __shared__ __align__(16) char smem[64 * 65 * 4];  // 16640 B
  const int idx = blockIdx.x, t = threadIdx.x;

  if (idx < 512) {
    // ---- weights: f32 [K,N] -> bf16 [N, koff+K] (stride 65: conflict-free)
    float(*T)[65] = (float(*)[65])smem;
    const float* src;
    unsigned short* dst;
    int N, ds, koff, k0, n0;
    if (idx < 64) {
      src = lf_w1; dst = w1t_lf; N = 512; ds = 512; koff = 0;
      k0 = (idx & 7) * 64; n0 = (idx >> 3) * 64;
    } else if (idx < 128) {
      int l = idx - 64;
      src = if_w1; dst = w1t_if; N = 512; ds = 512; koff = 0;
      k0 = (l & 7) * 64; n0 = (l >> 3) * 64;
    } else if (idx < 256) {
      int l = idx - 128;
      src = lf_wm; dst = wcat_t; N = 1024; ds = 1024; koff = 0;
      k0 = (l & 7) * 64; n0 = (l >> 3) * 64;
    } else if (idx < 384) {
      int l = idx - 256;
      src = if_wm; dst = wcat_t; N = 1024; ds = 1024; koff = 512;
      k0 = (l & 7) * 64; n0 = (l >> 3) * 64;
    } else {
      int l = idx - 384;
      src = fh_w; dst = fh_wt; N = 512; ds = 1024; koff = 0;
      k0 = (l & 15) * 64; n0 = (l >> 4) * 64;
    }
#pragma unroll
    for (int i = 0; i < 16; i++) {
      int e = t + i * 256, r = e >> 6, c = e & 63;
      T[r][c] = src[(size_t)(k0 + r) * N + n0 + c];
    }
    __syncthreads();
#pragma unroll
    for (int i = 0; i < 8; i++) {
      int e = t + i * 256, r = e >> 5, c2 = (e & 31) * 2;
      *(unsigned*)&dst[(size_t)(n0 + r) * ds + koff + k0 + c2] =
          pk2(T[c2][r], T[c2 + 1][r]);
    }
  } else {
    // ---- qb f32 -> bf16 pure stream ----
    int j = idx - 512;  // 2048 blocks x 4096 floats
    const float4* src = (const float4*)(qb + (size_t)j * 4096);
    uint2* dst = (uint2*)(qb_bf + (size_t)j * 4096);
#pragma unroll
    for (int i = 0; i < 4; i++) {
      int e = t + i * 256;
      float4 v = src[e];
      uint2 p;
      p.x = pk2(v.x, v.y);
      p.y = pk2(v.z, v.w);
      dst[e] = p;
    }
  }
}

// ---------------------------------------------------------------------------
// Fused scores: per (i-chunk, batch). S[64q x 128i] = qb @ ib^T * SCALE.
// B operand staged directly from f32 ib with inline bf16 convert (native
// [i][h] layout). Emits P1[b,i,q] normalized bf16 (softmax over q, qmask)
// and P2[b,q,i] raw exp bf16 (imask) + psum[b*64+q][8] per-wave partials.
__global__ __launch_bounds__(256) void k_scores_f(
    const float* __restrict__ ib, const unsigned short* __restrict__ qbf,
    const int* __restrict__ imask, const int* __restrict__ qmask,
    unsigned short* __restrict__ P1, unsigned short* __restrict__ P2,
    float* __restrict__ psum) {
  __shared__ unsigned short As[64 * 64];
  __shared__ unsigned short Bs[128 * 64];
  __shared__ __align__(16) unsigned short X[128 * 72];  // E:[64][136] / Pl:[128][72]
  const int b = blockIdx.y, ic = blockIdx.x, i0 = ic * 128;
  const int t = threadIdx.x, w = t >> 6, lane = t & 63, c = lane & 15, qq = lane >> 4;

  floatx4 acc[4][2];
#pragma unroll
  for (int ti = 0; ti < 4; ti++)
#pragma unroll
    for (int tj = 0; tj < 2; tj++) acc[ti][tj] = (floatx4){0.f, 0.f, 0.f, 0.f};

  for (int k0 = 0; k0 < 512; k0 += 64) {
#pragma unroll
    for (int i = 0; i < 2; i++) {
      int s = i * 256 + t, row = s >> 3, src = (s & 7) ^ (row & 7);
      GLD_LDS16(qbf + ((size_t)b * 64 + row) * 512 + k0 + src * 8,
                &As[(i * 256 + w * 64) * 8]);
    }
    // B: [128 i][64 h] from f32 ib, inline convert. 2048 float4 slots.
#pragma unroll
    for (int i = 0; i < 8; i++) {
      int s = i * 256 + t, row = s >> 4, c4 = s & 15;
      float4 v = *(const float4*)&ib[((size_t)b * 256 + i0 + row) * 512 + k0 + c4 * 4];
      int gs = (c4 >> 1) ^ (row & 7), sub = c4 & 1;
      uint2 p;
      p.x = pk2(v.x, v.y);
      p.y = pk2(v.z, v.w);
      *(uint2*)&Bs[row * 64 + gs * 8 + sub * 4] = p;
    }
    __syncthreads();
#pragma unroll
    for (int kk = 0; kk < 2; kk++) {
      short8 a[4], bb[2];
#pragma unroll
      for (int ti = 0; ti < 4; ti++)
        a[ti] = *(const short8*)&As[(ti * 16 + c) * 64 + ((kk * 4 + qq) ^ (c & 7)) * 8];
#pragma unroll
      for (int tj = 0; tj < 2; tj++)
        bb[tj] = *(const short8*)&Bs[(w * 32 + tj * 16 + c) * 64 + ((kk * 4 + qq) ^ (c & 7)) * 8];
#pragma unroll
      for (int ti = 0; ti < 4; ti++)
#pragma unroll
        for (int tj = 0; tj < 2; tj++)
          acc[ti][tj] = __builtin_amdgcn_mfma_f32_16x16x32_bf16(a[ti], bb[tj], acc[ti][tj], 0, 0, 0);
    }
    __syncthreads();
  }

  const int il0 = w * 32 + c;  // tj=0 local i; tj=1 is il0+16
  int imsk0 = imask[b * 256 + i0 + il0];
  int imsk1 = imask[b * 256 + i0 + il0 + 16];
  int qm[4][4];
#pragma unroll
  for (int ti = 0; ti < 4; ti++)
#pragma unroll
    for (int rr = 0; rr < 4; rr++) qm[ti][rr] = qmask[b * 64 + ti * 16 + qq * 4 + rr];

  // ---- E phase: raw exp (imask) into X[64][136], per-wave row sums ----
#pragma unroll
  for (int ti = 0; ti < 4; ti++)
#pragma unroll
    for (int rr = 0; rr < 4; rr++) {
      int qv = ti * 16 + qq * 4 + rr;
      float e0 = imsk0 ? 0.f : __expf(acc[ti][0][rr] * SCALE);
      float e1 = imsk1 ? 0.f : __expf(acc[ti][1][rr] * SCALE);
      X[qv * 136 + il0] = f2bf(e0);
      X[qv * 136 + il0 + 16] = f2bf(e1);
      float s = e0 + e1;
#pragma unroll
      for (int o = 1; o <= 8; o <<= 1) s += __shfl_xor(s, o, 64);
      if (c == 0) psum[((size_t)(b * 64 + qv)) * 8 + ic * 4 + w] = s;
    }
  __syncthreads();
#pragma unroll
  for (int i = 0; i < 4; i++) {
    int e2 = t + i * 256, qv = e2 >> 4, g = e2 & 15;
    *(uint4*)&P2[((size_t)b * 64 + qv) * 256 + i0 + g * 8] = *(const uint4*)&X[qv * 136 + g * 8];
  }
  __syncthreads();

  // ---- P1 phase: column softmax over q (qmask), normalized, into X[128][72]
#pragma unroll
  for (int tj = 0; tj < 2; tj++) {
    float ev[4][4];
    float s1 = 0.f;
#pragma unroll
    for (int ti = 0; ti < 4; ti++)
#pragma unroll
      for (int rr = 0; rr < 4; rr++) {
        ev[ti][rr] = qm[ti][rr] ? 0.f : __expf(acc[ti][tj][rr] * SCALE);
        s1 += ev[ti][rr];
      }
    s1 += __shfl_xor(s1, 16, 64);
    s1 += __shfl_xor(s1, 32, 64);
    float inv = 1.f / s1;
    int il = il0 + tj * 16;
#pragma unroll
    for (int ti = 0; ti < 4; ti++)
#pragma unroll
      for (int rr = 0; rr < 4; rr++)
        X[il * 72 + ti * 16 + qq * 4 + rr] = f2bf(ev[ti][rr] * inv);
  }
  __syncthreads();
#pragma unroll
  for (int i = 0; i < 4; i++) {
    int e2 = t + i * 256, il = e2 >> 3, g = e2 & 7;
    *(uint4*)&P1[((size_t)b * 256 + i0 + il) * 64 + g * 8] = *(const uint4*)&X[il * 72 + g * 8];
  }
}

// ---------------------------------------------------------------------------
// lfeat[b,64,512] = (P2 @ ib) * rowscale. B built in-LDS from f32 ib:
// Tb[64tok][128h] convert+swizzle, then transpose into fragment-layout Bs.
// K=256, 4 chunks. Row scale 1/sum(psum[row][0..7]) folded into epilogue.
__global__ __launch_bounds__(256) void k_av2(const unsigned short* __restrict__ P2,
                                             const float* __restrict__ ib,
                                             const float* __restrict__ psum,
                                             unsigned short* __restrict__ lfeat) {
  __shared__ unsigned short As[64 * 64];
  __shared__ unsigned short Bs[128 * 64];
  __shared__ __align__(16) unsigned short Tb[64 * 128];
  const int b = blockIdx.y, n0 = blockIdx.x * 128;
  const int t = threadIdx.x, w = t >> 6, lane = t & 63, c = lane & 15, q = lane >> 4;
  const int wm = w >> 1, wn = w & 1;
  floatx4 acc[2][4];
#pragma unroll
  for (int ti = 0; ti < 2; ti++)
#pragma unroll
    for (int tj = 0; tj < 4; tj++) acc[ti][tj] = (floatx4){0.f, 0.f, 0.f, 0.f};

  for (int kc = 0; kc < 256; kc += 64) {
    // A: P2 tile via global_load_lds
#pragma unroll
    for (int i = 0; i < 2; i++) {
      int s = i * 256 + t, row = s >> 3, src = (s & 7) ^ (row & 7);
      GLD_LDS16(P2 + ((size_t)b * 64 + row) * 256 + kc + src * 8, &As[(i * 256 + w * 64) * 8]);
    }
    // Tb: f32 ib [64 tok][128 h] convert + 16B-group XOR swizzle
#pragma unroll
    for (int i = 0; i < 8; i++) {
      int e = i * 256 + t, tok = e >> 5, h4 = (e & 31) * 4;
      float4 v = *(const float4*)&ib[((size_t)b * 256 + kc + tok) * 512 + n0 + h4];
      uint2 p;
      p.x = pk2(v.x, v.y);
      p.y = pk2(v.z, v.w);
      int col = ((((h4 >> 3) ^ (tok >> 3)) & 15) << 3) | (h4 & 7);
      *(uint2*)&Tb[tok * 128 + col] = p;
    }
    __syncthreads();
    // Transpose Tb -> Bs [h=128 rows][tok=64], fragment XOR swizzle on kgroup
#pragma unroll
    for (int i = 0; i < 4; i++) {
      int e = i * 256 + t, h = e >> 3, tc = (e & 7) * 8;
      int hg = h >> 3, ho = h & 7;
      unsigned y[8];
#pragma unroll
      for (int k = 0; k < 8; k++) {
        int r = tc + k;
        y[k] = Tb[r * 128 + (((hg ^ (r >> 3)) & 15) << 3) + ho];
      }
      uint4 vv;
      vv.x = y[0] | (y[1] << 16);
      vv.y = y[2] | (y[3] << 16);
      vv.z = y[4] | (y[5] << 16);
      vv.w = y[6] | (y[7] << 16);
      *(uint4*)&Bs[h * 64 + (((tc >> 3) ^ (h & 7)) << 3)] = vv;
    }
    __syncthreads();
#pragma unroll
    for (int kk = 0; kk < 2; kk++) {
      short8 a[2], bb[4];
#pragma unroll
      for (int ti = 0; ti < 2; ti++)
        a[ti] = *(const short8*)&As[(wm * 32 + ti * 16 + c) * 64 + ((kk * 4 + q) ^ (c & 7)) * 8];
#pragma unroll
      for (int tj = 0; tj < 4; tj++)
        bb[tj] = *(const short8*)&Bs[(wn * 64 + tj * 16 + c) * 64 + ((kk * 4 + q) ^ (c & 7)) * 8];
#pragma unroll
      for (int ti = 0; ti < 2; ti++)
#pragma unroll
        for (int tj = 0; tj < 4; tj++)
          acc[ti][tj] = __builtin_amdgcn_mfma_f32_16x16x32_bf16(a[ti], bb[tj], acc[ti][tj], 0, 0, 0);
    }
    __syncthreads();
  }
#pragma unroll
  for (int ti = 0; ti < 2; ti++)
#pragma unroll
    for (int rr = 0; rr < 4; rr++) {
      int m = wm * 32 + ti * 16 + q * 4 + rr;
      const float* ps = psum + ((size_t)(b * 64 + m)) * 8;
      float s = ps[0] + ps[1] + ps[2] + ps[3] + ps[4] + ps[5] + ps[6] + ps[7];
      float inv = 1.f / s;
      unsigned short* op = lfeat + ((size_t)b * 64 + m) * 512 + n0 + wn * 64;
#pragma unroll
      for (int tj = 0; tj < 4; tj++) op[tj * 16 + c] = f2bf(acc[ti][tj][rr] * inv);
    }
}

// ---------------------------------------------------------------------------
// qbW1T[b,512n,64q] = (qb_bf[b] @ lf_w1)^T, bf16.
__global__ __launch_bounds__(256) void k_qbw1(const unsigned short* __restrict__ qbf,
                                              const unsigned short* __restrict__ W1t,
                                              unsigned short* __restrict__ qbW1T) {
  __shared__ unsigned short As[64 * 64];
  __shared__ unsigned short Bs[128 * 64];
  const int b = blockIdx.y, n0 = blockIdx.x * 128;
  const int t = threadIdx.x, w = t >> 6, lane = t & 63, c = lane & 15, q = lane >> 4;
  const int wm = w >> 1, wn = w & 1;
  floatx4 acc[2][4];
#pragma unroll
  for (int ti = 0; ti < 2; ti++)
#pragma unroll
    for (int tj = 0; tj < 4; tj++) acc[ti][tj] = (floatx4){0.f, 0.f, 0.f, 0.f};

  for (int k0 = 0; k0 < 512; k0 += 64) {
#pragma unroll
    for (int i = 0; i < 2; i++) {
      int s = i * 256 + t, row = s >> 3, src = (s & 7) ^ (row & 7);
      GLD_LDS16(qbf + ((size_t)b * 64 + row) * 512 + k0 + src * 8,
                &As[(i * 256 + w * 64) * 8]);
    }
#pragma unroll
    for (int i = 0; i < 4; i++) {
      int s = i * 256 + t, row = s >> 3, src = (s & 7) ^ (row & 7);
      GLD_LDS16(W1t + (size_t)(n0 + row) * 512 + k0 + src * 8,
                &Bs[(i * 256 + w * 64) * 8]);
    }
    __syncthreads();
#pragma unroll
    for (int kk = 0; kk < 2; kk++) {
      short8 a[2], bb[4];
#pragma unroll
      for (int ti = 0; ti < 2; ti++)
        a[ti] = *(const short8*)&As[(wm * 32 + ti * 16 + c) * 64 + ((kk * 4 + q) ^ (c & 7)) * 8];
#pragma unroll
      for (int tj = 0; tj < 4; tj++)
        bb[tj] = *(const short8*)&Bs[(wn * 64 + tj * 16 + c) * 64 + ((kk * 4 + q) ^ (c & 7)) * 8];
#pragma unroll
      for (int ti = 0; ti < 2; ti++)
#pragma unroll
        for (int tj = 0; tj < 4; tj++)
          acc[ti][tj] = __builtin_amdgcn_mfma_f32_16x16x32_bf16(a[ti], bb[tj], acc[ti][tj], 0, 0, 0);
    }
    __syncthreads();
  }
#pragma unroll
  for (int ti = 0; ti < 2; ti++)
#pragma unroll
    for (int tj = 0; tj < 4; tj++) {
      int n = n0 + wn * 64 + tj * 16 + c;
      int m = wm * 32 + ti * 16 + q * 4;
      uint2 p;
      p.x = pk2(acc[ti][tj][0], acc[ti][tj][1]);
      p.y = pk2(acc[ti][tj][2], acc[ti][tj][3]);
      *(uint2*)&qbW1T[((size_t)b * 512 + n) * 64 + m] = p;
    }
}

// ---------------------------------------------------------------------------
// lp_i partials: A = P1[b,256,64], B = qbW1T[b,512,64]. K=64. Fused relu*w2.
__global__ __launch_bounds__(256) void k_logits_i64(
    const unsigned short* __restrict__ P1, const unsigned short* __restrict__ qbW1T,
    const float* __restrict__ b1, const float* __restrict__ w2,
    float* __restrict__ outp) {
  __shared__ unsigned short As[128 * 64];
  __shared__ unsigned short Bs[128 * 64];
  __shared__ float red[2][128];
  const int b = blockIdx.y;
  const int mt = blockIdx.x & 1, nc = blockIdx.x >> 1;
  const int m0 = mt * 128, n0 = nc * 128;
  const int t = threadIdx.x, w = t >> 6, lane = t & 63, c = lane & 15, q = lane >> 4;
  const int wm = w >> 1, wn = w & 1;

#pragma unroll
  for (int i = 0; i < 4; i++) {
    int s = i * 256 + t, row = s >> 3, src = (s & 7) ^ (row & 7);
    GLD_LDS16(P1 + ((size_t)b * 256 + m0 + row) * 64 + src * 8, &As[(i * 256 + w * 64) * 8]);
  }
#pragma unroll
  for (int i = 0; i < 4; i++) {
    int s = i * 256 + t, row = s >> 3, src = (s & 7) ^ (row & 7);
    GLD_LDS16(qbW1T + ((size_t)b * 512 + n0 + row) * 64 + src * 8, &Bs[(i * 256 + w * 64) * 8]);
  }
  __syncthreads();
  floatx4 acc[4][4];
#pragma unroll
  for (int ti = 0; ti < 4; ti++)
#pragma unroll
    for (int tj = 0; tj < 4; tj++) acc[ti][tj] = (floatx4){0.f, 0.f, 0.f, 0.f};
#pragma unroll
  for (int kk = 0; kk < 2; kk++) {
    short8 a[4], bb[4];
#pragma unroll
    for (int ti = 0; ti < 4; ti++)
      a[ti] = *(const short8*)&As[(wm * 64 + ti * 16 + c) * 64 + ((kk * 4 + q) ^ (c & 7)) * 8];
#pragma unroll
    for (int tj = 0; tj < 4; tj++)
      bb[tj] = *(const short8*)&Bs[(wn * 64 + tj * 16 + c) * 64 + ((kk * 4 + q) ^ (c & 7)) * 8];
#pragma unroll
    for (int ti = 0; ti < 4; ti++)
#pragma unroll
      for (int tj = 0; tj < 4; tj++)
        acc[ti][tj] = __builtin_amdgcn_mfma_f32_16x16x32_bf16(a[ti], bb[tj], acc[ti][tj], 0, 0, 0);
  }

  float partial[4][4] = {};
#pragma unroll
  for (int tj = 0; tj < 4; tj++) {
    int n = n0 + wn * 64 + tj * 16 + c;
    float bia = b1[n], wwv = w2[n];
#pragma unroll
    for (int ti = 0; ti < 4; ti++)
#pragma unroll
      for (int r = 0; r < 4; r++)
        partial[ti][r] += fmaxf(acc[ti][tj][r] + bia, 0.f) * wwv;
  }
#pragma unroll
  for (int msk = 1; msk <= 8; msk <<= 1)
#pragma unroll
    for (int ti = 0; ti < 4; ti++)
#pragma unroll
      for (int r = 0; r < 4; r++)
        partial[ti][r] += __shfl_xor(partial[ti][r], msk, 64);
  if (c == 0) {
#pragma unroll
    for (int ti = 0; ti < 4; ti++)
#pragma unroll
      for (int r = 0; r < 4; r++)
        red[wn][wm * 64 + ti * 16 + q * 4 + r] = partial[ti][r];
  }
  __syncthreads();
  if (t < 128) outp[(size_t)nc * 65536 + b * 256 + m0 + t] = red[0][t] + red[1][t];
}

// ---------------------------------------------------------------------------
// Partial logits (l-side).
__global__ __launch_bounds__(256) void k_logits_part(
    const unsigned short* __restrict__ X, const unsigned short* __restrict__ W1t,
    const float* __restrict__ b1, const float* __restrict__ w2,
    float* __restrict__ outp, int M) {
  __shared__ unsigned short As[128 * 64];
  __shared__ unsigned short Bs[128 * 64];
  __shared__ float red[2][128];
  const int t = threadIdx.x, w = t >> 6, lane = t & 63;
  const int wm = w >> 1, wn = w & 1, c = lane & 15, q = lane >> 4;
  const int idx = blockIdx.x;
  const int m_tile = (idx & 7) + ((idx >> 5) << 3), nc = (idx >> 3) & 3;
  const int m0 = m_tile * 128, n0 = nc * 128;

  floatx4 acc[4][4];
#pragma unroll
  for (int ti = 0; ti < 4; ti++)
#pragma unroll
    for (int tj = 0; tj < 4; tj++) acc[ti][tj] = (floatx4){0.f, 0.f, 0.f, 0.f};

  for (int k0 = 0; k0 < 512; k0 += 64) {
#pragma unroll
    for (int it = 0; it < 4; it++) {
      int s = it * 256 + t, row = s >> 3, src = (s & 7) ^ (row & 7);
      GLD_LDS16(X + (size_t)(m0 + row) * 512 + k0 + src * 8, &As[(it * 256 + w * 64) * 8]);
      GLD_LDS16(W1t + (size_t)(n0 + row) * 512 + k0 + src * 8, &Bs[(it * 256 + w * 64) * 8]);
    }
    __syncthreads();
#pragma unroll
    for (int kk = 0; kk < 2; kk++) {
      short8 a[4], bb[4];
#pragma unroll
      for (int ti = 0; ti < 4; ti++)
        a[ti] = *(const short8*)&As[(wm * 64 + ti * 16 + c) * 64 + ((kk * 4 + q) ^ (c & 7)) * 8];
#pragma unroll
      for (int tj = 0; tj < 4; tj++)
        bb[tj] = *(const short8*)&Bs[(wn * 64 + tj * 16 + c) * 64 + ((kk * 4 + q) ^ (c & 7)) * 8];
#pragma unroll
      for (int ti = 0; ti < 4; ti++)
#pragma unroll
        for (int tj = 0; tj < 4; tj++)
          acc[ti][tj] = __builtin_amdgcn_mfma_f32_16x16x32_bf16(a[ti], bb[tj], acc[ti][tj], 0, 0, 0);
    }
    __syncthreads();
  }
  float partial[4][4] = {};
#pragma unroll
  for (int tj = 0; tj < 4; tj++) {
    int n = n0 + wn * 64 + tj * 16 + c;
    float bia = b1[n], wwv = w2[n];
#pragma unroll
    for (int ti = 0; ti < 4; ti++)
#pragma unroll
      for (int r = 0; r < 4; r++)
        partial[ti][r] += fmaxf(acc[ti][tj][r] + bia, 0.f) * wwv;
  }
#pragma unroll
  for (int msk = 1; msk <= 8; msk <<= 1)
#pragma unroll
    for (int ti = 0; ti < 4; ti++)
#pragma unroll
      for (int r = 0; r < 4; r++)
        partial[ti][r] += __shfl_xor(partial[ti][r], msk, 64);
  if (c == 0) {
#pragma unroll
    for (int ti = 0; ti < 4; ti++)
#pragma unroll
      for (int r = 0; r < 4; r++)
        red[wn][wm * 64 + ti * 16 + q * 4 + r] = partial[ti][r];
  }
  __syncthreads();
  if (t < 128) outp[(size_t)nc * M + m0 + t] = red[0][t] + red[1][t];
}

// ---------------------------------------------------------------------------
// Fused i-side epilogue: softmax(lp_i w/ imask) -> i_weight out + att in LDS;
// v = att^T @ P1 ; pooled_i = sum_l v[l] * qb[b,l,:].
__global__ __launch_bounds__(256) void k_final_i(const float* __restrict__ lp,
                                                 const int* __restrict__ imask,
                                                 const unsigned short* __restrict__ P1,
                                                 const unsigned short* __restrict__ qbf,
                                                 float* __restrict__ iw_out,
                                                 unsigned short* __restrict__ pooled) {
  __shared__ float red4[4];
  __shared__ float ar[256];
  __shared__ float red[4][64];
  __shared__ float vsm[64];
  const int b = blockIdx.x, t = threadIdx.x;
  const int i = b * 256 + t;
  float x = lp[i] + lp[65536 + i] + lp[131072 + i] + lp[196608 + i];
  float v = imask[i] ? -1e9f : x;
  float wmx = wave_max(v);
  if ((t & 63) == 0) red4[t >> 6] = wmx;
  __syncthreads();
  float mx = fmaxf(fmaxf(red4[0], red4[1]), fmaxf(red4[2], red4[3]));
  __syncthreads();
  float e = __expf(v - mx);
  float ws = wave_sum(e);
  if ((t & 63) == 0) red4[t >> 6] = ws;
  __syncthreads();
  float s = red4[0] + red4[1] + red4[2] + red4[3];
  float p = e / s;
  iw_out[i] = p;
  ar[t] = p;
  __syncthreads();
  // v[64] = att^T @ P1
  const int part = t >> 6, lane = t & 63;
  const unsigned short* Pb = P1 + ((size_t)b * 256 + part * 64) * 64 + lane;
  float s0 = 0.f, s1 = 0.f;
#pragma unroll 8
  for (int ii = 0; ii < 64; ii += 2) {
    s0 += ar[part * 64 + ii] * bf2f(Pb[(size_t)ii * 64]);
    s1 += ar[part * 64 + ii + 1] * bf2f(Pb[(size_t)(ii + 1) * 64]);
  }
  red[part][lane] = s0 + s1;
  __syncthreads();
  if (t < 64) vsm[t] = red[0][t] + red[1][t] + red[2][t] + red[3][t];
  __syncthreads();
  // pooled_i over qb_bf, L=64
  float a0 = 0.f, a1 = 0.f;
  const unsigned short* Xb = qbf + (size_t)b * 64 * 512 + 2 * t;
#pragma unroll 4
  for (int l = 0; l < 64; l++) {
    unsigned u = *(const unsigned*)&Xb[(size_t)l * 512];
    float a = vsm[l];
    a0 += a * bf2f((unsigned short)(u & 0xffff));
    a1 += a * bf2f((unsigned short)(u >> 16));
  }
  *(unsigned*)&pooled[(size_t)b * 1024 + 2 * t] = pk2(a0, a1);
}

// ---------------------------------------------------------------------------
// Fused l-side epilogue: softmax(lp_l w/ qmask) in LDS; pooled_l from lfeat.
__global__ __launch_bounds__(256) void k_final_l(const float* __restrict__ lp,
                                                 const int* __restrict__ qmask,
                                                 const unsigned short* __restrict__ lfeat,
                                                 unsigned short* __restrict__ pooled) {
  __shared__ float ar[64];
  const int b = blockIdx.x, t = threadIdx.x;
  if (t < 64) {
    const int i = b * 64 + t;
    float x = lp[i] + lp[16384 + i] + lp[32768 + i] + lp[49152 + i];
    float v = qmask[i] ? -1e9f : x;
    float mx = wave_max(v);
    float e = __expf(v - mx);
    float s = wave_sum(e);
    ar[t] = e / s;
  }
  __syncthreads();
  float a0 = 0.f, a1 = 0.f;
  const unsigned short* Xb = lfeat + (size_t)b * 64 * 512 + 2 * t;
#pragma unroll 4
  for (int l = 0; l < 64; l++) {
    unsigned u = *(const unsigned*)&Xb[(size_t)l * 512];
    float a = ar[l];
    a0 += a * bf2f((unsigned short)(u & 0xffff));
    a1 += a * bf2f((unsigned short)(u >> 16));
  }
  *(unsigned*)&pooled[(size_t)b * 1024 + 512 + 2 * t] = pk2(a0, a1);
}

// ---------------------------------------------------------------------------
// Epilogue GEMM: out[M,N] = X[M,K]bf16 @ Wt[N,K]bf16 + biasA (+biasB).
__global__ __launch_bounds__(256) void k_egemm(const unsigned short* __restrict__ X,
                                               const unsigned short* __restrict__ Wt,
                                               const float* __restrict__ biasA,
                                               const float* __restrict__ biasB,
                                               float* __restrict__ outf,
                                               unsigned short* __restrict__ outbf,
                                               int N, int K) {
  __shared__ unsigned short As[64 * 64];
  __shared__ unsigned short Bs[64 * 64];
  const int n0 = blockIdx.x * 64, m0 = blockIdx.y * 64;
  const int t = threadIdx.x, w = t >> 6, lane = t & 63, c = lane & 15, q = lane >> 4;
  const int wm = w >> 1, wn = w & 1;
  floatx4 acc[2][2];
#pragma unroll
  for (int ti = 0; ti < 2; ti++)
#pragma unroll
    for (int tj = 0; tj < 2; tj++) acc[ti][tj] = (floatx4){0.f, 0.f, 0.f, 0.f};

  for (int k0 = 0; k0 < K; k0 += 64) {
#pragma unroll
    for (int i = 0; i < 2; i++) {
      int s = i * 256 + t, row = s >> 3, src = (s & 7) ^ (row & 7);
      GLD_LDS16(X + (size_t)(m0 + row) * K + k0 + src * 8, &As[(i * 256 + w * 64) * 8]);
      GLD_LDS16(Wt + (size_t)(n0 + row) * K + k0 + src * 8, &Bs[(i * 256 + w * 64) * 8]);
    }
    __syncthreads();
#pragma unroll
    for (int kk = 0; kk < 2; kk++) {
      short8 a[2], bb[2];
#pragma unroll
      for (int ti = 0; ti < 2; ti++)
        a[ti] = *(const short8*)&As[(wm * 32 + ti * 16 + c) * 64 + ((kk * 4 + q) ^ (c & 7)) * 8];
#pragma unroll
      for (int tj = 0; tj < 2; tj++)
        bb[tj] = *(const short8*)&Bs[(wn * 32 + tj * 16 + c) * 64 + ((kk * 4 + q) ^ (c & 7)) * 8];
#pragma unroll
      for (int ti = 0; ti < 2; ti++)
#pragma unroll
        for (int tj = 0; tj < 2; tj++)
          acc[ti][tj] = __builtin_amdgcn_mfma_f32_16x16x32_bf16(a[ti], bb[tj], acc[ti][tj], 0, 0, 0);
    }
    __syncthreads();
  }
#pragma unroll
  for (int tj = 0; tj < 2; tj++) {
    int n = n0 + wn * 32 + tj * 16 + c;
    float bias = biasA[n] + (biasB ? biasB[n] : 0.f);
#pragma unroll
    for (int ti = 0; ti < 2; ti++)
#pragma unroll
      for (int rr = 0; rr < 4; rr++) {
        int m = m0 + wm * 32 + ti * 16 + q * 4 + rr;
        float v = acc[ti][tj][rr] + bias;
        if (outbf) outbf[(size_t)m * N + n] = f2bf(v);
        else outf[(size_t)m * N + n] = v;
      }
  }
}

// ---------------------------------------------------------------------------
extern "C" void kernel_launch(void* const* d_in, const int* in_sizes, int n_in,
                              void* d_out, int out_size, void* d_ws, size_t ws_size,
                              hipStream_t stream) {
  const float* ib = (const float*)d_in[0];
  const float* qb = (const float*)d_in[1];
  const int* imask = (const int*)d_in[2];
  const int* qmask = (const int*)d_in[3];
  const float* lf_w1 = (const float*)d_in[4];
  const float* lf_b1 = (const float*)d_in[5];
  const float* lf_w2 = (const float*)d_in[6];
  const float* lf_wm = (const float*)d_in[8];
  const float* lf_bm = (const float*)d_in[9];
  const float* if_w1 = (const float*)d_in[10];
  const float* if_b1 = (const float*)d_in[11];
  const float* if_w2 = (const float*)d_in[12];
  const float* if_wm = (const float*)d_in[14];
  const float* if_bm = (const float*)d_in[15];
  const float* fh_w = (const float*)d_in[16];
  const float* fh_b = (const float*)d_in[17];
  float* out = (float*)d_out;  // [256*512] out, then [256*256] i_weight

  float* lp_i = (float*)d_ws;              // 262,144 (4 x 65536)
  float* lp_l = lp_i + 262144;             // 65,536 (4 x 16384)
  float* att_i = lp_l + 65536;             // 65,536 (unused, kept for layout)
  float* att_l = att_i + 65536;            // 16,384 (unused)
  float* psum = att_l + 16384;             // 131,072 (16384 x 8)
  unsigned short* P1 = (unsigned short*)(psum + 131072);  // 4,194,304
  unsigned short* P2 = P1 + 4194304;                      // 4,194,304
  unsigned short* lfeat = P2 + 4194304;                   // 33,554,432 slot
  unsigned short* qb_bf = lfeat + 33554432;               // 8,388,608
  unsigned short* qbW1T = qb_bf + 8388608;                // 8,388,608
  unsigned short* ibT_unused = qbW1T + 8388608;           // 33,554,432 (dead)
  unsigned short* w1t_lf = ibT_unused + 33554432;         // 262,144
  unsigned short* w1t_if = w1t_lf + 262144;               // 262,144
  unsigned short* wcat_t = w1t_if + 262144;               // 1,048,576
  unsigned short* fh_wt = wcat_t + 1048576;               // 524,288
  unsigned short* pooled_bf = fh_wt + 524288;             // 262,144
  unsigned short* F_bf = pooled_bf + 262144;              // 262,144

  k_prep<<<2560, 256, 0, stream>>>(qb, lf_w1, if_w1, lf_wm, if_wm, fh_w,
                                   qb_bf, w1t_lf, w1t_if, wcat_t, fh_wt);

  k_scores_f<<<dim3(2, 256), 256, 0, stream>>>(ib, qb_bf, imask, qmask, P1, P2, psum);
  k_av2<<<dim3(4, 256), 256, 0, stream>>>(P2, ib, psum, lfeat);
  k_qbw1<<<dim3(4, 256), 256, 0, stream>>>(qb_bf, w1t_lf, qbW1T);
  k_logits_i64<<<dim3(8, 256), 256, 0, stream>>>(P1, qbW1T, lf_b1, lf_w2, lp_i);
  k_logits_part<<<512, 256, 0, stream>>>(lfeat, w1t_if, if_b1, if_w2, lp_l, 16384);
  k_final_i<<<256, 256, 0, stream>>>(lp_i, imask, P1, qb_bf, out + 131072, pooled_bf);
  k_final_l<<<256, 256, 0, stream>>>(lp_l, qmask, lfeat, pooled_bf);

  k_egemm<<<dim3(16, 4), 256, 0, stream>>>(pooled_bf, wcat_t, lf_bm, if_bm,
                                           nullptr, F_bf, 1024, 1024);
  k_egemm<<<dim3(8, 4), 256, 0, stream>>>(F_bf, fh_wt, fh_b, nullptr,
                                          out, nullptr, 512, 1024);
}

// Round 6
// 371.469 us; speedup vs baseline: 1.2575x; 1.0265x over previous
//
#include <hip/hip_runtime.h>
#include <math.h>

// ---------------------------------------------------------------------------
// BiAttention round 12: VALU-staging + occupancy pass (no dataflow change).
//  - pk2 -> v_cvt_pk_bf16_f32 (1 instr vs ~7; RNE, bit-identical for finite).
//  - k_scores_f: X unioned onto As+Bs (X only live post-K-loop): 42->24 KB
//    LDS, 3->6 blocks/CU.
//  - k_av2: Tb->Bs transpose done IN PLACE (gather->regs, barrier, write
//    back into Tb's buffer): 40->24 KB LDS, 4->6 blocks/CU.
//  - k_final_i + k_final_l fused (grid 512, -1 launch).
//  - everything else identical to verified R11.
// Fragment scheme (verified R2..R11): A/B frag row = lane&15, k-group
// (lane>>4)*8 contiguous, XOR swizzle (colgroup ^ (row&7));
// C/D: col = lane&15, row = (lane>>4)*4 + r.
// ---------------------------------------------------------------------------

#define SCALE 0.04419417382415922f  // 1/sqrt(512)

typedef __attribute__((ext_vector_type(8))) short short8;
typedef __attribute__((ext_vector_type(4))) float floatx4;

__device__ __forceinline__ unsigned short f2bf(float x) {
  unsigned u = __float_as_uint(x);
  unsigned r = u + 0x7FFFu + ((u >> 16) & 1u);
  return (unsigned short)(r >> 16);
}
__device__ __forceinline__ float bf2f(unsigned short h) {
  return __uint_as_float(((unsigned)h) << 16);
}
// Packed f32x2 -> bf16x2, RNE (hardware). lo = a, hi = b.
__device__ __forceinline__ unsigned pk2(float a, float b) {
  unsigned r;
  asm("v_cvt_pk_bf16_f32 %0, %1, %2" : "=v"(r) : "v"(a), "v"(b));
  return r;
}

__device__ __forceinline__ float wave_max(float v) {
#pragma unroll
  for (int o = 32; o > 0; o >>= 1) v = fmaxf(v, __shfl_xor(v, o, 64));
  return v;
}
__device__ __forceinline__ float wave_sum(float v) {
#pragma unroll
  for (int o = 32; o > 0; o >>= 1) v += __shfl_xor(v, o, 64);
  return v;
}

#define GLD_LDS16(gptr, lptr)                                             \
  __builtin_amdgcn_global_load_lds(                                       \
      (const __attribute__((address_space(1))) void*)(gptr),              \
      (__attribute__((address_space(3))) void*)(lptr), 16, 0, 0)

// ---------------------------------------------------------------------------
// Merged prep: idx<512 weights; [512,2560) qb pure stream convert.
__global__ __launch_bounds__(256) void k_prep(
    const float* __restrict__ qb, const float* __restrict__ lf_w1,
    const float* __restrict__ if_w1, const float* __restrict__ lf_wm,
    const float* __restrict__ if_wm, const float* __restrict__ fh_w,
    unsigned short* __restrict__ qb_bf, unsigned short* __restrict__ w1t_lf,
    unsigned short* __restrict__ w1t_if, unsigned short* __restrict__ wcat_t,
    unsigned short* __restrict__ fh_wt) {
  __shared__ __align__(16) char smem[64 * 65 * 4];  // 16640 B
  const int idx = blockIdx.x, t = threadIdx.x;

  if (idx < 512) {
    // ---- weights: f32 [K,N] -> bf16 [N, koff+K] (stride 65: conflict-free)
    float(*T)[65] = (float(*)[65])smem;
    const float* src;
    unsigned short* dst;
    int N, ds, koff, k0, n0;
    if (idx < 64) {
      src = lf_w1; dst = w1t_lf; N = 512; ds = 512; koff = 0;
      k0 = (idx & 7) * 64; n0 = (idx >> 3) * 64;
    } else if (idx < 128) {
      int l = idx - 64;
      src = if_w1; dst = w1t_if; N = 512; ds = 512; koff = 0;
      k0 = (l & 7) * 64; n0 = (l >> 3) * 64;
    } else if (idx < 256) {
      int l = idx - 128;
      src = lf_wm; dst = wcat_t; N = 1024; ds = 1024; koff = 0;
      k0 = (l & 7) * 64; n0 = (l >> 3) * 64;
    } else if (idx < 384) {
      int l = idx - 256;
      src = if_wm; dst = wcat_t; N = 1024; ds = 1024; koff = 512;
      k0 = (l & 7) * 64; n0 = (l >> 3) * 64;
    } else {
      int l = idx - 384;
      src = fh_w; dst = fh_wt; N = 512; ds = 1024; koff = 0;
      k0 = (l & 15) * 64; n0 = (l >> 4) * 64;
    }
#pragma unroll
    for (int i = 0; i < 16; i++) {
      int e = t + i * 256, r = e >> 6, c = e & 63;
      T[r][c] = src[(size_t)(k0 + r) * N + n0 + c];
    }
    __syncthreads();
#pragma unroll
    for (int i = 0; i < 8; i++) {
      int e = t + i * 256, r = e >> 5, c2 = (e & 31) * 2;
      *(unsigned*)&dst[(size_t)(n0 + r) * ds + koff + k0 + c2] =
          pk2(T[c2][r], T[c2 + 1][r]);
    }
  } else {
    // ---- qb f32 -> bf16 pure stream ----
    int j = idx - 512;  // 2048 blocks x 4096 floats
    const float4* src = (const float4*)(qb + (size_t)j * 4096);
    uint2* dst = (uint2*)(qb_bf + (size_t)j * 4096);
#pragma unroll
    for (int i = 0; i < 4; i++) {
      int e = t + i * 256;
      float4 v = src[e];
      uint2 p;
      p.x = pk2(v.x, v.y);
      p.y = pk2(v.z, v.w);
      dst[e] = p;
    }
  }
}

// ---------------------------------------------------------------------------
// Fused scores: per (i-chunk, batch). S[64q x 128i] = qb @ ib^T * SCALE.
// B operand staged directly from f32 ib with inline bf16 convert. X (exp /
// P1 staging) unioned onto As+Bs (only live after the K loop): 24 KB LDS.
__global__ __launch_bounds__(256) void k_scores_f(
    const float* __restrict__ ib, const unsigned short* __restrict__ qbf,
    const int* __restrict__ imask, const int* __restrict__ qmask,
    unsigned short* __restrict__ P1, unsigned short* __restrict__ P2,
    float* __restrict__ psum) {
  __shared__ __align__(16) unsigned short U[64 * 64 + 128 * 64];  // 24576 B
  unsigned short* As = U;            // [64][64]
  unsigned short* Bs = U + 64 * 64;  // [128][64]
  unsigned short* X = U;             // E:[64][136] / Pl:[128][72], post-loop
  const int b = blockIdx.y, ic = blockIdx.x, i0 = ic * 128;
  const int t = threadIdx.x, w = t >> 6, lane = t & 63, c = lane & 15, qq = lane >> 4;

  floatx4 acc[4][2];
#pragma unroll
  for (int ti = 0; ti < 4; ti++)
#pragma unroll
    for (int tj = 0; tj < 2; tj++) acc[ti][tj] = (floatx4){0.f, 0.f, 0.f, 0.f};

  for (int k0 = 0; k0 < 512; k0 += 64) {
#pragma unroll
    for (int i = 0; i < 2; i++) {
      int s = i * 256 + t, row = s >> 3, src = (s & 7) ^ (row & 7);
      GLD_LDS16(qbf + ((size_t)b * 64 + row) * 512 + k0 + src * 8,
                &As[(i * 256 + w * 64) * 8]);
    }
    // B: [128 i][64 h] from f32 ib, inline convert. 2048 float4 slots.
#pragma unroll
    for (int i = 0; i < 8; i++) {
      int s = i * 256 + t, row = s >> 4, c4 = s & 15;
      float4 v = *(const float4*)&ib[((size_t)b * 256 + i0 + row) * 512 + k0 + c4 * 4];
      int gs = (c4 >> 1) ^ (row & 7), sub = c4 & 1;
      uint2 p;
      p.x = pk2(v.x, v.y);
      p.y = pk2(v.z, v.w);
      *(uint2*)&Bs[row * 64 + gs * 8 + sub * 4] = p;
    }
    __syncthreads();
#pragma unroll
    for (int kk = 0; kk < 2; kk++) {
      short8 a[4], bb[2];
#pragma unroll
      for (int ti = 0; ti < 4; ti++)
        a[ti] = *(const short8*)&As[(ti * 16 + c) * 64 + ((kk * 4 + qq) ^ (c & 7)) * 8];
#pragma unroll
      for (int tj = 0; tj < 2; tj++)
        bb[tj] = *(const short8*)&Bs[(w * 32 + tj * 16 + c) * 64 + ((kk * 4 + qq) ^ (c & 7)) * 8];
#pragma unroll
      for (int ti = 0; ti < 4; ti++)
#pragma unroll
        for (int tj = 0; tj < 2; tj++)
          acc[ti][tj] = __builtin_amdgcn_mfma_f32_16x16x32_bf16(a[ti], bb[tj], acc[ti][tj], 0, 0, 0);
    }
    __syncthreads();
  }

  const int il0 = w * 32 + c;  // tj=0 local i; tj=1 is il0+16
  int imsk0 = imask[b * 256 + i0 + il0];
  int imsk1 = imask[b * 256 + i0 + il0 + 16];
  int qm[4][4];
#pragma unroll
  for (int ti = 0; ti < 4; ti++)
#pragma unroll
    for (int rr = 0; rr < 4; rr++) qm[ti][rr] = qmask[b * 64 + ti * 16 + qq * 4 + rr];

  // ---- E phase: raw exp (imask) into X[64][136], per-wave row sums ----
#pragma unroll
  for (int ti = 0; ti < 4; ti++)
#pragma unroll
    for (int rr = 0; rr < 4; rr++) {
      int qv = ti * 16 + qq * 4 + rr;
      float e0 = imsk0 ? 0.f : __expf(acc[ti][0][rr] * SCALE);
      float e1 = imsk1 ? 0.f : __expf(acc[ti][1][rr] * SCALE);
      X[qv * 136 + il0] = f2bf(e0);
      X[qv * 136 + il0 + 16] = f2bf(e1);
      float s = e0 + e1;
#pragma unroll
      for (int o = 1; o <= 8; o <<= 1) s += __shfl_xor(s, o, 64);
      if (c == 0) psum[((size_t)(b * 64 + qv)) * 8 + ic * 4 + w] = s;
    }
  __syncthreads();
#pragma unroll
  for (int i = 0; i < 4; i++) {
    int e2 = t + i * 256, qv = e2 >> 4, g = e2 & 15;
    *(uint4*)&P2[((size_t)b * 64 + qv) * 256 + i0 + g * 8] = *(const uint4*)&X[qv * 136 + g * 8];
  }
  __syncthreads();

  // ---- P1 phase: column softmax over q (qmask), normalized, into X[128][72]
#pragma unroll
  for (int tj = 0; tj < 2; tj++) {
    float ev[4][4];
    float s1 = 0.f;
#pragma unroll
    for (int ti = 0; ti < 4; ti++)
#pragma unroll
      for (int rr = 0; rr < 4; rr++) {
        ev[ti][rr] = qm[ti][rr] ? 0.f : __expf(acc[ti][tj][rr] * SCALE);
        s1 += ev[ti][rr];
      }
    s1 += __shfl_xor(s1, 16, 64);
    s1 += __shfl_xor(s1, 32, 64);
    float inv = 1.f / s1;
    int il = il0 + tj * 16;
#pragma unroll
    for (int ti = 0; ti < 4; ti++)
#pragma unroll
      for (int rr = 0; rr < 4; rr++)
        X[il * 72 + ti * 16 + qq * 4 + rr] = f2bf(ev[ti][rr] * inv);
  }
  __syncthreads();
#pragma unroll
  for (int i = 0; i < 4; i++) {
    int e2 = t + i * 256, il = e2 >> 3, g = e2 & 7;
    *(uint4*)&P1[((size_t)b * 256 + i0 + il) * 64 + g * 8] = *(const uint4*)&X[il * 72 + g * 8];
  }
}

// ---------------------------------------------------------------------------
// lfeat[b,64,512] = (P2 @ ib) * rowscale. B built in-LDS from f32 ib:
// Tb[64tok][128h] convert+swizzle, then IN-PLACE transpose (gather->regs,
// barrier, write back) into fragment-layout Bs aliasing Tb. 24 KB LDS.
__global__ __launch_bounds__(256) void k_av2(const unsigned short* __restrict__ P2,
                                             const float* __restrict__ ib,
                                             const float* __restrict__ psum,
                                             unsigned short* __restrict__ lfeat) {
  __shared__ unsigned short As[64 * 64];
  __shared__ __align__(16) unsigned short Tb[128 * 64];  // Tb then Bs (aliased)
  const int b = blockIdx.y, n0 = blockIdx.x * 128;
  const int t = threadIdx.x, w = t >> 6, lane = t & 63, c = lane & 15, q = lane >> 4;
  const int wm = w >> 1, wn = w & 1;
  floatx4 acc[2][4];
#pragma unroll
  for (int ti = 0; ti < 2; ti++)
#pragma unroll
    for (int tj = 0; tj < 4; tj++) acc[ti][tj] = (floatx4){0.f, 0.f, 0.f, 0.f};

  for (int kc = 0; kc < 256; kc += 64) {
    // A: P2 tile via global_load_lds
#pragma unroll
    for (int i = 0; i < 2; i++) {
      int s = i * 256 + t, row = s >> 3, src = (s & 7) ^ (row & 7);
      GLD_LDS16(P2 + ((size_t)b * 64 + row) * 256 + kc + src * 8, &As[(i * 256 + w * 64) * 8]);
    }
    // Tb: f32 ib [64 tok][128 h] convert + 16B-group XOR swizzle
#pragma unroll
    for (int i = 0; i < 8; i++) {
      int e = i * 256 + t, tok = e >> 5, h4 = (e & 31) * 4;
      float4 v = *(const float4*)&ib[((size_t)b * 256 + kc + tok) * 512 + n0 + h4];
      uint2 p;
      p.x = pk2(v.x, v.y);
      p.y = pk2(v.z, v.w);
      int col = ((((h4 >> 3) ^ (tok >> 3)) & 15) << 3) | (h4 & 7);
      *(uint2*)&Tb[tok * 128 + col] = p;
    }
    __syncthreads();
    // Gather transpose into regs (all reads complete before any write)
    uint4 vv[4];
#pragma unroll
    for (int i = 0; i < 4; i++) {
      int e = i * 256 + t, h = e >> 3, tc = (e & 7) * 8;
      int hg = h >> 3, ho = h & 7;
      unsigned y[8];
#pragma unroll
      for (int k = 0; k < 8; k++) {
        int r = tc + k;
        y[k] = Tb[r * 128 + (((hg ^ (r >> 3)) & 15) << 3) + ho];
      }
      vv[i].x = y[0] | (y[1] << 16);
      vv[i].y = y[2] | (y[3] << 16);
      vv[i].z = y[4] | (y[5] << 16);
      vv[i].w = y[6] | (y[7] << 16);
    }
    __syncthreads();
    // Write back in-place as Bs [h=128 rows][tok=64], fragment XOR swizzle
#pragma unroll
    for (int i = 0; i < 4; i++) {
      int e = i * 256 + t, h = e >> 3, tc = (e & 7) * 8;
      *(uint4*)&Tb[h * 64 + (((tc >> 3) ^ (h & 7)) << 3)] = vv[i];
    }
    __syncthreads();
    const unsigned short* Bs = Tb;
#pragma unroll
    for (int kk = 0; kk < 2; kk++) {
      short8 a[2], bb[4];
#pragma unroll
      for (int ti = 0; ti < 2; ti++)
        a[ti] = *(const short8*)&As[(wm * 32 + ti * 16 + c) * 64 + ((kk * 4 + q) ^ (c & 7)) * 8];
#pragma unroll
      for (int tj = 0; tj < 4; tj++)
        bb[tj] = *(const short8*)&Bs[(wn * 64 + tj * 16 + c) * 64 + ((kk * 4 + q) ^ (c & 7)) * 8];
#pragma unroll
      for (int ti = 0; ti < 2; ti++)
#pragma unroll
        for (int tj = 0; tj < 4; tj++)
          acc[ti][tj] = __builtin_amdgcn_mfma_f32_16x16x32_bf16(a[ti], bb[tj], acc[ti][tj], 0, 0, 0);
    }
    __syncthreads();
  }
#pragma unroll
  for (int ti = 0; ti < 2; ti++)
#pragma unroll
    for (int rr = 0; rr < 4; rr++) {
      int m = wm * 32 + ti * 16 + q * 4 + rr;
      const float* ps = psum + ((size_t)(b * 64 + m)) * 8;
      float s = ps[0] + ps[1] + ps[2] + ps[3] + ps[4] + ps[5] + ps[6] + ps[7];
      float inv = 1.f / s;
      unsigned short* op = lfeat + ((size_t)b * 64 + m) * 512 + n0 + wn * 64;
#pragma unroll
      for (int tj = 0; tj < 4; tj++) op[tj * 16 + c] = f2bf(acc[ti][tj][rr] * inv);
    }
}

// ---------------------------------------------------------------------------
// qbW1T[b,512n,64q] = (qb_bf[b] @ lf_w1)^T, bf16.
__global__ __launch_bounds__(256) void k_qbw1(const unsigned short* __restrict__ qbf,
                                              const unsigned short* __restrict__ W1t,
                                              unsigned short* __restrict__ qbW1T) {
  __shared__ unsigned short As[64 * 64];
  __shared__ unsigned short Bs[128 * 64];
  const int b = blockIdx.y, n0 = blockIdx.x * 128;
  const int t = threadIdx.x, w = t >> 6, lane = t & 63, c = lane & 15, q = lane >> 4;
  const int wm = w >> 1, wn = w & 1;
  floatx4 acc[2][4];
#pragma unroll
  for (int ti = 0; ti < 2; ti++)
#pragma unroll
    for (int tj = 0; tj < 4; tj++) acc[ti][tj] = (floatx4){0.f, 0.f, 0.f, 0.f};

  for (int k0 = 0; k0 < 512; k0 += 64) {
#pragma unroll
    for (int i = 0; i < 2; i++) {
      int s = i * 256 + t, row = s >> 3, src = (s & 7) ^ (row & 7);
      GLD_LDS16(qbf + ((size_t)b * 64 + row) * 512 + k0 + src * 8,
                &As[(i * 256 + w * 64) * 8]);
    }
#pragma unroll
    for (int i = 0; i < 4; i++) {
      int s = i * 256 + t, row = s >> 3, src = (s & 7) ^ (row & 7);
      GLD_LDS16(W1t + (size_t)(n0 + row) * 512 + k0 + src * 8,
                &Bs[(i * 256 + w * 64) * 8]);
    }
    __syncthreads();
#pragma unroll
    for (int kk = 0; kk < 2; kk++) {
      short8 a[2], bb[4];
#pragma unroll
      for (int ti = 0; ti < 2; ti++)
        a[ti] = *(const short8*)&As[(wm * 32 + ti * 16 + c) * 64 + ((kk * 4 + q) ^ (c & 7)) * 8];
#pragma unroll
      for (int tj = 0; tj < 4; tj++)
        bb[tj] = *(const short8*)&Bs[(wn * 64 + tj * 16 + c) * 64 + ((kk * 4 + q) ^ (c & 7)) * 8];
#pragma unroll
      for (int ti = 0; ti < 2; ti++)
#pragma unroll
        for (int tj = 0; tj < 4; tj++)
          acc[ti][tj] = __builtin_amdgcn_mfma_f32_16x16x32_bf16(a[ti], bb[tj], acc[ti][tj], 0, 0, 0);
    }
    __syncthreads();
  }
#pragma unroll
  for (int ti = 0; ti < 2; ti++)
#pragma unroll
    for (int tj = 0; tj < 4; tj++) {
      int n = n0 + wn * 64 + tj * 16 + c;
      int m = wm * 32 + ti * 16 + q * 4;
      uint2 p;
      p.x = pk2(acc[ti][tj][0], acc[ti][tj][1]);
      p.y = pk2(acc[ti][tj][2], acc[ti][tj][3]);
      *(uint2*)&qbW1T[((size_t)b * 512 + n) * 64 + m] = p;
    }
}

// ---------------------------------------------------------------------------
// lp_i partials: A = P1[b,256,64], B = qbW1T[b,512,64]. K=64. Fused relu*w2.
__global__ __launch_bounds__(256) void k_logits_i64(
    const unsigned short* __restrict__ P1, const unsigned short* __restrict__ qbW1T,
    const float* __restrict__ b1, const float* __restrict__ w2,
    float* __restrict__ outp) {
  __shared__ unsigned short As[128 * 64];
  __shared__ unsigned short Bs[128 * 64];
  __shared__ float red[2][128];
  const int b = blockIdx.y;
  const int mt = blockIdx.x & 1, nc = blockIdx.x >> 1;
  const int m0 = mt * 128, n0 = nc * 128;
  const int t = threadIdx.x, w = t >> 6, lane = t & 63, c = lane & 15, q = lane >> 4;
  const int wm = w >> 1, wn = w & 1;

#pragma unroll
  for (int i = 0; i < 4; i++) {
    int s = i * 256 + t, row = s >> 3, src = (s & 7) ^ (row & 7);
    GLD_LDS16(P1 + ((size_t)b * 256 + m0 + row) * 64 + src * 8, &As[(i * 256 + w * 64) * 8]);
  }
#pragma unroll
  for (int i = 0; i < 4; i++) {
    int s = i * 256 + t, row = s >> 3, src = (s & 7) ^ (row & 7);
    GLD_LDS16(qbW1T + ((size_t)b * 512 + n0 + row) * 64 + src * 8, &Bs[(i * 256 + w * 64) * 8]);
  }
  __syncthreads();
  floatx4 acc[4][4];
#pragma unroll
  for (int ti = 0; ti < 4; ti++)
#pragma unroll
    for (int tj = 0; tj < 4; tj++) acc[ti][tj] = (floatx4){0.f, 0.f, 0.f, 0.f};
#pragma unroll
  for (int kk = 0; kk < 2; kk++) {
    short8 a[4], bb[4];
#pragma unroll
    for (int ti = 0; ti < 4; ti++)
      a[ti] = *(const short8*)&As[(wm * 64 + ti * 16 + c) * 64 + ((kk * 4 + q) ^ (c & 7)) * 8];
#pragma unroll
    for (int tj = 0; tj < 4; tj++)
      bb[tj] = *(const short8*)&Bs[(wn * 64 + tj * 16 + c) * 64 + ((kk * 4 + q) ^ (c & 7)) * 8];
#pragma unroll
    for (int ti = 0; ti < 4; ti++)
#pragma unroll
      for (int tj = 0; tj < 4; tj++)
        acc[ti][tj] = __builtin_amdgcn_mfma_f32_16x16x32_bf16(a[ti], bb[tj], acc[ti][tj], 0, 0, 0);
  }

  float partial[4][4] = {};
#pragma unroll
  for (int tj = 0; tj < 4; tj++) {
    int n = n0 + wn * 64 + tj * 16 + c;
    float bia = b1[n], wwv = w2[n];
#pragma unroll
    for (int ti = 0; ti < 4; ti++)
#pragma unroll
      for (int r = 0; r < 4; r++)
        partial[ti][r] += fmaxf(acc[ti][tj][r] + bia, 0.f) * wwv;
  }
#pragma unroll
  for (int msk = 1; msk <= 8; msk <<= 1)
#pragma unroll
    for (int ti = 0; ti < 4; ti++)
#pragma unroll
      for (int r = 0; r < 4; r++)
        partial[ti][r] += __shfl_xor(partial[ti][r], msk, 64);
  if (c == 0) {
#pragma unroll
    for (int ti = 0; ti < 4; ti++)
#pragma unroll
      for (int r = 0; r < 4; r++)
        red[wn][wm * 64 + ti * 16 + q * 4 + r] = partial[ti][r];
  }
  __syncthreads();
  if (t < 128) outp[(size_t)nc * 65536 + b * 256 + m0 + t] = red[0][t] + red[1][t];
}

// ---------------------------------------------------------------------------
// Partial logits (l-side).
__global__ __launch_bounds__(256) void k_logits_part(
    const unsigned short* __restrict__ X, const unsigned short* __restrict__ W1t,
    const float* __restrict__ b1, const float* __restrict__ w2,
    float* __restrict__ outp, int M) {
  __shared__ unsigned short As[128 * 64];
  __shared__ unsigned short Bs[128 * 64];
  __shared__ float red[2][128];
  const int t = threadIdx.x, w = t >> 6, lane = t & 63;
  const int wm = w >> 1, wn = w & 1, c = lane & 15, q = lane >> 4;
  const int idx = blockIdx.x;
  const int m_tile = (idx & 7) + ((idx >> 5) << 3), nc = (idx >> 3) & 3;
  const int m0 = m_tile * 128, n0 = nc * 128;

  floatx4 acc[4][4];
#pragma unroll
  for (int ti = 0; ti < 4; ti++)
#pragma unroll
    for (int tj = 0; tj < 4; tj++) acc[ti][tj] = (floatx4){0.f, 0.f, 0.f, 0.f};

  for (int k0 = 0; k0 < 512; k0 += 64) {
#pragma unroll
    for (int it = 0; it < 4; it++) {
      int s = it * 256 + t, row = s >> 3, src = (s & 7) ^ (row & 7);
      GLD_LDS16(X + (size_t)(m0 + row) * 512 + k0 + src * 8, &As[(it * 256 + w * 64) * 8]);
      GLD_LDS16(W1t + (size_t)(n0 + row) * 512 + k0 + src * 8, &Bs[(it * 256 + w * 64) * 8]);
    }
    __syncthreads();
#pragma unroll
    for (int kk = 0; kk < 2; kk++) {
      short8 a[4], bb[4];
#pragma unroll
      for (int ti = 0; ti < 4; ti++)
        a[ti] = *(const short8*)&As[(wm * 64 + ti * 16 + c) * 64 + ((kk * 4 + q) ^ (c & 7)) * 8];
#pragma unroll
      for (int tj = 0; tj < 4; tj++)
        bb[tj] = *(const short8*)&Bs[(wn * 64 + tj * 16 + c) * 64 + ((kk * 4 + q) ^ (c & 7)) * 8];
#pragma unroll
      for (int ti = 0; ti < 4; ti++)
#pragma unroll
        for (int tj = 0; tj < 4; tj++)
          acc[ti][tj] = __builtin_amdgcn_mfma_f32_16x16x32_bf16(a[ti], bb[tj], acc[ti][tj], 0, 0, 0);
    }
    __syncthreads();
  }
  float partial[4][4] = {};
#pragma unroll
  for (int tj = 0; tj < 4; tj++) {
    int n = n0 + wn * 64 + tj * 16 + c;
    float bia = b1[n], wwv = w2[n];
#pragma unroll
    for (int ti = 0; ti < 4; ti++)
#pragma unroll
      for (int r = 0; r < 4; r++)
        partial[ti][r] += fmaxf(acc[ti][tj][r] + bia, 0.f) * wwv;
  }
#pragma unroll
  for (int msk = 1; msk <= 8; msk <<= 1)
#pragma unroll
    for (int ti = 0; ti < 4; ti++)
#pragma unroll
      for (int r = 0; r < 4; r++)
        partial[ti][r] += __shfl_xor(partial[ti][r], msk, 64);
  if (c == 0) {
#pragma unroll
    for (int ti = 0; ti < 4; ti++)
#pragma unroll
      for (int r = 0; r < 4; r++)
        red[wn][wm * 64 + ti * 16 + q * 4 + r] = partial[ti][r];
  }
  __syncthreads();
  if (t < 128) outp[(size_t)nc * M + m0 + t] = red[0][t] + red[1][t];
}

// ---------------------------------------------------------------------------
// Fused epilogues. Blocks [0,256): i-side (softmax -> i_weight + att in LDS;
// v = att^T @ P1; pooled_i from qb_bf). Blocks [256,512): l-side.
__global__ __launch_bounds__(256) void k_final(const float* __restrict__ lp_i,
                                               const float* __restrict__ lp_l,
                                               const int* __restrict__ imask,
                                               const int* __restrict__ qmask,
                                               const unsigned short* __restrict__ P1,
                                               const unsigned short* __restrict__ qbf,
                                               const unsigned short* __restrict__ lfeat,
                                               float* __restrict__ iw_out,
                                               unsigned short* __restrict__ pooled) {
  __shared__ float red4[4];
  __shared__ float ar[256];
  __shared__ float red[4][64];
  __shared__ float vsm[64];
  const int t = threadIdx.x;
  if (blockIdx.x < 256) {
    const int b = blockIdx.x;
    const int i = b * 256 + t;
    float x = lp_i[i] + lp_i[65536 + i] + lp_i[131072 + i] + lp_i[196608 + i];
    float v = imask[i] ? -1e9f : x;
    float wmx = wave_max(v);
    if ((t & 63) == 0) red4[t >> 6] = wmx;
    __syncthreads();
    float mx = fmaxf(fmaxf(red4[0], red4[1]), fmaxf(red4[2], red4[3]));
    __syncthreads();
    float e = __expf(v - mx);
    float ws = wave_sum(e);
    if ((t & 63) == 0) red4[t >> 6] = ws;
    __syncthreads();
    float s = red4[0] + red4[1] + red4[2] + red4[3];
    float p = e / s;
    iw_out[i] = p;
    ar[t] = p;
    __syncthreads();
    // v[64] = att^T @ P1
    const int part = t >> 6, lane = t & 63;
    const unsigned short* Pb = P1 + ((size_t)b * 256 + part * 64) * 64 + lane;
    float s0 = 0.f, s1 = 0.f;
#pragma unroll 8
    for (int ii = 0; ii < 64; ii += 2) {
      s0 += ar[part * 64 + ii] * bf2f(Pb[(size_t)ii * 64]);
      s1 += ar[part * 64 + ii + 1] * bf2f(Pb[(size_t)(ii + 1) * 64]);
    }
    red[part][lane] = s0 + s1;
    __syncthreads();
    if (t < 64) vsm[t] = red[0][t] + red[1][t] + red[2][t] + red[3][t];
    __syncthreads();
    // pooled_i over qb_bf, L=64
    float a0 = 0.f, a1 = 0.f;
    const unsigned short* Xb = qbf + (size_t)b * 64 * 512 + 2 * t;
#pragma unroll 4
    for (int l = 0; l < 64; l++) {
      unsigned u = *(const unsigned*)&Xb[(size_t)l * 512];
      float a = vsm[l];
      a0 += a * bf2f((unsigned short)(u & 0xffff));
      a1 += a * bf2f((unsigned short)(u >> 16));
    }
    *(unsigned*)&pooled[(size_t)b * 1024 + 2 * t] = pk2(a0, a1);
  } else {
    const int b = blockIdx.x - 256;
    if (t < 64) {
      const int i = b * 64 + t;
      float x = lp_l[i] + lp_l[16384 + i] + lp_l[32768 + i] + lp_l[49152 + i];
      float v = qmask[i] ? -1e9f : x;
      float mx = wave_max(v);
      float e = __expf(v - mx);
      float s = wave_sum(e);
      ar[t] = e / s;
    }
    __syncthreads();
    float a0 = 0.f, a1 = 0.f;
    const unsigned short* Xb = lfeat + (size_t)b * 64 * 512 + 2 * t;
#pragma unroll 4
    for (int l = 0; l < 64; l++) {
      unsigned u = *(const unsigned*)&Xb[(size_t)l * 512];
      float a = ar[l];
      a0 += a * bf2f((unsigned short)(u & 0xffff));
      a1 += a * bf2f((unsigned short)(u >> 16));
    }
    *(unsigned*)&pooled[(size_t)b * 1024 + 512 + 2 * t] = pk2(a0, a1);
  }
}

// ---------------------------------------------------------------------------
// Epilogue GEMM: out[M,N] = X[M,K]bf16 @ Wt[N,K]bf16 + biasA (+biasB).
__global__ __launch_bounds__(256) void k_egemm(const unsigned short* __restrict__ X,
                                               const unsigned short* __restrict__ Wt,
                                               const float* __restrict__ biasA,
                                               const float* __restrict__ biasB,
                                               float* __restrict__ outf,
                                               unsigned short* __restrict__ outbf,
                                               int N, int K) {
  __shared__ unsigned short As[64 * 64];
  __shared__ unsigned short Bs[64 * 64];
  const int n0 = blockIdx.x * 64, m0 = blockIdx.y * 64;
  const int t = threadIdx.x, w = t >> 6, lane = t & 63, c = lane & 15, q = lane >> 4;
  const int wm = w >> 1, wn = w & 1;
  floatx4 acc[2][2];
#pragma unroll
  for (int ti = 0; ti < 2; ti++)
#pragma unroll
    for (int tj = 0; tj < 2; tj++) acc[ti][tj] = (floatx4){0.f, 0.f, 0.f, 0.f};

  for (int k0 = 0; k0 < K; k0 += 64) {
#pragma unroll
    for (int i = 0; i < 2; i++) {
      int s = i * 256 + t, row = s >> 3, src = (s & 7) ^ (row & 7);
      GLD_LDS16(X + (size_t)(m0 + row) * K + k0 + src * 8, &As[(i * 256 + w * 64) * 8]);
      GLD_LDS16(Wt + (size_t)(n0 + row) * K + k0 + src * 8, &Bs[(i * 256 + w * 64) * 8]);
    }
    __syncthreads();
#pragma unroll
    for (int kk = 0; kk < 2; kk++) {
      short8 a[2], bb[2];
#pragma unroll
      for (int ti = 0; ti < 2; ti++)
        a[ti] = *(const short8*)&As[(wm * 32 + ti * 16 + c) * 64 + ((kk * 4 + q) ^ (c & 7)) * 8];
#pragma unroll
      for (int tj = 0; tj < 2; tj++)
        bb[tj] = *(const short8*)&Bs[(wn * 32 + tj * 16 + c) * 64 + ((kk * 4 + q) ^ (c & 7)) * 8];
#pragma unroll
      for (int ti = 0; ti < 2; ti++)
#pragma unroll
        for (int tj = 0; tj < 2; tj++)
          acc[ti][tj] = __builtin_amdgcn_mfma_f32_16x16x32_bf16(a[ti], bb[tj], acc[ti][tj], 0, 0, 0);
    }
    __syncthreads();
  }
#pragma unroll
  for (int tj = 0; tj < 2; tj++) {
    int n = n0 + wn * 32 + tj * 16 + c;
    float bias = biasA[n] + (biasB ? biasB[n] : 0.f);
#pragma unroll
    for (int ti = 0; ti < 2; ti++)
#pragma unroll
      for (int rr = 0; rr < 4; rr++) {
        int m = m0 + wm * 32 + ti * 16 + q * 4 + rr;
        float v = acc[ti][tj][rr] + bias;
        if (outbf) outbf[(size_t)m * N + n] = f2bf(v);
        else outf[(size_t)m * N + n] = v;
      }
  }
}

// ---------------------------------------------------------------------------
extern "C" void kernel_launch(void* const* d_in, const int* in_sizes, int n_in,
                              void* d_out, int out_size, void* d_ws, size_t ws_size,
                              hipStream_t stream) {
  const float* ib = (const float*)d_in[0];
  const float* qb = (const float*)d_in[1];
  const int* imask = (const int*)d_in[2];
  const int* qmask = (const int*)d_in[3];
  const float* lf_w1 = (const float*)d_in[4];
  const float* lf_b1 = (const float*)d_in[5];
  const float* lf_w2 = (const float*)d_in[6];
  const float* lf_wm = (const float*)d_in[8];
  const float* lf_bm = (const float*)d_in[9];
  const float* if_w1 = (const float*)d_in[10];
  const float* if_b1 = (const float*)d_in[11];
  const float* if_w2 = (const float*)d_in[12];
  const float* if_wm = (const float*)d_in[14];
  const float* if_bm = (const float*)d_in[15];
  const float* fh_w = (const float*)d_in[16];
  const float* fh_b = (const float*)d_in[17];
  float* out = (float*)d_out;  // [256*512] out, then [256*256] i_weight

  float* lp_i = (float*)d_ws;              // 262,144 (4 x 65536)
  float* lp_l = lp_i + 262144;             // 65,536 (4 x 16384)
  float* att_i = lp_l + 65536;             // 65,536 (unused, kept for layout)
  float* att_l = att_i + 65536;            // 16,384 (unused)
  float* psum = att_l + 16384;             // 131,072 (16384 x 8)
  unsigned short* P1 = (unsigned short*)(psum + 131072);  // 4,194,304
  unsigned short* P2 = P1 + 4194304;                      // 4,194,304
  unsigned short* lfeat = P2 + 4194304;                   // 33,554,432 slot
  unsigned short* qb_bf = lfeat + 33554432;               // 8,388,608
  unsigned short* qbW1T = qb_bf + 8388608;                // 8,388,608
  unsigned short* ibT_unused = qbW1T + 8388608;           // 33,554,432 (dead)
  unsigned short* w1t_lf = ibT_unused + 33554432;         // 262,144
  unsigned short* w1t_if = w1t_lf + 262144;               // 262,144
  unsigned short* wcat_t = w1t_if + 262144;               // 1,048,576
  unsigned short* fh_wt = wcat_t + 1048576;               // 524,288
  unsigned short* pooled_bf = fh_wt + 524288;             // 262,144
  unsigned short* F_bf = pooled_bf + 262144;              // 262,144

  k_prep<<<2560, 256, 0, stream>>>(qb, lf_w1, if_w1, lf_wm, if_wm, fh_w,
                                   qb_bf, w1t_lf, w1t_if, wcat_t, fh_wt);

  k_scores_f<<<dim3(2, 256), 256, 0, stream>>>(ib, qb_bf, imask, qmask, P1, P2, psum);
  k_av2<<<dim3(4, 256), 256, 0, stream>>>(P2, ib, psum, lfeat);
  k_qbw1<<<dim3(4, 256), 256, 0, stream>>>(qb_bf, w1t_lf, qbW1T);
  k_logits_i64<<<dim3(8, 256), 256, 0, stream>>>(P1, qbW1T, lf_b1, lf_w2, lp_i);
  k_logits_part<<<512, 256, 0, stream>>>(lfeat, w1t_if, if_b1, if_w2, lp_l, 16384);
  k_final<<<512, 256, 0, stream>>>(lp_i, lp_l, imask, qmask, P1, qb_bf, lfeat,
                                   out + 131072, pooled_bf);

  k_egemm<<<dim3(16, 4), 256, 0, stream>>>(pooled_bf, wcat_t, lf_bm, if_bm,
                                           nullptr, F_bf, 1024, 1024);
  k_egemm<<<dim3(8, 4), 256, 0, stream>>>(F_bf, fh_wt, fh_b, nullptr,
                                          out, nullptr, 512, 1024);
}

// Round 8
// 371.292 us; speedup vs baseline: 1.2581x; 1.0005x over previous
//
#include <hip/hip_runtime.h>
#include <math.h>

// ---------------------------------------------------------------------------
// BiAttention round 14 (R13 resubmission — prior bench died on container
// acquisition, not kernel verdict; source audited for hangs/OOB, none found):
//  - k_qbw1 fused into k_logits_i (grid 4x256): qbW1 slice computed in-block
//    (K=512 GEMM), written to LDS fragments (Bs2, XOR swizzle), then both
//    mt-halves of P1 @ qbW1^T run in the same block. Kills qbW1T's 16.7 MB
//    write + 33.5 MB read + 1 launch.
//  - k_scores_f / k_av2: ALL staging reg-based (A too: GLD_LDS16 would force
//    vmcnt(0) drain at barrier, killing prefetch) with next-chunk loads
//    issued before the barrier (T14 async-STAGE): HBM/L2 latency hides under
//    transpose+MFMA.
//  - everything else identical to verified R12.
// Fragment scheme (verified R2..R12): A/B frag row = lane&15, k-group
// (lane>>4)*8 contiguous, XOR swizzle (colgroup ^ (row&7));
// C/D: col = lane&15, row = (lane>>4)*4 + r.
// ---------------------------------------------------------------------------

#define SCALE 0.04419417382415922f  // 1/sqrt(512)

typedef __attribute__((ext_vector_type(8))) short short8;
typedef __attribute__((ext_vector_type(4))) float floatx4;

__device__ __forceinline__ unsigned short f2bf(float x) {
  unsigned u = __float_as_uint(x);
  unsigned r = u + 0x7FFFu + ((u >> 16) & 1u);
  return (unsigned short)(r >> 16);
}
__device__ __forceinline__ float bf2f(unsigned short h) {
  return __uint_as_float(((unsigned)h) << 16);
}
// Packed f32x2 -> bf16x2, RNE (hardware). lo = a, hi = b.
__device__ __forceinline__ unsigned pk2(float a, float b) {
  unsigned r;
  asm("v_cvt_pk_bf16_f32 %0, %1, %2" : "=v"(r) : "v"(a), "v"(b));
  return r;
}

__device__ __forceinline__ float wave_max(float v) {
#pragma unroll
  for (int o = 32; o > 0; o >>= 1) v = fmaxf(v, __shfl_xor(v, o, 64));
  return v;
}
__device__ __forceinline__ float wave_sum(float v) {
#pragma unroll
  for (int o = 32; o > 0; o >>= 1) v += __shfl_xor(v, o, 64);
  return v;
}

#define GLD_LDS16(gptr, lptr)                                             \
  __builtin_amdgcn_global_load_lds(                                       \
      (const __attribute__((address_space(1))) void*)(gptr),              \
      (__attribute__((address_space(3))) void*)(lptr), 16, 0, 0)

// ---------------------------------------------------------------------------
// Merged prep: idx<512 weights; [512,2560) qb pure stream convert.
__global__ __launch_bounds__(256) void k_prep(
    const float* __restrict__ qb, const float* __restrict__ lf_w1,
    const float* __restrict__ if_w1, const float* __restrict__ lf_wm,
    const float* __restrict__ if_wm, const float* __restrict__ fh_w,
    unsigned short* __restrict__ qb_bf, unsigned short* __restrict__ w1t_lf,
    unsigned short* __restrict__ w1t_if, unsigned short* __restrict__ wcat_t,
    unsigned short* __restrict__ fh_wt) {
  __shared__ __align__(16) char smem[64 * 65 * 4];  // 16640 B
  const int idx = blockIdx.x, t = threadIdx.x;

  if (idx < 512) {
    // ---- weights: f32 [K,N] -> bf16 [N, koff+K] (stride 65: conflict-free)
    float(*T)[65] = (float(*)[65])smem;
    const float* src;
    unsigned short* dst;
    int N, ds, koff, k0, n0;
    if (idx < 64) {
      src = lf_w1; dst = w1t_lf; N = 512; ds = 512; koff = 0;
      k0 = (idx & 7) * 64; n0 = (idx >> 3) * 64;
    } else if (idx < 128) {
      int l = idx - 64;
      src = if_w1; dst = w1t_if; N = 512; ds = 512; koff = 0;
      k0 = (l & 7) * 64; n0 = (l >> 3) * 64;
    } else if (idx < 256) {
      int l = idx - 128;
      src = lf_wm; dst = wcat_t; N = 1024; ds = 1024; koff = 0;
      k0 = (l & 7) * 64; n0 = (l >> 3) * 64;
    } else if (idx < 384) {
      int l = idx - 256;
      src = if_wm; dst = wcat_t; N = 1024; ds = 1024; koff = 512;
      k0 = (l & 7) * 64; n0 = (l >> 3) * 64;
    } else {
      int l = idx - 384;
      src = fh_w; dst = fh_wt; N = 512; ds = 1024; koff = 0;
      k0 = (l & 15) * 64; n0 = (l >> 4) * 64;
    }
#pragma unroll
    for (int i = 0; i < 16; i++) {
      int e = t + i * 256, r = e >> 6, c = e & 63;
      T[r][c] = src[(size_t)(k0 + r) * N + n0 + c];
    }
    __syncthreads();
#pragma unroll
    for (int i = 0; i < 8; i++) {
      int e = t + i * 256, r = e >> 5, c2 = (e & 31) * 2;
      *(unsigned*)&dst[(size_t)(n0 + r) * ds + koff + k0 + c2] =
          pk2(T[c2][r], T[c2 + 1][r]);
    }
  } else {
    // ---- qb f32 -> bf16 pure stream ----
    int j = idx - 512;  // 2048 blocks x 4096 floats
    const float4* src = (const float4*)(qb + (size_t)j * 4096);
    uint2* dst = (uint2*)(qb_bf + (size_t)j * 4096);
#pragma unroll
    for (int i = 0; i < 4; i++) {
      int e = t + i * 256;
      float4 v = src[e];
      uint2 p;
      p.x = pk2(v.x, v.y);
      p.y = pk2(v.z, v.w);
      dst[e] = p;
    }
  }
}

// ---------------------------------------------------------------------------
// Fused scores: per (i-chunk, batch). S[64q x 128i] = qb @ ib^T * SCALE.
// All staging reg-based with next-chunk prefetch (T14). X unioned onto
// As+Bs (only live post-K-loop): 24 KB LDS.
__global__ __launch_bounds__(256) void k_scores_f(
    const float* __restrict__ ib, const unsigned short* __restrict__ qbf,
    const int* __restrict__ imask, const int* __restrict__ qmask,
    unsigned short* __restrict__ P1, unsigned short* __restrict__ P2,
    float* __restrict__ psum) {
  __shared__ __align__(16) unsigned short U[64 * 64 + 128 * 64];  // 24576 B
  unsigned short* As = U;            // [64][64]
  unsigned short* Bs = U + 64 * 64;  // [128][64]
  unsigned short* X = U;             // E:[64][136] / Pl:[128][72], post-loop
  const int b = blockIdx.y, ic = blockIdx.x, i0 = ic * 128;
  const int t = threadIdx.x, w = t >> 6, lane = t & 63, c = lane & 15, qq = lane >> 4;

  floatx4 acc[4][2];
#pragma unroll
  for (int ti = 0; ti < 4; ti++)
#pragma unroll
    for (int tj = 0; tj < 2; tj++) acc[ti][tj] = (floatx4){0.f, 0.f, 0.f, 0.f};

  uint4 qa[2];
  float4 vb[8];
  // prologue: k0 = 0
#pragma unroll
  for (int i = 0; i < 2; i++) {
    int s = i * 256 + t, row = s >> 3, srcg = (s & 7) ^ (row & 7);
    qa[i] = *(const uint4*)&qbf[((size_t)b * 64 + row) * 512 + srcg * 8];
  }
#pragma unroll
  for (int i = 0; i < 8; i++) {
    int s = i * 256 + t, row = s >> 4, c4 = s & 15;
    vb[i] = *(const float4*)&ib[((size_t)b * 256 + i0 + row) * 512 + c4 * 4];
  }

  for (int k0 = 0; k0 < 512; k0 += 64) {
    // stage current chunk from regs
#pragma unroll
    for (int i = 0; i < 2; i++) {
      int s = i * 256 + t;
      *(uint4*)&As[s * 8] = qa[i];
    }
#pragma unroll
    for (int i = 0; i < 8; i++) {
      int s = i * 256 + t, row = s >> 4, c4 = s & 15;
      int gs = (c4 >> 1) ^ (row & 7), sub = c4 & 1;
      uint2 p;
      p.x = pk2(vb[i].x, vb[i].y);
      p.y = pk2(vb[i].z, vb[i].w);
      *(uint2*)&Bs[row * 64 + gs * 8 + sub * 4] = p;
    }
    // prefetch next chunk (stays in flight across barriers)
    if (k0 < 448) {
      int kn = k0 + 64;
#pragma unroll
      for (int i = 0; i < 2; i++) {
        int s = i * 256 + t, row = s >> 3, srcg = (s & 7) ^ (row & 7);
        qa[i] = *(const uint4*)&qbf[((size_t)b * 64 + row) * 512 + kn + srcg * 8];
      }
#pragma unroll
      for (int i = 0; i < 8; i++) {
        int s = i * 256 + t, row = s >> 4, c4 = s & 15;
        vb[i] = *(const float4*)&ib[((size_t)b * 256 + i0 + row) * 512 + kn + c4 * 4];
      }
    }
    __syncthreads();
#pragma unroll
    for (int kk = 0; kk < 2; kk++) {
      short8 a[4], bb[2];
#pragma unroll
      for (int ti = 0; ti < 4; ti++)
        a[ti] = *(const short8*)&As[(ti * 16 + c) * 64 + ((kk * 4 + qq) ^ (c & 7)) * 8];
#pragma unroll
      for (int tj = 0; tj < 2; tj++)
        bb[tj] = *(const short8*)&Bs[(w * 32 + tj * 16 + c) * 64 + ((kk * 4 + qq) ^ (c & 7)) * 8];
#pragma unroll
      for (int ti = 0; ti < 4; ti++)
#pragma unroll
        for (int tj = 0; tj < 2; tj++)
          acc[ti][tj] = __builtin_amdgcn_mfma_f32_16x16x32_bf16(a[ti], bb[tj], acc[ti][tj], 0, 0, 0);
    }
    __syncthreads();
  }

  const int il0 = w * 32 + c;  // tj=0 local i; tj=1 is il0+16
  int imsk0 = imask[b * 256 + i0 + il0];
  int imsk1 = imask[b * 256 + i0 + il0 + 16];
  int qm[4][4];
#pragma unroll
  for (int ti = 0; ti < 4; ti++)
#pragma unroll
    for (int rr = 0; rr < 4; rr++) qm[ti][rr] = qmask[b * 64 + ti * 16 + qq * 4 + rr];

  // ---- E phase: raw exp (imask) into X[64][136], per-wave row sums ----
#pragma unroll
  for (int ti = 0; ti < 4; ti++)
#pragma unroll
    for (int rr = 0; rr < 4; rr++) {
      int qv = ti * 16 + qq * 4 + rr;
      float e0 = imsk0 ? 0.f : __expf(acc[ti][0][rr] * SCALE);
      float e1 = imsk1 ? 0.f : __expf(acc[ti][1][rr] * SCALE);
      X[qv * 136 + il0] = f2bf(e0);
      X[qv * 136 + il0 + 16] = f2bf(e1);
      float s = e0 + e1;
#pragma unroll
      for (int o = 1; o <= 8; o <<= 1) s += __shfl_xor(s, o, 64);
      if (c == 0) psum[((size_t)(b * 64 + qv)) * 8 + ic * 4 + w] = s;
    }
  __syncthreads();
#pragma unroll
  for (int i = 0; i < 4; i++) {
    int e2 = t + i * 256, qv = e2 >> 4, g = e2 & 15;
    *(uint4*)&P2[((size_t)b * 64 + qv) * 256 + i0 + g * 8] = *(const uint4*)&X[qv * 136 + g * 8];
  }
  __syncthreads();

  // ---- P1 phase: column softmax over q (qmask), normalized, into X[128][72]
#pragma unroll
  for (int tj = 0; tj < 2; tj++) {
    float ev[4][4];
    float s1 = 0.f;
#pragma unroll
    for (int ti = 0; ti < 4; ti++)
#pragma unroll
      for (int rr = 0; rr < 4; rr++) {
        ev[ti][rr] = qm[ti][rr] ? 0.f : __expf(acc[ti][tj][rr] * SCALE);
        s1 += ev[ti][rr];
      }
    s1 += __shfl_xor(s1, 16, 64);
    s1 += __shfl_xor(s1, 32, 64);
    float inv = 1.f / s1;
    int il = il0 + tj * 16;
#pragma unroll
    for (int ti = 0; ti < 4; ti++)
#pragma unroll
      for (int rr = 0; rr < 4; rr++)
        X[il * 72 + ti * 16 + qq * 4 + rr] = f2bf(ev[ti][rr] * inv);
  }
  __syncthreads();
#pragma unroll
  for (int i = 0; i < 4; i++) {
    int e2 = t + i * 256, il = e2 >> 3, g = e2 & 7;
    *(uint4*)&P1[((size_t)b * 256 + i0 + il) * 64 + g * 8] = *(const uint4*)&X[il * 72 + g * 8];
  }
}

// ---------------------------------------------------------------------------
// lfeat[b,64,512] = (P2 @ ib) * rowscale. All staging reg-based with
// next-chunk prefetch (T14); in-place Tb->Bs transpose. 24 KB LDS.
__global__ __launch_bounds__(256) void k_av2(const unsigned short* __restrict__ P2,
                                             const float* __restrict__ ib,
                                             const float* __restrict__ psum,
                                             unsigned short* __restrict__ lfeat) {
  __shared__ unsigned short As[64 * 64];
  __shared__ __align__(16) unsigned short Tb[128 * 64];  // Tb then Bs (aliased)
  const int b = blockIdx.y, n0 = blockIdx.x * 128;
  const int t = threadIdx.x, w = t >> 6, lane = t & 63, c = lane & 15, q = lane >> 4;
  const int wm = w >> 1, wn = w & 1;
  floatx4 acc[2][4];
#pragma unroll
  for (int ti = 0; ti < 2; ti++)
#pragma unroll
    for (int tj = 0; tj < 4; tj++) acc[ti][tj] = (floatx4){0.f, 0.f, 0.f, 0.f};

  uint4 pa[2];
  float4 vb[8];
  // prologue: kc = 0
#pragma unroll
  for (int i = 0; i < 2; i++) {
    int s = i * 256 + t, row = s >> 3, srcg = (s & 7) ^ (row & 7);
    pa[i] = *(const uint4*)&P2[((size_t)b * 64 + row) * 256 + srcg * 8];
  }
#pragma unroll
  for (int i = 0; i < 8; i++) {
    int e = i * 256 + t, tok = e >> 5, h4 = (e & 31) * 4;
    vb[i] = *(const float4*)&ib[((size_t)b * 256 + tok) * 512 + n0 + h4];
  }

  for (int kc = 0; kc < 256; kc += 64) {
    // stage current chunk from regs
#pragma unroll
    for (int i = 0; i < 2; i++) {
      int s = i * 256 + t;
      *(uint4*)&As[s * 8] = pa[i];
    }
#pragma unroll
    for (int i = 0; i < 8; i++) {
      int e = i * 256 + t, tok = e >> 5, h4 = (e & 31) * 4;
      uint2 p;
      p.x = pk2(vb[i].x, vb[i].y);
      p.y = pk2(vb[i].z, vb[i].w);
      int col = ((((h4 >> 3) ^ (tok >> 3)) & 15) << 3) | (h4 & 7);
      *(uint2*)&Tb[tok * 128 + col] = p;
    }
    // prefetch next chunk
    if (kc < 192) {
      int kn = kc + 64;
#pragma unroll
      for (int i = 0; i < 2; i++) {
        int s = i * 256 + t, row = s >> 3, srcg = (s & 7) ^ (row & 7);
        pa[i] = *(const uint4*)&P2[((size_t)b * 64 + row) * 256 + kn + srcg * 8];
      }
#pragma unroll
      for (int i = 0; i < 8; i++) {
        int e = i * 256 + t, tok = e >> 5, h4 = (e & 31) * 4;
        vb[i] = *(const float4*)&ib[((size_t)b * 256 + kn + tok) * 512 + n0 + h4];
      }
    }
    __syncthreads();
    // Gather transpose into regs (all reads complete before any write)
    uint4 vv[4];
#pragma unroll
    for (int i = 0; i < 4; i++) {
      int e = i * 256 + t, h = e >> 3, tc = (e & 7) * 8;
      int hg = h >> 3, ho = h & 7;
      unsigned y[8];
#pragma unroll
      for (int k = 0; k < 8; k++) {
        int r = tc + k;
        y[k] = Tb[r * 128 + (((hg ^ (r >> 3)) & 15) << 3) + ho];
      }
      vv[i].x = y[0] | (y[1] << 16);
      vv[i].y = y[2] | (y[3] << 16);
      vv[i].z = y[4] | (y[5] << 16);
      vv[i].w = y[6] | (y[7] << 16);
    }
    __syncthreads();
    // Write back in-place as Bs [h=128 rows][tok=64], fragment XOR swizzle
#pragma unroll
    for (int i = 0; i < 4; i++) {
      int e = i * 256 + t, h = e >> 3, tc = (e & 7) * 8;
      *(uint4*)&Tb[h * 64 + (((tc >> 3) ^ (h & 7)) << 3)] = vv[i];
    }
    __syncthreads();
    const unsigned short* Bs = Tb;
#pragma unroll
    for (int kk = 0; kk < 2; kk++) {
      short8 a[2], bb[4];
#pragma unroll
      for (int ti = 0; ti < 2; ti++)
        a[ti] = *(const short8*)&As[(wm * 32 + ti * 16 + c) * 64 + ((kk * 4 + q) ^ (c & 7)) * 8];
#pragma unroll
      for (int tj = 0; tj < 4; tj++)
        bb[tj] = *(const short8*)&Bs[(wn * 64 + tj * 16 + c) * 64 + ((kk * 4 + q) ^ (c & 7)) * 8];
#pragma unroll
      for (int ti = 0; ti < 2; ti++)
#pragma unroll
        for (int tj = 0; tj < 4; tj++)
          acc[ti][tj] = __builtin_amdgcn_mfma_f32_16x16x32_bf16(a[ti], bb[tj], acc[ti][tj], 0, 0, 0);
    }
    __syncthreads();
  }
#pragma unroll
  for (int ti = 0; ti < 2; ti++)
#pragma unroll
    for (int rr = 0; rr < 4; rr++) {
      int m = wm * 32 + ti * 16 + q * 4 + rr;
      const float* ps = psum + ((size_t)(b * 64 + m)) * 8;
      float s = ps[0] + ps[1] + ps[2] + ps[3] + ps[4] + ps[5] + ps[6] + ps[7];
      float inv = 1.f / s;
      unsigned short* op = lfeat + ((size_t)b * 64 + m) * 512 + n0 + wn * 64;
#pragma unroll
      for (int tj = 0; tj < 4; tj++) op[tj * 16 + c] = f2bf(acc[ti][tj][rr] * inv);
    }
}

// ---------------------------------------------------------------------------
// Fused i-side logits: phase1 computes qbW1 slice [128n x 64q] (K=512) into
// LDS fragments Bs2; phase2 runs P1 @ qbW1^T for both m-halves with fused
// relu*w2 reduction. Replaces k_qbw1 + k_logits_i64.
__global__ __launch_bounds__(256) void k_logits_i(
    const unsigned short* __restrict__ qbf, const unsigned short* __restrict__ W1t,
    const unsigned short* __restrict__ P1, const float* __restrict__ b1,
    const float* __restrict__ w2, float* __restrict__ outp) {
  __shared__ __align__(16) unsigned short U[16384];  // 32 KB
  __shared__ float red[2][128];
  unsigned short* As = U;           // phase1 A: qbf [64][64]
  unsigned short* Bs = U + 4096;    // phase1 B: W1t [128][64]
  unsigned short* Bs2 = U;          // phase2 B: qbW1 frags [128][64]
  unsigned short* As2 = U + 8192;   // phase2 A: P1 tile [128][64]
  const int b = blockIdx.y, nc = blockIdx.x, n0 = nc * 128;
  const int t = threadIdx.x, w = t >> 6, lane = t & 63, c = lane & 15, q = lane >> 4;
  const int wm = w >> 1, wn = w & 1;

  // ---- phase 1: qbW1 = qb_bf @ W1 (K=512) ----
  floatx4 acc[2][4];
#pragma unroll
  for (int ti = 0; ti < 2; ti++)
#pragma unroll
    for (int tj = 0; tj < 4; tj++) acc[ti][tj] = (floatx4){0.f, 0.f, 0.f, 0.f};

  for (int k0 = 0; k0 < 512; k0 += 64) {
#pragma unroll
    for (int i = 0; i < 2; i++) {
      int s = i * 256 + t, row = s >> 3, src = (s & 7) ^ (row & 7);
      GLD_LDS16(qbf + ((size_t)b * 64 + row) * 512 + k0 + src * 8,
                &As[(i * 256 + w * 64) * 8]);
    }
#pragma unroll
    for (int i = 0; i < 4; i++) {
      int s = i * 256 + t, row = s >> 3, src = (s & 7) ^ (row & 7);
      GLD_LDS16(W1t + (size_t)(n0 + row) * 512 + k0 + src * 8,
                &Bs[(i * 256 + w * 64) * 8]);
    }
    __syncthreads();
#pragma unroll
    for (int kk = 0; kk < 2; kk++) {
      short8 a[2], bb[4];
#pragma unroll
      for (int ti = 0; ti < 2; ti++)
        a[ti] = *(const short8*)&As[(wm * 32 + ti * 16 + c) * 64 + ((kk * 4 + q) ^ (c & 7)) * 8];
#pragma unroll
      for (int tj = 0; tj < 4; tj++)
        bb[tj] = *(const short8*)&Bs[(wn * 64 + tj * 16 + c) * 64 + ((kk * 4 + q) ^ (c & 7)) * 8];
#pragma unroll
      for (int ti = 0; ti < 2; ti++)
#pragma unroll
        for (int tj = 0; tj < 4; tj++)
          acc[ti][tj] = __builtin_amdgcn_mfma_f32_16x16x32_bf16(a[ti], bb[tj], acc[ti][tj], 0, 0, 0);
    }
    __syncthreads();
  }

  // acc -> Bs2 fragments: row n_local (lane&15-style), k = q index, XOR swz.
  // (safe: writes happen after final loop barrier; Bs2 aliases As/Bs.)
#pragma unroll
  for (int ti = 0; ti < 2; ti++)
#pragma unroll
    for (int tj = 0; tj < 4; tj++) {
      int nl = wn * 64 + tj * 16 + c;
      int qb_ = wm * 32 + ti * 16 + q * 4;
      uint2 p;
      p.x = pk2(acc[ti][tj][0], acc[ti][tj][1]);
      p.y = pk2(acc[ti][tj][2], acc[ti][tj][3]);
      *(uint2*)&Bs2[nl * 64 + (((qb_ >> 3) ^ (nl & 7)) << 3) + (qb_ & 7)] = p;
    }

  // ---- phase 2: for each m-half, P1 @ qbW1^T (K=64), fused relu*w2 ----
  for (int mt = 0; mt < 2; mt++) {
    const int m0 = mt * 128;
#pragma unroll
    for (int i = 0; i < 4; i++) {
      int s = i * 256 + t, row = s >> 3, src = (s & 7) ^ (row & 7);
      GLD_LDS16(P1 + ((size_t)b * 256 + m0 + row) * 64 + src * 8,
                &As2[(i * 256 + w * 64) * 8]);
    }
    __syncthreads();  // As2 ready; Bs2 ds_writes visible (first iter)
    floatx4 acc2[4][4];
#pragma unroll
    for (int ti = 0; ti < 4; ti++)
#pragma unroll
      for (int tj = 0; tj < 4; tj++) acc2[ti][tj] = (floatx4){0.f, 0.f, 0.f, 0.f};
#pragma unroll
    for (int kk = 0; kk < 2; kk++) {
      short8 a[4], bb[4];
#pragma unroll
      for (int ti = 0; ti < 4; ti++)
        a[ti] = *(const short8*)&As2[(wm * 64 + ti * 16 + c) * 64 + ((kk * 4 + q) ^ (c & 7)) * 8];
#pragma unroll
      for (int tj = 0; tj < 4; tj++)
        bb[tj] = *(const short8*)&Bs2[(wn * 64 + tj * 16 + c) * 64 + ((kk * 4 + q) ^ (c & 7)) * 8];
#pragma unroll
      for (int ti = 0; ti < 4; ti++)
#pragma unroll
        for (int tj = 0; tj < 4; tj++)
          acc2[ti][tj] = __builtin_amdgcn_mfma_f32_16x16x32_bf16(a[ti], bb[tj], acc2[ti][tj], 0, 0, 0);
    }

    float partial[4][4] = {};
#pragma unroll
    for (int tj = 0; tj < 4; tj++) {
      int n = n0 + wn * 64 + tj * 16 + c;
      float bia = b1[n], wwv = w2[n];
#pragma unroll
      for (int ti = 0; ti < 4; ti++)
#pragma unroll
        for (int r = 0; r < 4; r++)
          partial[ti][r] += fmaxf(acc2[ti][tj][r] + bia, 0.f) * wwv;
    }
#pragma unroll
    for (int msk = 1; msk <= 8; msk <<= 1)
#pragma unroll
      for (int ti = 0; ti < 4; ti++)
#pragma unroll
        for (int r = 0; r < 4; r++)
          partial[ti][r] += __shfl_xor(partial[ti][r], msk, 64);
    if (c == 0) {
#pragma unroll
      for (int ti = 0; ti < 4; ti++)
#pragma unroll
        for (int r = 0; r < 4; r++)
          red[wn][wm * 64 + ti * 16 + q * 4 + r] = partial[ti][r];
    }
    __syncthreads();
    if (t < 128) outp[(size_t)nc * 65536 + b * 256 + m0 + t] = red[0][t] + red[1][t];
    __syncthreads();  // protect red + As2 before next mt
  }
}

// ---------------------------------------------------------------------------
// Partial logits (l-side).
__global__ __launch_bounds__(256) void k_logits_part(
    const unsigned short* __restrict__ X, const unsigned short* __restrict__ W1t,
    const float* __restrict__ b1, const float* __restrict__ w2,
    float* __restrict__ outp, int M) {
  __shared__ unsigned short As[128 * 64];
  __shared__ unsigned short Bs[128 * 64];
  __shared__ float red[2][128];
  const int t = threadIdx.x, w = t >> 6, lane = t & 63;
  const int wm = w >> 1, wn = w & 1, c = lane & 15, q = lane >> 4;
  const int idx = blockIdx.x;
  const int m_tile = (idx & 7) + ((idx >> 5) << 3), nc = (idx >> 3) & 3;
  const int m0 = m_tile * 128, n0 = nc * 128;

  floatx4 acc[4][4];
#pragma unroll
  for (int ti = 0; ti < 4; ti++)
#pragma unroll
    for (int tj = 0; tj < 4; tj++) acc[ti][tj] = (floatx4){0.f, 0.f, 0.f, 0.f};

  for (int k0 = 0; k0 < 512; k0 += 64) {
#pragma unroll
    for (int it = 0; it < 4; it++) {
      int s = it * 256 + t, row = s >> 3, src = (s & 7) ^ (row & 7);
      GLD_LDS16(X + (size_t)(m0 + row) * 512 + k0 + src * 8, &As[(it * 256 + w * 64) * 8]);
      GLD_LDS16(W1t + (size_t)(n0 + row) * 512 + k0 + src * 8, &Bs[(it * 256 + w * 64) * 8]);
    }
    __syncthreads();
#pragma unroll
    for (int kk = 0; kk < 2; kk++) {
      short8 a[4], bb[4];
#pragma unroll
      for (int ti = 0; ti < 4; ti++)
        a[ti] = *(const short8*)&As[(wm * 64 + ti * 16 + c) * 64 + ((kk * 4 + q) ^ (c & 7)) * 8];
#pragma unroll
      for (int tj = 0; tj < 4; tj++)
        bb[tj] = *(const short8*)&Bs[(wn * 64 + tj * 16 + c) * 64 + ((kk * 4 + q) ^ (c & 7)) * 8];
#pragma unroll
      for (int ti = 0; ti < 4; ti++)
#pragma unroll
        for (int tj = 0; tj < 4; tj++)
          acc[ti][tj] = __builtin_amdgcn_mfma_f32_16x16x32_bf16(a[ti], bb[tj], acc[ti][tj], 0, 0, 0);
    }
    __syncthreads();
  }
  float partial[4][4] = {};
#pragma unroll
  for (int tj = 0; tj < 4; tj++) {
    int n = n0 + wn * 64 + tj * 16 + c;
    float bia = b1[n], wwv = w2[n];
#pragma unroll
    for (int ti = 0; ti < 4; ti++)
#pragma unroll
      for (int r = 0; r < 4; r++)
        partial[ti][r] += fmaxf(acc[ti][tj][r] + bia, 0.f) * wwv;
  }
#pragma unroll
  for (int msk = 1; msk <= 8; msk <<= 1)
#pragma unroll
    for (int ti = 0; ti < 4; ti++)
#pragma unroll
      for (int r = 0; r < 4; r++)
        partial[ti][r] += __shfl_xor(partial[ti][r], msk, 64);
  if (c == 0) {
#pragma unroll
    for (int ti = 0; ti < 4; ti++)
#pragma unroll
      for (int r = 0; r < 4; r++)
        red[wn][wm * 64 + ti * 16 + q * 4 + r] = partial[ti][r];
  }
  __syncthreads();
  if (t < 128) outp[(size_t)nc * M + m0 + t] = red[0][t] + red[1][t];
}

// ---------------------------------------------------------------------------
// Fused epilogues. Blocks [0,256): i-side (softmax -> i_weight + att in LDS;
// v = att^T @ P1; pooled_i from qb_bf). Blocks [256,512): l-side.
__global__ __launch_bounds__(256) void k_final(const float* __restrict__ lp_i,
                                               const float* __restrict__ lp_l,
                                               const int* __restrict__ imask,
                                               const int* __restrict__ qmask,
                                               const unsigned short* __restrict__ P1,
                                               const unsigned short* __restrict__ qbf,
                                               const unsigned short* __restrict__ lfeat,
                                               float* __restrict__ iw_out,
                                               unsigned short* __restrict__ pooled) {
  __shared__ float red4[4];
  __shared__ float ar[256];
  __shared__ float red[4][64];
  __shared__ float vsm[64];
  const int t = threadIdx.x;
  if (blockIdx.x < 256) {
    const int b = blockIdx.x;
    const int i = b * 256 + t;
    float x = lp_i[i] + lp_i[65536 + i] + lp_i[131072 + i] + lp_i[196608 + i];
    float v = imask[i] ? -1e9f : x;
    float wmx = wave_max(v);
    if ((t & 63) == 0) red4[t >> 6] = wmx;
    __syncthreads();
    float mx = fmaxf(fmaxf(red4[0], red4[1]), fmaxf(red4[2], red4[3]));
    __syncthreads();
    float e = __expf(v - mx);
    float ws = wave_sum(e);
    if ((t & 63) == 0) red4[t >> 6] = ws;
    __syncthreads();
    float s = red4[0] + red4[1] + red4[2] + red4[3];
    float p = e / s;
    iw_out[i] = p;
    ar[t] = p;
    __syncthreads();
    // v[64] = att^T @ P1
    const int part = t >> 6, lane = t & 63;
    const unsigned short* Pb = P1 + ((size_t)b * 256 + part * 64) * 64 + lane;
    float s0 = 0.f, s1 = 0.f;
#pragma unroll 8
    for (int ii = 0; ii < 64; ii += 2) {
      s0 += ar[part * 64 + ii] * bf2f(Pb[(size_t)ii * 64]);
      s1 += ar[part * 64 + ii + 1] * bf2f(Pb[(size_t)(ii + 1) * 64]);
    }
    red[part][lane] = s0 + s1;
    __syncthreads();
    if (t < 64) vsm[t] = red[0][t] + red[1][t] + red[2][t] + red[3][t];
    __syncthreads();
    // pooled_i over qb_bf, L=64
    float a0 = 0.f, a1 = 0.f;
    const unsigned short* Xb = qbf + (size_t)b * 64 * 512 + 2 * t;
#pragma unroll 4
    for (int l = 0; l < 64; l++) {
      unsigned u = *(const unsigned*)&Xb[(size_t)l * 512];
      float a = vsm[l];
      a0 += a * bf2f((unsigned short)(u & 0xffff));
      a1 += a * bf2f((unsigned short)(u >> 16));
    }
    *(unsigned*)&pooled[(size_t)b * 1024 + 2 * t] = pk2(a0, a1);
  } else {
    const int b = blockIdx.x - 256;
    if (t < 64) {
      const int i = b * 64 + t;
      float x = lp_l[i] + lp_l[16384 + i] + lp_l[32768 + i] + lp_l[49152 + i];
      float v = qmask[i] ? -1e9f : x;
      float mx = wave_max(v);
      float e = __expf(v - mx);
      float s = wave_sum(e);
      ar[t] = e / s;
    }
    __syncthreads();
    float a0 = 0.f, a1 = 0.f;
    const unsigned short* Xb = lfeat + (size_t)b * 64 * 512 + 2 * t;
#pragma unroll 4
    for (int l = 0; l < 64; l++) {
      unsigned u = *(const unsigned*)&Xb[(size_t)l * 512];
      float a = ar[l];
      a0 += a * bf2f((unsigned short)(u & 0xffff));
      a1 += a * bf2f((unsigned short)(u >> 16));
    }
    *(unsigned*)&pooled[(size_t)b * 1024 + 512 + 2 * t] = pk2(a0, a1);
  }
}

// ---------------------------------------------------------------------------
// Epilogue GEMM: out[M,N] = X[M,K]bf16 @ Wt[N,K]bf16 + biasA (+biasB).
__global__ __launch_bounds__(256) void k_egemm(const unsigned short* __restrict__ X,
                                               const unsigned short* __restrict__ Wt,
                                               const float* __restrict__ biasA,
                                               const float* __restrict__ biasB,
                                               float* __restrict__ outf,
                                               unsigned short* __restrict__ outbf,
                                               int N, int K) {
  __shared__ unsigned short As[64 * 64];
  __shared__ unsigned short Bs[64 * 64];
  const int n0 = blockIdx.x * 64, m0 = blockIdx.y * 64;
  const int t = threadIdx.x, w = t >> 6, lane = t & 63, c = lane & 15, q = lane >> 4;
  const int wm = w >> 1, wn = w & 1;
  floatx4 acc[2][2];
#pragma unroll
  for (int ti = 0; ti < 2; ti++)
#pragma unroll
    for (int tj = 0; tj < 2; tj++) acc[ti][tj] = (floatx4){0.f, 0.f, 0.f, 0.f};

  for (int k0 = 0; k0 < K; k0 += 64) {
#pragma unroll
    for (int i = 0; i < 2; i++) {
      int s = i * 256 + t, row = s >> 3, src = (s & 7) ^ (row & 7);
      GLD_LDS16(X + (size_t)(m0 + row) * K + k0 + src * 8, &As[(i * 256 + w * 64) * 8]);
      GLD_LDS16(Wt + (size_t)(n0 + row) * K + k0 + src * 8, &Bs[(i * 256 + w * 64) * 8]);
    }
    __syncthreads();
#pragma unroll
    for (int kk = 0; kk < 2; kk++) {
      short8 a[2], bb[2];
#pragma unroll
      for (int ti = 0; ti < 2; ti++)
        a[ti] = *(const short8*)&As[(wm * 32 + ti * 16 + c) * 64 + ((kk * 4 + q) ^ (c & 7)) * 8];
#pragma unroll
      for (int tj = 0; tj < 2; tj++)
        bb[tj] = *(const short8*)&Bs[(wn * 32 + tj * 16 + c) * 64 + ((kk * 4 + q) ^ (c & 7)) * 8];
#pragma unroll
      for (int ti = 0; ti < 2; ti++)
#pragma unroll
        for (int tj = 0; tj < 2; tj++)
          acc[ti][tj] = __builtin_amdgcn_mfma_f32_16x16x32_bf16(a[ti], bb[tj], acc[ti][tj], 0, 0, 0);
    }
    __syncthreads();
  }
#pragma unroll
  for (int tj = 0; tj < 2; tj++) {
    int n = n0 + wn * 32 + tj * 16 + c;
    float bias = biasA[n] + (biasB ? biasB[n] : 0.f);
#pragma unroll
    for (int ti = 0; ti < 2; ti++)
#pragma unroll
      for (int rr = 0; rr < 4; rr++) {
        int m = m0 + wm * 32 + ti * 16 + q * 4 + rr;
        float v = acc[ti][tj][rr] + bias;
        if (outbf) outbf[(size_t)m * N + n] = f2bf(v);
        else outf[(size_t)m * N + n] = v;
      }
  }
}

// ---------------------------------------------------------------------------
extern "C" void kernel_launch(void* const* d_in, const int* in_sizes, int n_in,
                              void* d_out, int out_size, void* d_ws, size_t ws_size,
                              hipStream_t stream) {
  const float* ib = (const float*)d_in[0];
  const float* qb = (const float*)d_in[1];
  const int* imask = (const int*)d_in[2];
  const int* qmask = (const int*)d_in[3];
  const float* lf_w1 = (const float*)d_in[4];
  const float* lf_b1 = (const float*)d_in[5];
  const float* lf_w2 = (const float*)d_in[6];
  const float* lf_wm = (const float*)d_in[8];
  const float* lf_bm = (const float*)d_in[9];
  const float* if_w1 = (const float*)d_in[10];
  const float* if_b1 = (const float*)d_in[11];
  const float* if_w2 = (const float*)d_in[12];
  const float* if_wm = (const float*)d_in[14];
  const float* if_bm = (const float*)d_in[15];
  const float* fh_w = (const float*)d_in[16];
  const float* fh_b = (const float*)d_in[17];
  float* out = (float*)d_out;  // [256*512] out, then [256*256] i_weight

  float* lp_i = (float*)d_ws;              // 262,144 (4 x 65536)
  float* lp_l = lp_i + 262144;             // 65,536 (4 x 16384)
  float* att_i = lp_l + 65536;             // 65,536 (unused, kept for layout)
  float* att_l = att_i + 65536;            // 16,384 (unused)
  float* psum = att_l + 16384;             // 131,072 (16384 x 8)
  unsigned short* P1 = (unsigned short*)(psum + 131072);  // 4,194,304
  unsigned short* P2 = P1 + 4194304;                      // 4,194,304
  unsigned short* lfeat = P2 + 4194304;                   // 33,554,432 slot
  unsigned short* qb_bf = lfeat + 33554432;               // 8,388,608
  unsigned short* qbW1T_unused = qb_bf + 8388608;         // 8,388,608 (dead)
  unsigned short* ibT_unused = qbW1T_unused + 8388608;    // 33,554,432 (dead)
  unsigned short* w1t_lf = ibT_unused + 33554432;         // 262,144
  unsigned short* w1t_if = w1t_lf + 262144;               // 262,144
  unsigned short* wcat_t = w1t_if + 262144;               // 1,048,576
  unsigned short* fh_wt = wcat_t + 1048576;               // 524,288
  unsigned short* pooled_bf = fh_wt + 524288;             // 262,144
  unsigned short* F_bf = pooled_bf + 262144;              // 262,144

  k_prep<<<2560, 256, 0, stream>>>(qb, lf_w1, if_w1, lf_wm, if_wm, fh_w,
                                   qb_bf, w1t_lf, w1t_if, wcat_t, fh_wt);

  k_scores_f<<<dim3(2, 256), 256, 0, stream>>>(ib, qb_bf, imask, qmask, P1, P2, psum);
  k_av2<<<dim3(4, 256), 256, 0, stream>>>(P2, ib, psum, lfeat);
  k_logits_i<<<dim3(4, 256), 256, 0, stream>>>(qb_bf, w1t_lf, P1, lf_b1, lf_w2, lp_i);
  k_logits_part<<<512, 256, 0, stream>>>(lfeat, w1t_if, if_b1, if_w2, lp_l, 16384);
  k_final<<<512, 256, 0, stream>>>(lp_i, lp_l, imask, qmask, P1, qb_bf, lfeat,
                                   out + 131072, pooled_bf);

  k_egemm<<<dim3(16, 4), 256, 0, stream>>>(pooled_bf, wcat_t, lf_bm, if_bm,
                                           nullptr, F_bf, 1024, 1024);
  k_egemm<<<dim3(8, 4), 256, 0, stream>>>(F_bf, fh_wt, fh_b, nullptr,
                                          out, nullptr, 512, 1024);
}